// Round 5
// baseline (380.022 us; speedup 1.0000x reference)
//
#include <hip/hip_runtime.h>
#include <hip/hip_bf16.h>

// Problem constants (reference file)
#define NN 50000
#define F_IN 512
#define HH 128
#define CC 64

typedef __attribute__((ext_vector_type(8))) short short8v;   // 8 bf16 (4 VGPRs)
typedef __attribute__((ext_vector_type(4))) float f32x4;     // MFMA accumulator

__device__ __forceinline__ short f2b(float f) {
    unsigned u = __builtin_bit_cast(unsigned, f);
    unsigned r = (u + 0x7fffu + ((u >> 16) & 1u)) >> 16;     // RNE
    return (short)r;
}
__device__ __forceinline__ float b2f(short s) {
    unsigned u = ((unsigned)(unsigned short)s) << 16;
    return __builtin_bit_cast(float, u);
}
__device__ __forceinline__ float b2f_lo(unsigned p) {        // low 16 bits
    return __builtin_bit_cast(float, p << 16);
}
__device__ __forceinline__ float b2f_hi(unsigned p) {        // high 16 bits
    return __builtin_bit_cast(float, p & 0xffff0000u);
}

// ---------------------------------------------------------------------------
// Weight prep: Bt[n][k] = W_{n/OUTW}[k][n%OUTW]  (bf16, transposed + concat)
// ---------------------------------------------------------------------------
template <int K, int OUTW>
__global__ __launch_bounds__(256) void wprep(const float* __restrict__ W0,
                                             const float* __restrict__ W1,
                                             const float* __restrict__ W2,
                                             short* __restrict__ Bt) {
    const int id = blockIdx.x * 256 + threadIdx.x;
    const int nth = 3 * OUTW * (K / 8);
    if (id >= nth) return;
    const int n = id / (K / 8);
    const int kq = id % (K / 8);
    const int sel = n / OUTW;
    const int c = n % OUTW;
    const float* W = sel == 0 ? W0 : (sel == 1 ? W1 : W2);
    short v[8];
#pragma unroll
    for (int j = 0; j < 8; ++j) v[j] = f2b(W[(size_t)(kq * 8 + j) * OUTW + c]);
#pragma unroll
    for (int j = 0; j < 8; ++j) Bt[(size_t)n * K + kq * 8 + j] = v[j];
}

// ---------------------------------------------------------------------------
// MFMA GEMM, 2 column-tiles: C[M, NTOT] = A[M,K] @ Bt^T, split into O0/O1/O2
// (each M x BNout, bf16). BM=128, BK=32, 256 threads (4 waves = 2x2).
// grid = ceil(M/128) * 2. Reg-staged prefetch pipeline (T14 depth-1).
// ---------------------------------------------------------------------------
template <int K, int NTOT, int BNout, bool AF32>
__global__ __launch_bounds__(256) void gemm_mfma(const void* __restrict__ Avoid,
                                                 const short* __restrict__ Bt,
                                                 short* __restrict__ O0,
                                                 short* __restrict__ O1,
                                                 short* __restrict__ O2,
                                                 int M) {
    constexpr int BM = 128, BK = 32;
    constexpr int LDK = BK + 8;                 // 40 shorts = 80 B row stride
    constexpr int BN_blk = NTOT / 2;            // 192 or 96
    constexpr int FM = 4;                       // 16-row frags per wave (64 rows)
    constexpr int FN = BN_blk / 32;             // 16-col frags per wave (6 or 3)
    constexpr int NKT = K / BK;
    constexpr int NA = AF32 ? 4 : 2;            // per-thread A stage regs
    constexpr int NBLD = (BN_blk * 4 + 255) / 256;  // per-thread B int4 (3 or 2)
    constexpr int NBTOT = BN_blk * 4;           // total B int4 slots

    __shared__ short As[BM * LDK];
    __shared__ short Bs[BN_blk * LDK];

    const int tid = threadIdx.x;
    const int lane = tid & 63;
    const int wid = tid >> 6;                   // 0..3
    const int wm = wid >> 1;                    // 0..1 (64-row half)
    const int wn = wid & 1;                     // 0..1 (BN_blk/2-col half)
    const int bm = blockIdx.x >> 1;
    const int bn = blockIdx.x & 1;
    const int m0 = bm * BM;
    const int n0 = bn * BN_blk;

    f32x4 acc[FM][FN];
#pragma unroll
    for (int i = 0; i < FM; ++i)
#pragma unroll
        for (int j = 0; j < FN; ++j) acc[i][j] = (f32x4){0.f, 0.f, 0.f, 0.f};

    // staging registers
    float4 aF[NA];
    int4   aH[NA];
    int4   bR[NBLD];

    const float* Af = (const float*)Avoid;
    const short* Ah = (const short*)Avoid;

    // ---- prologue: load tile 0 into regs ----
    {
        const int k0 = 0;
        if (AF32) {
#pragma unroll
            for (int p = 0; p < NA; ++p) {
                int idx = p * 256 + tid;
                int r = idx >> 3, kq = idx & 7;
                int gr = m0 + r; if (gr >= M) gr = M - 1;
                aF[p] = *reinterpret_cast<const float4*>(&Af[(size_t)gr * K + k0 + kq * 4]);
            }
        } else {
#pragma unroll
            for (int p = 0; p < NA; ++p) {
                int idx = p * 256 + tid;
                int r = idx >> 2, kq = idx & 3;
                int gr = m0 + r; if (gr >= M) gr = M - 1;
                aH[p] = *reinterpret_cast<const int4*>(&Ah[(size_t)gr * K + k0 + kq * 8]);
            }
        }
#pragma unroll
        for (int p = 0; p < NBLD; ++p) {
            int idx = p * 256 + tid;
            if (idx < NBTOT) {
                int r = idx >> 2, kq = idx & 3;
                bR[p] = *reinterpret_cast<const int4*>(&Bt[(size_t)(n0 + r) * K + k0 + kq * 8]);
            }
        }
    }

    for (int kt = 0; kt < NKT; ++kt) {
        __syncthreads();                        // prior MFMA done reading LDS
        // ---- write staged regs -> LDS ----
        if (AF32) {
#pragma unroll
            for (int p = 0; p < NA; ++p) {
                int idx = p * 256 + tid;
                int r = idx >> 3, kq = idx & 7;
                const float4 v = aF[p];
                unsigned p0 = (unsigned)(unsigned short)f2b(v.x) |
                              ((unsigned)(unsigned short)f2b(v.y) << 16);
                unsigned p1 = (unsigned)(unsigned short)f2b(v.z) |
                              ((unsigned)(unsigned short)f2b(v.w) << 16);
                int2 w; w.x = (int)p0; w.y = (int)p1;
                *reinterpret_cast<int2*>(&As[r * LDK + kq * 4]) = w;
            }
        } else {
#pragma unroll
            for (int p = 0; p < NA; ++p) {
                int idx = p * 256 + tid;
                int r = idx >> 2, kq = idx & 3;
                *reinterpret_cast<int4*>(&As[r * LDK + kq * 8]) = aH[p];
            }
        }
#pragma unroll
        for (int p = 0; p < NBLD; ++p) {
            int idx = p * 256 + tid;
            if (idx < NBTOT) {
                int r = idx >> 2, kq = idx & 3;
                *reinterpret_cast<int4*>(&Bs[r * LDK + kq * 8]) = bR[p];
            }
        }
        __syncthreads();

        // ---- issue prefetch of tile kt+1 (in flight during MFMA) ----
        if (kt + 1 < NKT) {
            const int k0 = (kt + 1) * BK;
            if (AF32) {
#pragma unroll
                for (int p = 0; p < NA; ++p) {
                    int idx = p * 256 + tid;
                    int r = idx >> 3, kq = idx & 7;
                    int gr = m0 + r; if (gr >= M) gr = M - 1;
                    aF[p] = *reinterpret_cast<const float4*>(&Af[(size_t)gr * K + k0 + kq * 4]);
                }
            } else {
#pragma unroll
                for (int p = 0; p < NA; ++p) {
                    int idx = p * 256 + tid;
                    int r = idx >> 2, kq = idx & 3;
                    int gr = m0 + r; if (gr >= M) gr = M - 1;
                    aH[p] = *reinterpret_cast<const int4*>(&Ah[(size_t)gr * K + k0 + kq * 8]);
                }
            }
#pragma unroll
            for (int p = 0; p < NBLD; ++p) {
                int idx = p * 256 + tid;
                if (idx < NBTOT) {
                    int r = idx >> 2, kq = idx & 3;
                    bR[p] = *reinterpret_cast<const int4*>(&Bt[(size_t)(n0 + r) * K + k0 + kq * 8]);
                }
            }
        }

        // ---- compute tile kt from LDS ----
        short8v af[FM];
#pragma unroll
        for (int f = 0; f < FM; ++f)
            af[f] = *reinterpret_cast<const short8v*>(
                &As[(wm * 64 + f * 16 + (lane & 15)) * LDK + (lane >> 4) * 8]);
#pragma unroll
        for (int j = 0; j < FN; ++j) {
            short8v bf = *reinterpret_cast<const short8v*>(
                &Bs[(wn * (FN * 16) + j * 16 + (lane & 15)) * LDK + (lane >> 4) * 8]);
#pragma unroll
            for (int i = 0; i < FM; ++i)
                acc[i][j] = __builtin_amdgcn_mfma_f32_16x16x32_bf16(
                    af[i], bf, acc[i][j], 0, 0, 0);
        }
    }

    // ---- store ----
#pragma unroll
    for (int i = 0; i < FM; ++i)
#pragma unroll
        for (int j = 0; j < FN; ++j) {
            int ct = n0 + wn * (FN * 16) + j * 16 + (lane & 15);
            int sel = ct / BNout;
            int cc = ct % BNout;
            short* outp = (sel == 0) ? O0 : ((sel == 1) ? O1 : O2);
#pragma unroll
            for (int e = 0; e < 4; ++e) {
                int row = m0 + wm * 64 + i * 16 + (lane >> 4) * 4 + e;
                if (row < M) outp[(size_t)row * BNout + cc] = f2b(acc[i][j][e]);
            }
        }
}

// ---------------------------------------------------------------------------
// CSR construction: histogram -> 2-level exclusive scan -> position scatter
// ---------------------------------------------------------------------------
__global__ __launch_bounds__(256) void hist_kernel(const int* __restrict__ row,
                                                   int* __restrict__ counts, int E) {
    int i = blockIdx.x * 256 + threadIdx.x;
    if (i < E) atomicAdd(&counts[row[i]], 1);
}

__global__ __launch_bounds__(256) void block_sums_kernel(const int* __restrict__ counts,
                                                         int* __restrict__ bsums, int n) {
    __shared__ int s[256];
    int tid = threadIdx.x;
    int i = blockIdx.x * 256 + tid;
    s[tid] = (i < n) ? counts[i] : 0;
    __syncthreads();
#pragma unroll
    for (int off = 128; off > 0; off >>= 1) {
        if (tid < off) s[tid] += s[tid + off];
        __syncthreads();
    }
    if (tid == 0) bsums[blockIdx.x] = s[0];
}

__global__ __launch_bounds__(64) void scan_bsums_kernel(int* __restrict__ bsums, int nb) {
    if (threadIdx.x == 0) {
        int a = 0;
        for (int i = 0; i < nb; ++i) {
            int t = bsums[i];
            bsums[i] = a;
            a += t;
        }
    }
}

__global__ __launch_bounds__(256) void scan_final_kernel(const int* __restrict__ counts,
                                                         const int* __restrict__ bsums,
                                                         int* __restrict__ rowptr,
                                                         int* __restrict__ cursor, int n) {
    __shared__ int s[256];
    int tid = threadIdx.x;
    int i = blockIdx.x * 256 + tid;
    int v = (i < n) ? counts[i] : 0;
    s[tid] = v;
    __syncthreads();
#pragma unroll
    for (int off = 1; off < 256; off <<= 1) {
        int t = (tid >= off) ? s[tid - off] : 0;
        __syncthreads();
        s[tid] += t;
        __syncthreads();
    }
    int excl = s[tid] - v + bsums[blockIdx.x];
    if (i < n) {
        rowptr[i] = excl;
        cursor[i] = excl;
        if (i == n - 1) rowptr[n] = excl + v;
    }
}

__global__ __launch_bounds__(256) void scatter_edges_kernel(const int* __restrict__ row,
                                                            const int* __restrict__ col,
                                                            const float* __restrict__ val,
                                                            int* __restrict__ cursor,
                                                            int* __restrict__ cols_s,
                                                            float* __restrict__ vals_s, int E) {
    int i = blockIdx.x * 256 + threadIdx.x;
    if (i < E) {
        int r = row[i];
        int p = atomicAdd(&cursor[r], 1);
        cols_s[p] = col[i];
        vals_s[p] = val[i];
    }
}

// ---------------------------------------------------------------------------
__device__ __forceinline__ float wave_sum(float v) {
#pragma unroll
    for (int off = 32; off > 0; off >>= 1) v += __shfl_xor(v, off, 64);
    return v;
}
__device__ __forceinline__ float wave_max(float v) {
#pragma unroll
    for (int off = 32; off > 0; off >>= 1) v = fmaxf(v, __shfl_xor(v, off, 64));
    return v;
}

// ---------------------------------------------------------------------------
// Layer-1 fused: dual CSR spmm (low & high) + attention + combine -> h (bf16).
// One wave per node; H=128 -> lane owns feat pair (2*lane, 2*lane+1).
// ---------------------------------------------------------------------------
__global__ __launch_bounds__(256) void spmm_att1(const int* __restrict__ rowptr,
                                                 const int* __restrict__ cols,
                                                 const float* __restrict__ vals,
                                                 const short* __restrict__ xl,
                                                 const short* __restrict__ xh,
                                                 const short* __restrict__ xm,
                                                 const float* __restrict__ a_low,
                                                 const float* __restrict__ a_high,
                                                 const float* __restrict__ a_mlp,
                                                 const float* __restrict__ av,
                                                 short* __restrict__ hb,
                                                 int n) {
    const int node = blockIdx.x * 4 + (threadIdx.x >> 6);
    const int lane = threadIdx.x & 63;
    if (node >= n) return;
    const unsigned* XL = (const unsigned*)xl;   // row = 64 u32 (feat pairs)
    const unsigned* XH = (const unsigned*)xh;
    const unsigned* XM = (const unsigned*)xm;

    const int s = rowptr[node];
    const int e = rowptr[node + 1];

    float l0 = 0.f, l1 = 0.f, h0 = 0.f, h1 = 0.f;
    for (int b = s; b < e; b += 64) {
        const int idx = b + lane;
        int c = 0;
        float v = 0.f;
        if (idx < e) { c = cols[idx]; v = vals[idx]; }
        const int cnt = min(64, e - b);
        for (int j = 0; j < cnt; ++j) {
            const int cj = __shfl(c, j, 64);
            const float vj = __shfl(v, j, 64);
            const unsigned pl = XL[(size_t)cj * 64 + lane];
            const unsigned ph = XH[(size_t)cj * 64 + lane];
            l0 += vj * b2f_lo(pl);
            l1 += vj * b2f_hi(pl);
            h0 += vj * b2f_lo(ph);
            h1 += vj * b2f_hi(ph);
        }
    }

    const unsigned xhn = XH[(size_t)node * 64 + lane];
    const unsigned xmn = XM[(size_t)node * 64 + lane];
    float ol0 = fmaxf(l0, 0.f);
    float ol1 = fmaxf(l1, 0.f);
    float oh0 = fmaxf(b2f_lo(xhn) - h0, 0.f);
    float oh1 = fmaxf(b2f_hi(xhn) - h1, 0.f);
    float om0 = fmaxf(b2f_lo(xmn), 0.f);
    float om1 = fmaxf(b2f_hi(xmn), 0.f);

    const float2 aL = ((const float2*)a_low)[lane];
    const float2 aH = ((const float2*)a_high)[lane];
    const float2 aM = ((const float2*)a_mlp)[lane];
    float dl = wave_sum(ol0 * aL.x + ol1 * aL.y);
    float dh = wave_sum(oh0 * aH.x + oh1 * aH.y);
    float dm = wave_sum(om0 * aM.x + om1 * aM.y);

    const float g0 = 1.f / (1.f + expf(-dl));
    const float g1 = 1.f / (1.f + expf(-dh));
    const float g2 = 1.f / (1.f + expf(-dm));
    float s0 = (g0 * av[0] + g1 * av[3] + g2 * av[6]) * (1.f / 3.f);
    float s1 = (g0 * av[1] + g1 * av[4] + g2 * av[7]) * (1.f / 3.f);
    float s2 = (g0 * av[2] + g1 * av[5] + g2 * av[8]) * (1.f / 3.f);
    float mx = fmaxf(s0, fmaxf(s1, s2));
    float e0 = expf(s0 - mx), e1 = expf(s1 - mx), e2 = expf(s2 - mx);
    float inv = 1.f / (e0 + e1 + e2);
    float at0 = e0 * inv, at1 = e1 * inv, at2 = e2 * inv;

    float ho0 = 3.f * (at0 * ol0 + at1 * oh0 + at2 * om0);
    float ho1 = 3.f * (at0 * ol1 + at1 * oh1 + at2 * om1);
    unsigned pk = (unsigned)(unsigned short)f2b(ho0) |
                  ((unsigned)(unsigned short)f2b(ho1) << 16);
    ((unsigned*)hb)[(size_t)node * 64 + lane] = pk;
}

// ---------------------------------------------------------------------------
// Layer-2 fused: dual CSR spmm + attention + combine + log_softmax -> out.
// One wave per node; C=64 -> lane owns one class.
// ---------------------------------------------------------------------------
__global__ __launch_bounds__(256) void spmm_att2(const int* __restrict__ rowptr,
                                                 const int* __restrict__ cols,
                                                 const float* __restrict__ vals,
                                                 const short* __restrict__ xl,
                                                 const short* __restrict__ xh,
                                                 const short* __restrict__ xm,
                                                 const float* __restrict__ a_low,
                                                 const float* __restrict__ a_high,
                                                 const float* __restrict__ a_mlp,
                                                 const float* __restrict__ av,
                                                 float* __restrict__ out,
                                                 int n) {
    const int node = blockIdx.x * 4 + (threadIdx.x >> 6);
    const int lane = threadIdx.x & 63;
    if (node >= n) return;

    const int s = rowptr[node];
    const int e = rowptr[node + 1];

    float accl = 0.f, acch = 0.f;
    for (int b = s; b < e; b += 64) {
        const int idx = b + lane;
        int c = 0;
        float v = 0.f;
        if (idx < e) { c = cols[idx]; v = vals[idx]; }
        const int cnt = min(64, e - b);
        for (int j = 0; j < cnt; ++j) {
            const int cj = __shfl(c, j, 64);
            const float vj = __shfl(v, j, 64);
            accl += vj * b2f(xl[(size_t)cj * 64 + lane]);
            acch += vj * b2f(xh[(size_t)cj * 64 + lane]);
        }
    }

    float ol = fmaxf(accl, 0.f);
    float oh = fmaxf(b2f(xh[(size_t)node * 64 + lane]) - acch, 0.f);
    float om = fmaxf(b2f(xm[(size_t)node * 64 + lane]), 0.f);

    float dl = wave_sum(ol * a_low[lane]);
    float dh = wave_sum(oh * a_high[lane]);
    float dm = wave_sum(om * a_mlp[lane]);

    const float g0 = 1.f / (1.f + expf(-dl));
    const float g1 = 1.f / (1.f + expf(-dh));
    const float g2 = 1.f / (1.f + expf(-dm));
    float s0 = (g0 * av[0] + g1 * av[3] + g2 * av[6]) * (1.f / 3.f);
    float s1 = (g0 * av[1] + g1 * av[4] + g2 * av[7]) * (1.f / 3.f);
    float s2 = (g0 * av[2] + g1 * av[5] + g2 * av[8]) * (1.f / 3.f);
    float mx3 = fmaxf(s0, fmaxf(s1, s2));
    float e0 = expf(s0 - mx3), e1 = expf(s1 - mx3), e2 = expf(s2 - mx3);
    float inv = 1.f / (e0 + e1 + e2);
    float at0 = e0 * inv, at1 = e1 * inv, at2 = e2 * inv;

    float o = 3.f * (at0 * ol + at1 * oh + at2 * om);

    float m = wave_max(o);
    float ex = expf(o - m);
    float su = wave_sum(ex);
    out[(size_t)node * 64 + lane] = o - m - logf(su);
}

// ---------------------------------------------------------------------------
extern "C" void kernel_launch(void* const* d_in, const int* in_sizes, int n_in,
                              void* d_out, int out_size, void* d_ws, size_t ws_size,
                              hipStream_t stream) {
    const float* x    = (const float*)d_in[0];
    const int*   erow = (const int*)d_in[1];
    const int*   ecol = (const int*)d_in[2];
    const float* eval = (const float*)d_in[3];
    const float* Wl   = (const float*)d_in[4];
    const float* Wh   = (const float*)d_in[5];
    const float* Wm   = (const float*)d_in[6];
    const float* al   = (const float*)d_in[7];
    const float* ah   = (const float*)d_in[8];
    const float* am   = (const float*)d_in[9];
    const float* av   = (const float*)d_in[10];
    const float* Wl2  = (const float*)d_in[11];
    const float* Wh2  = (const float*)d_in[12];
    const float* Wm2  = (const float*)d_in[13];
    const float* al2  = (const float*)d_in[14];
    const float* ah2  = (const float*)d_in[15];
    const float* am2  = (const float*)d_in[16];
    const float* av2  = (const float*)d_in[17];
    float* out = (float*)d_out;

    const int E = in_sizes[1];
    const int N = NN;
    const size_t NH = (size_t)N * HH;

    short* xb    = (short*)d_ws;
    short* xl_b  = xb;                 // N*HH bf16
    short* xh_b  = xb + NH;            // N*HH bf16
    short* xm_b  = xb + 2 * NH;        // N*HH bf16
    short* hb    = xb + 3 * NH;        // N*HH bf16
    short* Bt1   = hb + NH;            // 384*512 bf16
    short* Bt2   = Bt1 + 384 * 512;    // 192*128 bf16
    int*   ip    = (int*)(Bt2 + 192 * 128);
    int*   counts = ip;                // N
    int*   rowptr = ip + N;            // N+1
    int*   cursor = ip + 2 * N + 1;    // N
    int*   bsums  = ip + 3 * N + 1;    // 256
    int*   cols_s = ip + 3 * N + 1 + 256;  // E
    float* vals_s = (float*)(cols_s + E);  // E

    // Layer-2 aliases (xl/xh/xm regions dead after spmm_att1)
    short* xl2_b = xb;                        // N*CC
    short* xh2_b = xb + (size_t)N * CC;       // N*CC
    short* xm2_b = xb + 2 * (size_t)N * CC;   // N*CC

    const int NB = (N + 255) / 256;
    const int EB = (E + 255) / 256;
    const int node_blocks = (N + 3) / 4;
    const int MT = (N + 127) / 128;

    // ---------------- CSR build + weight prep ----------------
    hipMemsetAsync(counts, 0, (size_t)N * sizeof(int), stream);
    hist_kernel<<<EB, 256, 0, stream>>>(erow, counts, E);
    block_sums_kernel<<<NB, 256, 0, stream>>>(counts, bsums, N);
    scan_bsums_kernel<<<1, 64, 0, stream>>>(bsums, NB);
    scan_final_kernel<<<NB, 256, 0, stream>>>(counts, bsums, rowptr, cursor, N);
    scatter_edges_kernel<<<EB, 256, 0, stream>>>(erow, ecol, eval, cursor, cols_s, vals_s, E);
    wprep<F_IN, HH><<<(3 * HH * (F_IN / 8) + 255) / 256, 256, 0, stream>>>(Wl, Wh, Wm, Bt1);
    wprep<HH, CC><<<(3 * CC * (HH / 8) + 255) / 256, 256, 0, stream>>>(Wl2, Wh2, Wm2, Bt2);

    // ---------------- Layer 1 ----------------
    gemm_mfma<F_IN, 384, HH, true><<<MT * 2, 256, 0, stream>>>(x, Bt1, xl_b, xh_b, xm_b, N);
    spmm_att1<<<node_blocks, 256, 0, stream>>>(rowptr, cols_s, vals_s,
                                               xl_b, xh_b, xm_b, al, ah, am, av, hb, N);

    // ---------------- Layer 2 ----------------
    gemm_mfma<HH, 192, CC, false><<<MT * 2, 256, 0, stream>>>(hb, Bt2, xl2_b, xh2_b, xm2_b, N);
    spmm_att2<<<node_blocks, 256, 0, stream>>>(rowptr, cols_s, vals_s,
                                               xl2_b, xh2_b, xm2_b,
                                               al2, ah2, am2, av2, out, N);
}

// Round 6
// 318.293 us; speedup vs baseline: 1.1939x; 1.1939x over previous
//
#include <hip/hip_runtime.h>
#include <hip/hip_bf16.h>

// Problem constants (reference file)
#define NN 50000
#define F_IN 512
#define HH 128
#define CC 64

typedef __attribute__((ext_vector_type(8))) short short8v;   // 8 bf16 (4 VGPRs)
typedef __attribute__((ext_vector_type(4))) float f32x4;     // MFMA accumulator

__device__ __forceinline__ short f2b(float f) {
    unsigned u = __builtin_bit_cast(unsigned, f);
    unsigned r = (u + 0x7fffu + ((u >> 16) & 1u)) >> 16;     // RNE
    return (short)r;
}
__device__ __forceinline__ float b2f(short s) {
    unsigned u = ((unsigned)(unsigned short)s) << 16;
    return __builtin_bit_cast(float, u);
}
__device__ __forceinline__ float b2f_lo(unsigned p) {        // low 16 bits
    return __builtin_bit_cast(float, p << 16);
}
__device__ __forceinline__ float b2f_hi(unsigned p) {        // high 16 bits
    return __builtin_bit_cast(float, p & 0xffff0000u);
}

// Bijective XCD swizzle (m204): physical XCD (= orig%8) gets a contiguous
// chunk of logical wgids -> column-tiles sharing an A-panel stay on one XCD.
__device__ __forceinline__ int xcd_swz(int bid, int nwg) {
    int q = nwg >> 3, r = nwg & 7;
    int xcd = bid & 7, off = bid >> 3;
    return (xcd < r ? xcd * (q + 1) : r * (q + 1) + (xcd - r) * q) + off;
}

// ---------------------------------------------------------------------------
// Weight prep: Bt[n][k] = W_{n/OUTW}[k][n%OUTW]  (bf16, transposed + concat)
// ---------------------------------------------------------------------------
template <int K, int OUTW>
__global__ __launch_bounds__(256) void wprep(const float* __restrict__ W0,
                                             const float* __restrict__ W1,
                                             const float* __restrict__ W2,
                                             short* __restrict__ Bt) {
    const int id = blockIdx.x * 256 + threadIdx.x;
    const int nth = 3 * OUTW * (K / 8);
    if (id >= nth) return;
    const int n = id / (K / 8);
    const int kq = id % (K / 8);
    const int sel = n / OUTW;
    const int c = n % OUTW;
    const float* W = sel == 0 ? W0 : (sel == 1 ? W1 : W2);
    short v[8];
#pragma unroll
    for (int j = 0; j < 8; ++j) v[j] = f2b(W[(size_t)(kq * 8 + j) * OUTW + c]);
#pragma unroll
    for (int j = 0; j < 8; ++j) Bt[(size_t)n * K + kq * 8 + j] = v[j];
}

// ---------------------------------------------------------------------------
// MFMA GEMM (round-3 structure): grid = ceil(M/128)*3, one column-tile of
// BNout per block. Outputs: bn 0/1 -> interleaved xlh buffer, bn 2 -> xm.
// BNout=128: 4 waves 2x2, FM=4 FN=4.  BNout=64: 4 waves 4x1, FM=2 FN=4.
// ---------------------------------------------------------------------------
template <int K, int BNout, bool AF32>
__global__ __launch_bounds__(256) void gemm_mfma(const void* __restrict__ Avoid,
                                                 const short* __restrict__ Bt,
                                                 short* __restrict__ xlh,
                                                 short* __restrict__ xm,
                                                 int M) {
    constexpr int BM = 128, BK = 32;
    constexpr int LDK = BK + 8;                 // 40 shorts = 80 B row stride
    constexpr int FM = (BNout == 128) ? 4 : 2;
    constexpr int FN = 4;
    constexpr int WM = FM * 16;                 // 64 or 32
    __shared__ short As[BM * LDK];
    __shared__ short Bs[BNout * LDK];

    const int tid = threadIdx.x;
    const int lane = tid & 63;
    const int wid = tid >> 6;
    const int wg = xcd_swz(blockIdx.x, gridDim.x);
    const int bm = wg / 3;
    const int bn = wg % 3;
    const int m0 = bm * BM;
    const int n0 = bn * BNout;
    const int wm = (BNout == 128) ? (wid >> 1) : wid;
    const int wn = (BNout == 128) ? (wid & 1) : 0;

    f32x4 acc[FM][FN];
#pragma unroll
    for (int i = 0; i < FM; ++i)
#pragma unroll
        for (int j = 0; j < FN; ++j) acc[i][j] = (f32x4){0.f, 0.f, 0.f, 0.f};

    for (int k0 = 0; k0 < K; k0 += BK) {
        __syncthreads();
        // ---- stage A tile (BM x BK) ----
        if (AF32) {
            const float* A = (const float*)Avoid;
#pragma unroll
            for (int p = 0; p < 4; ++p) {                   // 1024 float4 / 256
                int idx = p * 256 + tid;
                int r = idx >> 3, kq = idx & 7;
                int gr = m0 + r; if (gr >= M) gr = M - 1;
                const float4 v = *reinterpret_cast<const float4*>(
                    &A[(size_t)gr * K + k0 + kq * 4]);
                unsigned p0 = (unsigned)(unsigned short)f2b(v.x) |
                              ((unsigned)(unsigned short)f2b(v.y) << 16);
                unsigned p1 = (unsigned)(unsigned short)f2b(v.z) |
                              ((unsigned)(unsigned short)f2b(v.w) << 16);
                int2 w; w.x = (int)p0; w.y = (int)p1;
                *reinterpret_cast<int2*>(&As[r * LDK + kq * 4]) = w;
            }
        } else {
            const short* A = (const short*)Avoid;
#pragma unroll
            for (int p = 0; p < 2; ++p) {                   // 512 int4 / 256
                int idx = p * 256 + tid;
                int r = idx >> 2, kq = idx & 3;
                int gr = m0 + r; if (gr >= M) gr = M - 1;
                const int4 v = *reinterpret_cast<const int4*>(
                    &A[(size_t)gr * K + k0 + kq * 8]);
                *reinterpret_cast<int4*>(&As[r * LDK + kq * 8]) = v;
            }
        }
        // ---- stage B tile (BNout x BK) ----
#pragma unroll
        for (int p = 0; p < BNout / 64; ++p) {
            int idx = p * 256 + tid;
            int r = idx >> 2, kq = idx & 3;
            const int4 v = *reinterpret_cast<const int4*>(
                &Bt[(size_t)(n0 + r) * K + k0 + kq * 8]);
            *reinterpret_cast<int4*>(&Bs[r * LDK + kq * 8]) = v;
        }
        __syncthreads();

        short8v af[FM], bf[FN];
#pragma unroll
        for (int f = 0; f < FM; ++f)
            af[f] = *reinterpret_cast<const short8v*>(
                &As[(wm * WM + f * 16 + (lane & 15)) * LDK + (lane >> 4) * 8]);
#pragma unroll
        for (int f = 0; f < FN; ++f)
            bf[f] = *reinterpret_cast<const short8v*>(
                &Bs[(wn * 64 + f * 16 + (lane & 15)) * LDK + (lane >> 4) * 8]);
#pragma unroll
        for (int i = 0; i < FM; ++i)
#pragma unroll
            for (int j = 0; j < FN; ++j)
                acc[i][j] = __builtin_amdgcn_mfma_f32_16x16x32_bf16(
                    af[i], bf[j], acc[i][j], 0, 0, 0);
    }

    // ---- store (interleaved for bn 0/1, plain for bn 2) ----
#pragma unroll
    for (int i = 0; i < FM; ++i)
#pragma unroll
        for (int j = 0; j < FN; ++j) {
            int cc = wn * 64 + j * 16 + (lane & 15);
#pragma unroll
            for (int e = 0; e < 4; ++e) {
                int row = m0 + wm * WM + i * 16 + (lane >> 4) * 4 + e;
                if (row >= M) continue;
                short v = f2b(acc[i][j][e]);
                if (bn == 2) {
                    xm[(size_t)row * BNout + cc] = v;
                } else if (BNout == 128) {
                    // pair-interleaved: [node][64 pairs][{xl0,xl1,xh0,xh1}]
                    xlh[(size_t)row * 256 + (cc >> 1) * 4 + bn * 2 + (cc & 1)] = v;
                } else {
                    // element-interleaved: [node][64][{xl,xh}]
                    xlh[(size_t)row * 128 + cc * 2 + bn] = v;
                }
            }
        }
}

// ---------------------------------------------------------------------------
// CSR construction: histogram -> 2-level exclusive scan -> position scatter
// ---------------------------------------------------------------------------
__global__ __launch_bounds__(256) void hist_kernel(const int* __restrict__ row,
                                                   int* __restrict__ counts, int E) {
    int i = blockIdx.x * 256 + threadIdx.x;
    if (i < E) atomicAdd(&counts[row[i]], 1);
}

__global__ __launch_bounds__(256) void block_sums_kernel(const int* __restrict__ counts,
                                                         int* __restrict__ bsums, int n) {
    __shared__ int s[256];
    int tid = threadIdx.x;
    int i = blockIdx.x * 256 + tid;
    s[tid] = (i < n) ? counts[i] : 0;
    __syncthreads();
#pragma unroll
    for (int off = 128; off > 0; off >>= 1) {
        if (tid < off) s[tid] += s[tid + off];
        __syncthreads();
    }
    if (tid == 0) bsums[blockIdx.x] = s[0];
}

__global__ __launch_bounds__(64) void scan_bsums_kernel(int* __restrict__ bsums, int nb) {
    if (threadIdx.x == 0) {
        int a = 0;
        for (int i = 0; i < nb; ++i) {
            int t = bsums[i];
            bsums[i] = a;
            a += t;
        }
    }
}

__global__ __launch_bounds__(256) void scan_final_kernel(const int* __restrict__ counts,
                                                         const int* __restrict__ bsums,
                                                         int* __restrict__ rowptr,
                                                         int* __restrict__ cursor, int n) {
    __shared__ int s[256];
    int tid = threadIdx.x;
    int i = blockIdx.x * 256 + tid;
    int v = (i < n) ? counts[i] : 0;
    s[tid] = v;
    __syncthreads();
#pragma unroll
    for (int off = 1; off < 256; off <<= 1) {
        int t = (tid >= off) ? s[tid - off] : 0;
        __syncthreads();
        s[tid] += t;
        __syncthreads();
    }
    int excl = s[tid] - v + bsums[blockIdx.x];
    if (i < n) {
        rowptr[i] = excl;
        cursor[i] = excl;
        if (i == n - 1) rowptr[n] = excl + v;
    }
}

__global__ __launch_bounds__(256) void scatter_edges_kernel(const int* __restrict__ row,
                                                            const int* __restrict__ col,
                                                            const float* __restrict__ val,
                                                            int* __restrict__ cursor,
                                                            int* __restrict__ cols_s,
                                                            float* __restrict__ vals_s, int E) {
    int i = blockIdx.x * 256 + threadIdx.x;
    if (i < E) {
        int r = row[i];
        int p = atomicAdd(&cursor[r], 1);
        cols_s[p] = col[i];
        vals_s[p] = val[i];
    }
}

// ---------------------------------------------------------------------------
__device__ __forceinline__ float wave_sum(float v) {
#pragma unroll
    for (int off = 32; off > 0; off >>= 1) v += __shfl_xor(v, off, 64);
    return v;
}
__device__ __forceinline__ float wave_max(float v) {
#pragma unroll
    for (int off = 32; off > 0; off >>= 1) v = fmaxf(v, __shfl_xor(v, off, 64));
    return v;
}

// ---------------------------------------------------------------------------
// Layer-1 fused: dual CSR spmm + attention + combine -> h (bf16).
// xlh interleaved: [node][64 pairs][{xl0,xl1,xh0,xh1}] -> one dwordx2/edge.
// ---------------------------------------------------------------------------
__global__ __launch_bounds__(256) void spmm_att1(const int* __restrict__ rowptr,
                                                 const int* __restrict__ cols,
                                                 const float* __restrict__ vals,
                                                 const short* __restrict__ xlh,
                                                 const short* __restrict__ xm,
                                                 const float* __restrict__ a_low,
                                                 const float* __restrict__ a_high,
                                                 const float* __restrict__ a_mlp,
                                                 const float* __restrict__ av,
                                                 short* __restrict__ hb,
                                                 int n) {
    const int node = blockIdx.x * 4 + (threadIdx.x >> 6);
    const int lane = threadIdx.x & 63;
    if (node >= n) return;
    const uint2* XLH = (const uint2*)xlh;       // node stride 64 uint2
    const unsigned* XM = (const unsigned*)xm;

    const int s = rowptr[node];
    const int e = rowptr[node + 1];

    float l0 = 0.f, l1 = 0.f, h0 = 0.f, h1 = 0.f;
    for (int b = s; b < e; b += 64) {
        const int idx = b + lane;
        int c = 0;
        float v = 0.f;
        if (idx < e) { c = cols[idx]; v = vals[idx]; }
        const int cnt = min(64, e - b);
        for (int j = 0; j < cnt; ++j) {
            const int cj = __shfl(c, j, 64);
            const float vj = __shfl(v, j, 64);
            const uint2 p = XLH[(size_t)cj * 64 + lane];
            l0 += vj * b2f_lo(p.x);
            l1 += vj * b2f_hi(p.x);
            h0 += vj * b2f_lo(p.y);
            h1 += vj * b2f_hi(p.y);
        }
    }

    const uint2 self = XLH[(size_t)node * 64 + lane];
    const unsigned xmn = XM[(size_t)node * 64 + lane];
    float ol0 = fmaxf(l0, 0.f);
    float ol1 = fmaxf(l1, 0.f);
    float oh0 = fmaxf(b2f_lo(self.y) - h0, 0.f);
    float oh1 = fmaxf(b2f_hi(self.y) - h1, 0.f);
    float om0 = fmaxf(b2f_lo(xmn), 0.f);
    float om1 = fmaxf(b2f_hi(xmn), 0.f);

    const float2 aL = ((const float2*)a_low)[lane];
    const float2 aH = ((const float2*)a_high)[lane];
    const float2 aM = ((const float2*)a_mlp)[lane];
    float dl = wave_sum(ol0 * aL.x + ol1 * aL.y);
    float dh = wave_sum(oh0 * aH.x + oh1 * aH.y);
    float dm = wave_sum(om0 * aM.x + om1 * aM.y);

    const float g0 = 1.f / (1.f + expf(-dl));
    const float g1 = 1.f / (1.f + expf(-dh));
    const float g2 = 1.f / (1.f + expf(-dm));
    float s0 = (g0 * av[0] + g1 * av[3] + g2 * av[6]) * (1.f / 3.f);
    float s1 = (g0 * av[1] + g1 * av[4] + g2 * av[7]) * (1.f / 3.f);
    float s2 = (g0 * av[2] + g1 * av[5] + g2 * av[8]) * (1.f / 3.f);
    float mx = fmaxf(s0, fmaxf(s1, s2));
    float e0 = expf(s0 - mx), e1 = expf(s1 - mx), e2 = expf(s2 - mx);
    float inv = 1.f / (e0 + e1 + e2);
    float at0 = e0 * inv, at1 = e1 * inv, at2 = e2 * inv;

    float ho0 = 3.f * (at0 * ol0 + at1 * oh0 + at2 * om0);
    float ho1 = 3.f * (at0 * ol1 + at1 * oh1 + at2 * om1);
    unsigned pk = (unsigned)(unsigned short)f2b(ho0) |
                  ((unsigned)(unsigned short)f2b(ho1) << 16);
    ((unsigned*)hb)[(size_t)node * 64 + lane] = pk;
}

// ---------------------------------------------------------------------------
// Layer-2 fused: dual CSR spmm + attention + combine + log_softmax -> out.
// xlh2 interleaved: [node][64][{xl,xh}] -> one dword/edge.
// ---------------------------------------------------------------------------
__global__ __launch_bounds__(256) void spmm_att2(const int* __restrict__ rowptr,
                                                 const int* __restrict__ cols,
                                                 const float* __restrict__ vals,
                                                 const short* __restrict__ xlh,
                                                 const short* __restrict__ xm,
                                                 const float* __restrict__ a_low,
                                                 const float* __restrict__ a_high,
                                                 const float* __restrict__ a_mlp,
                                                 const float* __restrict__ av,
                                                 float* __restrict__ out,
                                                 int n) {
    const int node = blockIdx.x * 4 + (threadIdx.x >> 6);
    const int lane = threadIdx.x & 63;
    if (node >= n) return;
    const unsigned* XLH = (const unsigned*)xlh; // node stride 64 u32

    const int s = rowptr[node];
    const int e = rowptr[node + 1];

    float accl = 0.f, acch = 0.f;
    for (int b = s; b < e; b += 64) {
        const int idx = b + lane;
        int c = 0;
        float v = 0.f;
        if (idx < e) { c = cols[idx]; v = vals[idx]; }
        const int cnt = min(64, e - b);
        for (int j = 0; j < cnt; ++j) {
            const int cj = __shfl(c, j, 64);
            const float vj = __shfl(v, j, 64);
            const unsigned p = XLH[(size_t)cj * 64 + lane];
            accl += vj * b2f_lo(p);
            acch += vj * b2f_hi(p);
        }
    }

    const unsigned self = XLH[(size_t)node * 64 + lane];
    float ol = fmaxf(accl, 0.f);
    float oh = fmaxf(b2f_hi(self) - acch, 0.f);
    float om = fmaxf(b2f(xm[(size_t)node * 64 + lane]), 0.f);

    float dl = wave_sum(ol * a_low[lane]);
    float dh = wave_sum(oh * a_high[lane]);
    float dm = wave_sum(om * a_mlp[lane]);

    const float g0 = 1.f / (1.f + expf(-dl));
    const float g1 = 1.f / (1.f + expf(-dh));
    const float g2 = 1.f / (1.f + expf(-dm));
    float s0 = (g0 * av[0] + g1 * av[3] + g2 * av[6]) * (1.f / 3.f);
    float s1 = (g0 * av[1] + g1 * av[4] + g2 * av[7]) * (1.f / 3.f);
    float s2 = (g0 * av[2] + g1 * av[5] + g2 * av[8]) * (1.f / 3.f);
    float mx3 = fmaxf(s0, fmaxf(s1, s2));
    float e0 = expf(s0 - mx3), e1 = expf(s1 - mx3), e2 = expf(s2 - mx3);
    float inv = 1.f / (e0 + e1 + e2);
    float at0 = e0 * inv, at1 = e1 * inv, at2 = e2 * inv;

    float o = 3.f * (at0 * ol + at1 * oh + at2 * om);

    float m = wave_max(o);
    float ex = expf(o - m);
    float su = wave_sum(ex);
    out[(size_t)node * 64 + lane] = o - m - logf(su);
}

// ---------------------------------------------------------------------------
extern "C" void kernel_launch(void* const* d_in, const int* in_sizes, int n_in,
                              void* d_out, int out_size, void* d_ws, size_t ws_size,
                              hipStream_t stream) {
    const float* x    = (const float*)d_in[0];
    const int*   erow = (const int*)d_in[1];
    const int*   ecol = (const int*)d_in[2];
    const float* eval = (const float*)d_in[3];
    const float* Wl   = (const float*)d_in[4];
    const float* Wh   = (const float*)d_in[5];
    const float* Wm   = (const float*)d_in[6];
    const float* al   = (const float*)d_in[7];
    const float* ah   = (const float*)d_in[8];
    const float* am   = (const float*)d_in[9];
    const float* av   = (const float*)d_in[10];
    const float* Wl2  = (const float*)d_in[11];
    const float* Wh2  = (const float*)d_in[12];
    const float* Wm2  = (const float*)d_in[13];
    const float* al2  = (const float*)d_in[14];
    const float* ah2  = (const float*)d_in[15];
    const float* am2  = (const float*)d_in[16];
    const float* av2  = (const float*)d_in[17];
    float* out = (float*)d_out;

    const int E = in_sizes[1];
    const int N = NN;

    short* xb    = (short*)d_ws;
    short* xlh1  = xb;                          // N*256 shorts (xl/xh pair-interleaved)
    short* xm1   = xb + (size_t)N * 256;        // N*128
    short* hb    = xm1 + (size_t)N * 128;       // N*128
    short* Bt1   = hb + (size_t)N * 128;        // 384*512
    short* Bt2   = Bt1 + 384 * 512;             // 192*128
    int*   ip    = (int*)(Bt2 + 192 * 128);
    int*   counts = ip;                         // N
    int*   rowptr = ip + N;                     // N+1
    int*   cursor = ip + 2 * N + 1;             // N
    int*   bsums  = ip + 3 * N + 1;             // 256
    int*   cols_s = ip + 3 * N + 1 + 256;       // E
    float* vals_s = (float*)(cols_s + E);       // E

    // Layer-2 aliases (xlh1/xm1 regions dead after spmm_att1)
    short* xlh2 = xb;                           // N*128 shorts (element-interleaved)
    short* xm2  = xb + (size_t)N * 128;         // N*64

    const int NB = (N + 255) / 256;
    const int EB = (E + 255) / 256;
    const int node_blocks = (N + 3) / 4;
    const int MT = (N + 127) / 128;

    // ---------------- CSR build + weight prep ----------------
    hipMemsetAsync(counts, 0, (size_t)N * sizeof(int), stream);
    hist_kernel<<<EB, 256, 0, stream>>>(erow, counts, E);
    block_sums_kernel<<<NB, 256, 0, stream>>>(counts, bsums, N);
    scan_bsums_kernel<<<1, 64, 0, stream>>>(bsums, NB);
    scan_final_kernel<<<NB, 256, 0, stream>>>(counts, bsums, rowptr, cursor, N);
    scatter_edges_kernel<<<EB, 256, 0, stream>>>(erow, ecol, eval, cursor, cols_s, vals_s, E);
    wprep<F_IN, HH><<<(3 * HH * (F_IN / 8) + 255) / 256, 256, 0, stream>>>(Wl, Wh, Wm, Bt1);
    wprep<HH, CC><<<(3 * CC * (HH / 8) + 255) / 256, 256, 0, stream>>>(Wl2, Wh2, Wm2, Bt2);

    // ---------------- Layer 1 ----------------
    gemm_mfma<F_IN, HH, true><<<MT * 3, 256, 0, stream>>>(x, Bt1, xlh1, xm1, N);
    spmm_att1<<<node_blocks, 256, 0, stream>>>(rowptr, cols_s, vals_s,
                                               xlh1, xm1, al, ah, am, av, hb, N);

    // ---------------- Layer 2 ----------------
    gemm_mfma<HH, CC, false><<<MT * 3, 256, 0, stream>>>(hb, Bt2, xlh2, xm2, N);
    spmm_att2<<<node_blocks, 256, 0, stream>>>(rowptr, cols_s, vals_s,
                                               xlh2, xm2, al2, ah2, am2, av2, out, N);
}

// Round 7
// 294.082 us; speedup vs baseline: 1.2922x; 1.0823x over previous
//
#include <hip/hip_runtime.h>
#include <hip/hip_bf16.h>

// Problem constants (reference file)
#define NN 50000
#define F_IN 512
#define HH 128
#define CC 64

typedef __attribute__((ext_vector_type(8))) short short8v;   // 8 bf16 (4 VGPRs)
typedef __attribute__((ext_vector_type(4))) float f32x4;     // MFMA accumulator

__device__ __forceinline__ short f2b(float f) {
    unsigned u = __builtin_bit_cast(unsigned, f);
    unsigned r = (u + 0x7fffu + ((u >> 16) & 1u)) >> 16;     // RNE
    return (short)r;
}
__device__ __forceinline__ float b2f(short s) {
    unsigned u = ((unsigned)(unsigned short)s) << 16;
    return __builtin_bit_cast(float, u);
}
__device__ __forceinline__ float b2f_lo(unsigned p) {        // low 16 bits
    return __builtin_bit_cast(float, p << 16);
}
__device__ __forceinline__ float b2f_hi(unsigned p) {        // high 16 bits
    return __builtin_bit_cast(float, p & 0xffff0000u);
}

// Bijective XCD swizzle (m204)
__device__ __forceinline__ int xcd_swz(int bid, int nwg) {
    int q = nwg >> 3, r = nwg & 7;
    int xcd = bid & 7, off = bid >> 3;
    return (xcd < r ? xcd * (q + 1) : r * (q + 1) + (xcd - r) * q) + off;
}

// ---------------------------------------------------------------------------
// Weight prep: Bt[n][k] = W_{n/OUTW}[k][n%OUTW]  (bf16, transposed + concat)
// ---------------------------------------------------------------------------
template <int K, int OUTW>
__global__ __launch_bounds__(256) void wprep(const float* __restrict__ W0,
                                             const float* __restrict__ W1,
                                             const float* __restrict__ W2,
                                             short* __restrict__ Bt) {
    const int id = blockIdx.x * 256 + threadIdx.x;
    const int nth = 3 * OUTW * (K / 8);
    if (id >= nth) return;
    const int n = id / (K / 8);
    const int kq = id % (K / 8);
    const int sel = n / OUTW;
    const int c = n % OUTW;
    const float* W = sel == 0 ? W0 : (sel == 1 ? W1 : W2);
    short v[8];
#pragma unroll
    for (int j = 0; j < 8; ++j) v[j] = f2b(W[(size_t)(kq * 8 + j) * OUTW + c]);
#pragma unroll
    for (int j = 0; j < 8; ++j) Bt[(size_t)n * K + kq * 8 + j] = v[j];
}

// ---------------------------------------------------------------------------
// MFMA GEMM: grid = ceil(M/128)*3, one column-tile of BNout per block.
// Outputs: bn 0/1 -> interleaved xlh buffer, bn 2 -> xm.
// ---------------------------------------------------------------------------
template <int K, int BNout, bool AF32>
__global__ __launch_bounds__(256) void gemm_mfma(const void* __restrict__ Avoid,
                                                 const short* __restrict__ Bt,
                                                 short* __restrict__ xlh,
                                                 short* __restrict__ xm,
                                                 int M) {
    constexpr int BM = 128, BK = 32;
    constexpr int LDK = BK + 8;                 // 40 shorts = 80 B row stride
    constexpr int FM = (BNout == 128) ? 4 : 2;
    constexpr int FN = 4;
    constexpr int WM = FM * 16;                 // 64 or 32
    __shared__ short As[BM * LDK];
    __shared__ short Bs[BNout * LDK];

    const int tid = threadIdx.x;
    const int lane = tid & 63;
    const int wid = tid >> 6;
    const int wg = xcd_swz(blockIdx.x, gridDim.x);
    const int bm = wg / 3;
    const int bn = wg % 3;
    const int m0 = bm * BM;
    const int n0 = bn * BNout;
    const int wm = (BNout == 128) ? (wid >> 1) : wid;
    const int wn = (BNout == 128) ? (wid & 1) : 0;

    f32x4 acc[FM][FN];
#pragma unroll
    for (int i = 0; i < FM; ++i)
#pragma unroll
        for (int j = 0; j < FN; ++j) acc[i][j] = (f32x4){0.f, 0.f, 0.f, 0.f};

    for (int k0 = 0; k0 < K; k0 += BK) {
        __syncthreads();
        if (AF32) {
            const float* A = (const float*)Avoid;
#pragma unroll
            for (int p = 0; p < 4; ++p) {                   // 1024 float4 / 256
                int idx = p * 256 + tid;
                int r = idx >> 3, kq = idx & 7;
                int gr = m0 + r; if (gr >= M) gr = M - 1;
                const float4 v = *reinterpret_cast<const float4*>(
                    &A[(size_t)gr * K + k0 + kq * 4]);
                unsigned p0 = (unsigned)(unsigned short)f2b(v.x) |
                              ((unsigned)(unsigned short)f2b(v.y) << 16);
                unsigned p1 = (unsigned)(unsigned short)f2b(v.z) |
                              ((unsigned)(unsigned short)f2b(v.w) << 16);
                int2 w; w.x = (int)p0; w.y = (int)p1;
                *reinterpret_cast<int2*>(&As[r * LDK + kq * 4]) = w;
            }
        } else {
            const short* A = (const short*)Avoid;
#pragma unroll
            for (int p = 0; p < 2; ++p) {                   // 512 int4 / 256
                int idx = p * 256 + tid;
                int r = idx >> 2, kq = idx & 3;
                int gr = m0 + r; if (gr >= M) gr = M - 1;
                const int4 v = *reinterpret_cast<const int4*>(
                    &A[(size_t)gr * K + k0 + kq * 8]);
                *reinterpret_cast<int4*>(&As[r * LDK + kq * 8]) = v;
            }
        }
#pragma unroll
        for (int p = 0; p < BNout / 64; ++p) {
            int idx = p * 256 + tid;
            int r = idx >> 2, kq = idx & 3;
            const int4 v = *reinterpret_cast<const int4*>(
                &Bt[(size_t)(n0 + r) * K + k0 + kq * 8]);
            *reinterpret_cast<int4*>(&Bs[r * LDK + kq * 8]) = v;
        }
        __syncthreads();

        short8v af[FM], bf[FN];
#pragma unroll
        for (int f = 0; f < FM; ++f)
            af[f] = *reinterpret_cast<const short8v*>(
                &As[(wm * WM + f * 16 + (lane & 15)) * LDK + (lane >> 4) * 8]);
#pragma unroll
        for (int f = 0; f < FN; ++f)
            bf[f] = *reinterpret_cast<const short8v*>(
                &Bs[(wn * 64 + f * 16 + (lane & 15)) * LDK + (lane >> 4) * 8]);
#pragma unroll
        for (int i = 0; i < FM; ++i)
#pragma unroll
            for (int j = 0; j < FN; ++j)
                acc[i][j] = __builtin_amdgcn_mfma_f32_16x16x32_bf16(
                    af[i], bf[j], acc[i][j], 0, 0, 0);
    }

#pragma unroll
    for (int i = 0; i < FM; ++i)
#pragma unroll
        for (int j = 0; j < FN; ++j) {
            int cc = wn * 64 + j * 16 + (lane & 15);
#pragma unroll
            for (int e = 0; e < 4; ++e) {
                int row = m0 + wm * WM + i * 16 + (lane >> 4) * 4 + e;
                if (row >= M) continue;
                short v = f2b(acc[i][j][e]);
                if (bn == 2) {
                    xm[(size_t)row * BNout + cc] = v;
                } else if (BNout == 128) {
                    xlh[(size_t)row * 256 + (cc >> 1) * 4 + bn * 2 + (cc & 1)] = v;
                } else {
                    xlh[(size_t)row * 128 + cc * 2 + bn] = v;
                }
            }
        }
}

// ---------------------------------------------------------------------------
// CSR construction
// ---------------------------------------------------------------------------
__global__ __launch_bounds__(256) void hist_kernel(const int* __restrict__ row,
                                                   int* __restrict__ counts, int E) {
    int i = blockIdx.x * 256 + threadIdx.x;
    if (i < E) atomicAdd(&counts[row[i]], 1);
}

__global__ __launch_bounds__(256) void block_sums_kernel(const int* __restrict__ counts,
                                                         int* __restrict__ bsums, int n) {
    __shared__ int s[256];
    int tid = threadIdx.x;
    int i = blockIdx.x * 256 + tid;
    s[tid] = (i < n) ? counts[i] : 0;
    __syncthreads();
#pragma unroll
    for (int off = 128; off > 0; off >>= 1) {
        if (tid < off) s[tid] += s[tid + off];
        __syncthreads();
    }
    if (tid == 0) bsums[blockIdx.x] = s[0];
}

__global__ __launch_bounds__(64) void scan_bsums_kernel(int* __restrict__ bsums, int nb) {
    if (threadIdx.x == 0) {
        int a = 0;
        for (int i = 0; i < nb; ++i) {
            int t = bsums[i];
            bsums[i] = a;
            a += t;
        }
    }
}

__global__ __launch_bounds__(256) void scan_final_kernel(const int* __restrict__ counts,
                                                         const int* __restrict__ bsums,
                                                         int* __restrict__ rowptr,
                                                         int* __restrict__ cursor, int n) {
    __shared__ int s[256];
    int tid = threadIdx.x;
    int i = blockIdx.x * 256 + tid;
    int v = (i < n) ? counts[i] : 0;
    s[tid] = v;
    __syncthreads();
#pragma unroll
    for (int off = 1; off < 256; off <<= 1) {
        int t = (tid >= off) ? s[tid - off] : 0;
        __syncthreads();
        s[tid] += t;
        __syncthreads();
    }
    int excl = s[tid] - v + bsums[blockIdx.x];
    if (i < n) {
        rowptr[i] = excl;
        cursor[i] = excl;
        if (i == n - 1) rowptr[n] = excl + v;
    }
}

__global__ __launch_bounds__(256) void scatter_edges_kernel(const int* __restrict__ row,
                                                            const int* __restrict__ col,
                                                            const float* __restrict__ val,
                                                            int* __restrict__ cursor,
                                                            int* __restrict__ cols_s,
                                                            float* __restrict__ vals_s, int E) {
    int i = blockIdx.x * 256 + threadIdx.x;
    if (i < E) {
        int r = row[i];
        int p = atomicAdd(&cursor[r], 1);
        cols_s[p] = col[i];
        vals_s[p] = val[i];
    }
}

// ---------------------------------------------------------------------------
__device__ __forceinline__ float wave_sum(float v) {
#pragma unroll
    for (int off = 32; off > 0; off >>= 1) v += __shfl_xor(v, off, 64);
    return v;
}
__device__ __forceinline__ float wave_max(float v) {
#pragma unroll
    for (int off = 32; off > 0; off >>= 1) v = fmaxf(v, __shfl_xor(v, off, 64));
    return v;
}

// ---------------------------------------------------------------------------
// Layer-1 fused: dual CSR spmm + attention + combine -> h (bf16).
// Gather pipelined 4-deep: 4 independent row loads in flight per wave.
// ---------------------------------------------------------------------------
__global__ __launch_bounds__(256) void spmm_att1(const int* __restrict__ rowptr,
                                                 const int* __restrict__ cols,
                                                 const float* __restrict__ vals,
                                                 const short* __restrict__ xlh,
                                                 const short* __restrict__ xm,
                                                 const float* __restrict__ a_low,
                                                 const float* __restrict__ a_high,
                                                 const float* __restrict__ a_mlp,
                                                 const float* __restrict__ av,
                                                 short* __restrict__ hb,
                                                 int n) {
    const int node = blockIdx.x * 4 + (threadIdx.x >> 6);
    const int lane = threadIdx.x & 63;
    if (node >= n) return;
    const uint2* XLH = (const uint2*)xlh;       // node stride 64 uint2
    const unsigned* XM = (const unsigned*)xm;

    const int s = rowptr[node];
    const int e = rowptr[node + 1];

    float l0 = 0.f, l1 = 0.f, h0 = 0.f, h1 = 0.f;
    for (int b = s; b < e; b += 64) {
        const int idx = b + lane;
        int c = 0;
        float v = 0.f;
        if (idx < e) { c = cols[idx]; v = vals[idx]; }
        const int cnt = min(64, e - b);
        for (int j = 0; j < cnt; j += 4) {
            const int j1 = min(j + 1, cnt - 1);
            const int j2 = min(j + 2, cnt - 1);
            const int j3 = min(j + 3, cnt - 1);
            const int c0 = __shfl(c, j, 64);
            const int c1 = __shfl(c, j1, 64);
            const int c2 = __shfl(c, j2, 64);
            const int c3 = __shfl(c, j3, 64);
            const float t0 = __shfl(v, j, 64);
            const float t1 = __shfl(v, j1, 64);
            const float t2 = __shfl(v, j2, 64);
            const float t3 = __shfl(v, j3, 64);
            const float v0 = t0;
            const float v1 = (j + 1 < cnt) ? t1 : 0.f;
            const float v2 = (j + 2 < cnt) ? t2 : 0.f;
            const float v3 = (j + 3 < cnt) ? t3 : 0.f;
            // 4 independent coalesced row-gathers in flight
            const uint2 p0 = XLH[(size_t)c0 * 64 + lane];
            const uint2 p1 = XLH[(size_t)c1 * 64 + lane];
            const uint2 p2 = XLH[(size_t)c2 * 64 + lane];
            const uint2 p3 = XLH[(size_t)c3 * 64 + lane];
            l0 += v0 * b2f_lo(p0.x); l1 += v0 * b2f_hi(p0.x);
            h0 += v0 * b2f_lo(p0.y); h1 += v0 * b2f_hi(p0.y);
            l0 += v1 * b2f_lo(p1.x); l1 += v1 * b2f_hi(p1.x);
            h0 += v1 * b2f_lo(p1.y); h1 += v1 * b2f_hi(p1.y);
            l0 += v2 * b2f_lo(p2.x); l1 += v2 * b2f_hi(p2.x);
            h0 += v2 * b2f_lo(p2.y); h1 += v2 * b2f_hi(p2.y);
            l0 += v3 * b2f_lo(p3.x); l1 += v3 * b2f_hi(p3.x);
            h0 += v3 * b2f_lo(p3.y); h1 += v3 * b2f_hi(p3.y);
        }
    }

    const uint2 self = XLH[(size_t)node * 64 + lane];
    const unsigned xmn = XM[(size_t)node * 64 + lane];
    float ol0 = fmaxf(l0, 0.f);
    float ol1 = fmaxf(l1, 0.f);
    float oh0 = fmaxf(b2f_lo(self.y) - h0, 0.f);
    float oh1 = fmaxf(b2f_hi(self.y) - h1, 0.f);
    float om0 = fmaxf(b2f_lo(xmn), 0.f);
    float om1 = fmaxf(b2f_hi(xmn), 0.f);

    const float2 aL = ((const float2*)a_low)[lane];
    const float2 aH = ((const float2*)a_high)[lane];
    const float2 aM = ((const float2*)a_mlp)[lane];
    float dl = wave_sum(ol0 * aL.x + ol1 * aL.y);
    float dh = wave_sum(oh0 * aH.x + oh1 * aH.y);
    float dm = wave_sum(om0 * aM.x + om1 * aM.y);

    const float g0 = 1.f / (1.f + expf(-dl));
    const float g1 = 1.f / (1.f + expf(-dh));
    const float g2 = 1.f / (1.f + expf(-dm));
    float s0 = (g0 * av[0] + g1 * av[3] + g2 * av[6]) * (1.f / 3.f);
    float s1 = (g0 * av[1] + g1 * av[4] + g2 * av[7]) * (1.f / 3.f);
    float s2 = (g0 * av[2] + g1 * av[5] + g2 * av[8]) * (1.f / 3.f);
    float mx = fmaxf(s0, fmaxf(s1, s2));
    float e0 = expf(s0 - mx), e1 = expf(s1 - mx), e2 = expf(s2 - mx);
    float inv = 1.f / (e0 + e1 + e2);
    float at0 = e0 * inv, at1 = e1 * inv, at2 = e2 * inv;

    float ho0 = 3.f * (at0 * ol0 + at1 * oh0 + at2 * om0);
    float ho1 = 3.f * (at0 * ol1 + at1 * oh1 + at2 * om1);
    unsigned pk = (unsigned)(unsigned short)f2b(ho0) |
                  ((unsigned)(unsigned short)f2b(ho1) << 16);
    ((unsigned*)hb)[(size_t)node * 64 + lane] = pk;
}

// ---------------------------------------------------------------------------
// Layer-2 fused: dual CSR spmm + attention + combine + log_softmax -> out.
// Gather pipelined 4-deep.
// ---------------------------------------------------------------------------
__global__ __launch_bounds__(256) void spmm_att2(const int* __restrict__ rowptr,
                                                 const int* __restrict__ cols,
                                                 const float* __restrict__ vals,
                                                 const short* __restrict__ xlh,
                                                 const short* __restrict__ xm,
                                                 const float* __restrict__ a_low,
                                                 const float* __restrict__ a_high,
                                                 const float* __restrict__ a_mlp,
                                                 const float* __restrict__ av,
                                                 float* __restrict__ out,
                                                 int n) {
    const int node = blockIdx.x * 4 + (threadIdx.x >> 6);
    const int lane = threadIdx.x & 63;
    if (node >= n) return;
    const unsigned* XLH = (const unsigned*)xlh; // node stride 64 u32

    const int s = rowptr[node];
    const int e = rowptr[node + 1];

    float accl = 0.f, acch = 0.f;
    for (int b = s; b < e; b += 64) {
        const int idx = b + lane;
        int c = 0;
        float v = 0.f;
        if (idx < e) { c = cols[idx]; v = vals[idx]; }
        const int cnt = min(64, e - b);
        for (int j = 0; j < cnt; j += 4) {
            const int j1 = min(j + 1, cnt - 1);
            const int j2 = min(j + 2, cnt - 1);
            const int j3 = min(j + 3, cnt - 1);
            const int c0 = __shfl(c, j, 64);
            const int c1 = __shfl(c, j1, 64);
            const int c2 = __shfl(c, j2, 64);
            const int c3 = __shfl(c, j3, 64);
            const float t0 = __shfl(v, j, 64);
            const float t1 = __shfl(v, j1, 64);
            const float t2 = __shfl(v, j2, 64);
            const float t3 = __shfl(v, j3, 64);
            const float v0 = t0;
            const float v1 = (j + 1 < cnt) ? t1 : 0.f;
            const float v2 = (j + 2 < cnt) ? t2 : 0.f;
            const float v3 = (j + 3 < cnt) ? t3 : 0.f;
            const unsigned p0 = XLH[(size_t)c0 * 64 + lane];
            const unsigned p1 = XLH[(size_t)c1 * 64 + lane];
            const unsigned p2 = XLH[(size_t)c2 * 64 + lane];
            const unsigned p3 = XLH[(size_t)c3 * 64 + lane];
            accl += v0 * b2f_lo(p0); acch += v0 * b2f_hi(p0);
            accl += v1 * b2f_lo(p1); acch += v1 * b2f_hi(p1);
            accl += v2 * b2f_lo(p2); acch += v2 * b2f_hi(p2);
            accl += v3 * b2f_lo(p3); acch += v3 * b2f_hi(p3);
        }
    }

    const unsigned self = XLH[(size_t)node * 64 + lane];
    float ol = fmaxf(accl, 0.f);
    float oh = fmaxf(b2f_hi(self) - acch, 0.f);
    float om = fmaxf(b2f(xm[(size_t)node * 64 + lane]), 0.f);

    float dl = wave_sum(ol * a_low[lane]);
    float dh = wave_sum(oh * a_high[lane]);
    float dm = wave_sum(om * a_mlp[lane]);

    const float g0 = 1.f / (1.f + expf(-dl));
    const float g1 = 1.f / (1.f + expf(-dh));
    const float g2 = 1.f / (1.f + expf(-dm));
    float s0 = (g0 * av[0] + g1 * av[3] + g2 * av[6]) * (1.f / 3.f);
    float s1 = (g0 * av[1] + g1 * av[4] + g2 * av[7]) * (1.f / 3.f);
    float s2 = (g0 * av[2] + g1 * av[5] + g2 * av[8]) * (1.f / 3.f);
    float mx3 = fmaxf(s0, fmaxf(s1, s2));
    float e0 = expf(s0 - mx3), e1 = expf(s1 - mx3), e2 = expf(s2 - mx3);
    float inv = 1.f / (e0 + e1 + e2);
    float at0 = e0 * inv, at1 = e1 * inv, at2 = e2 * inv;

    float o = 3.f * (at0 * ol + at1 * oh + at2 * om);

    float m = wave_max(o);
    float ex = expf(o - m);
    float su = wave_sum(ex);
    out[(size_t)node * 64 + lane] = o - m - logf(su);
}

// ---------------------------------------------------------------------------
extern "C" void kernel_launch(void* const* d_in, const int* in_sizes, int n_in,
                              void* d_out, int out_size, void* d_ws, size_t ws_size,
                              hipStream_t stream) {
    const float* x    = (const float*)d_in[0];
    const int*   erow = (const int*)d_in[1];
    const int*   ecol = (const int*)d_in[2];
    const float* eval = (const float*)d_in[3];
    const float* Wl   = (const float*)d_in[4];
    const float* Wh   = (const float*)d_in[5];
    const float* Wm   = (const float*)d_in[6];
    const float* al   = (const float*)d_in[7];
    const float* ah   = (const float*)d_in[8];
    const float* am   = (const float*)d_in[9];
    const float* av   = (const float*)d_in[10];
    const float* Wl2  = (const float*)d_in[11];
    const float* Wh2  = (const float*)d_in[12];
    const float* Wm2  = (const float*)d_in[13];
    const float* al2  = (const float*)d_in[14];
    const float* ah2  = (const float*)d_in[15];
    const float* am2  = (const float*)d_in[16];
    const float* av2  = (const float*)d_in[17];
    float* out = (float*)d_out;

    const int E = in_sizes[1];
    const int N = NN;

    short* xb    = (short*)d_ws;
    short* xlh1  = xb;                          // N*256 shorts (xl/xh pair-interleaved)
    short* xm1   = xb + (size_t)N * 256;        // N*128
    short* hb    = xm1 + (size_t)N * 128;       // N*128
    short* Bt1   = hb + (size_t)N * 128;        // 384*512
    short* Bt2   = Bt1 + 384 * 512;             // 192*128
    int*   ip    = (int*)(Bt2 + 192 * 128);
    int*   counts = ip;                         // N
    int*   rowptr = ip + N;                     // N+1
    int*   cursor = ip + 2 * N + 1;             // N
    int*   bsums  = ip + 3 * N + 1;             // 256
    int*   cols_s = ip + 3 * N + 1 + 256;       // E
    float* vals_s = (float*)(cols_s + E);       // E

    // Layer-2 aliases (xlh1/xm1 regions dead after spmm_att1)
    short* xlh2 = xb;                           // N*128 shorts (element-interleaved)
    short* xm2  = xb + (size_t)N * 128;         // N*64

    const int NB = (N + 255) / 256;
    const int EB = (E + 255) / 256;
    const int node_blocks = (N + 3) / 4;
    const int MT = (N + 127) / 128;

    // ---------------- CSR build + weight prep ----------------
    hipMemsetAsync(counts, 0, (size_t)N * sizeof(int), stream);
    hist_kernel<<<EB, 256, 0, stream>>>(erow, counts, E);
    block_sums_kernel<<<NB, 256, 0, stream>>>(counts, bsums, N);
    scan_bsums_kernel<<<1, 64, 0, stream>>>(bsums, NB);
    scan_final_kernel<<<NB, 256, 0, stream>>>(counts, bsums, rowptr, cursor, N);
    scatter_edges_kernel<<<EB, 256, 0, stream>>>(erow, ecol, eval, cursor, cols_s, vals_s, E);
    wprep<F_IN, HH><<<(3 * HH * (F_IN / 8) + 255) / 256, 256, 0, stream>>>(Wl, Wh, Wm, Bt1);
    wprep<HH, CC><<<(3 * CC * (HH / 8) + 255) / 256, 256, 0, stream>>>(Wl2, Wh2, Wm2, Bt2);

    // ---------------- Layer 1 ----------------
    gemm_mfma<F_IN, HH, true><<<MT * 3, 256, 0, stream>>>(x, Bt1, xlh1, xm1, N);
    spmm_att1<<<node_blocks, 256, 0, stream>>>(rowptr, cols_s, vals_s,
                                               xlh1, xm1, al, ah, am, av, hb, N);

    // ---------------- Layer 2 ----------------
    gemm_mfma<HH, CC, false><<<MT * 3, 256, 0, stream>>>(hb, Bt2, xlh2, xm2, N);
    spmm_att2<<<node_blocks, 256, 0, stream>>>(rowptr, cols_s, vals_s,
                                               xlh2, xm2, al2, ah2, am2, av2, out, N);
}

// Round 8
// 294.035 us; speedup vs baseline: 1.2924x; 1.0002x over previous
//
#include <hip/hip_runtime.h>
#include <hip/hip_bf16.h>

// Problem constants (reference file)
#define NN 50000
#define F_IN 512
#define HH 128
#define CC 64

typedef __attribute__((ext_vector_type(8))) short short8v;   // 8 bf16 (4 VGPRs)
typedef __attribute__((ext_vector_type(4))) float f32x4;     // MFMA accumulator

__device__ __forceinline__ short f2b(float f) {
    unsigned u = __builtin_bit_cast(unsigned, f);
    unsigned r = (u + 0x7fffu + ((u >> 16) & 1u)) >> 16;     // RNE
    return (short)r;
}
__device__ __forceinline__ float b2f(short s) {
    unsigned u = ((unsigned)(unsigned short)s) << 16;
    return __builtin_bit_cast(float, u);
}
__device__ __forceinline__ float b2f_lo(unsigned p) {        // low 16 bits
    return __builtin_bit_cast(float, p << 16);
}
__device__ __forceinline__ float b2f_hi(unsigned p) {        // high 16 bits
    return __builtin_bit_cast(float, p & 0xffff0000u);
}

// Bijective XCD swizzle (m204)
__device__ __forceinline__ int xcd_swz(int bid, int nwg) {
    int q = nwg >> 3, r = nwg & 7;
    int xcd = bid & 7, off = bid >> 3;
    return (xcd < r ? xcd * (q + 1) : r * (q + 1) + (xcd - r) * q) + off;
}

// async global->LDS, 16 B per lane; LDS dest = (wave-uniform base) + lane*16
__device__ __forceinline__ void load_lds16(const short* g, short* l) {
    __builtin_amdgcn_global_load_lds(
        (const __attribute__((address_space(1))) unsigned int*)g,
        (__attribute__((address_space(3))) unsigned int*)l,
        16, 0, 0);
}

// ---------------------------------------------------------------------------
// x f32 -> bf16 streaming conversion (one-time)
// ---------------------------------------------------------------------------
__global__ __launch_bounds__(256) void xconv(const float* __restrict__ x,
                                             short* __restrict__ xb, int n8) {
    int i = blockIdx.x * 256 + threadIdx.x;
    if (i >= n8) return;
    const float4* xp = (const float4*)x;
    const float4 a = xp[2 * i];
    const float4 b = xp[2 * i + 1];
    short8v o;
    o[0] = f2b(a.x); o[1] = f2b(a.y); o[2] = f2b(a.z); o[3] = f2b(a.w);
    o[4] = f2b(b.x); o[5] = f2b(b.y); o[6] = f2b(b.z); o[7] = f2b(b.w);
    *reinterpret_cast<short8v*>(&xb[(size_t)i * 8]) = o;
}

// ---------------------------------------------------------------------------
// Weight prep: Bt[n][k] = W_{n/OUTW}[k][n%OUTW]  (bf16, transposed + concat)
// ---------------------------------------------------------------------------
template <int K, int OUTW>
__global__ __launch_bounds__(256) void wprep(const float* __restrict__ W0,
                                             const float* __restrict__ W1,
                                             const float* __restrict__ W2,
                                             short* __restrict__ Bt) {
    const int id = blockIdx.x * 256 + threadIdx.x;
    const int nth = 3 * OUTW * (K / 8);
    if (id >= nth) return;
    const int n = id / (K / 8);
    const int kq = id % (K / 8);
    const int sel = n / OUTW;
    const int c = n % OUTW;
    const float* W = sel == 0 ? W0 : (sel == 1 ? W1 : W2);
    short v[8];
#pragma unroll
    for (int j = 0; j < 8; ++j) v[j] = f2b(W[(size_t)(kq * 8 + j) * OUTW + c]);
#pragma unroll
    for (int j = 0; j < 8; ++j) Bt[(size_t)n * K + kq * 8 + j] = v[j];
}

// ---------------------------------------------------------------------------
// MFMA GEMM with global_load_lds staging + XOR slot swizzle.
// grid = ceil(M/128)*3; one 128-row x BNout-col tile per block; BK=64.
// LDS layout: row r (64 shorts = 8 slots of 16B); phys slot p holds logical
// slot s = p ^ (r&7)  (source pre-swizzled; gll dest linear; read swizzled).
// Outputs: bn 0/1 -> interleaved xlh, bn 2 -> xm.
// ---------------------------------------------------------------------------
template <int K, int BNout>
__global__ __launch_bounds__(256) void gemm_mfma(const short* __restrict__ A,
                                                 const short* __restrict__ Bt,
                                                 short* __restrict__ xlh,
                                                 short* __restrict__ xm,
                                                 int M) {
    constexpr int BM = 128, BK = 64;
    constexpr int FM = (BNout == 128) ? 4 : 2;
    constexpr int FN = 4;
    constexpr int WM = FM * 16;                 // 64 or 32
    constexpr int NKT = K / BK;
    constexpr int NBL = BNout / 32;             // B wave-loads per wave (4 or 2)

    __shared__ short As[BM * BK];               // 16 KB
    __shared__ short Bs[BNout * BK];            // 16 or 8 KB

    const int tid = threadIdx.x;
    const int lane = tid & 63;
    const int wid = tid >> 6;
    const int wg = xcd_swz(blockIdx.x, gridDim.x);
    const int bm = wg / 3;
    const int bn = wg % 3;
    const int m0 = bm * BM;
    const int n0 = bn * BNout;
    const int wm = (BNout == 128) ? (wid >> 1) : wid;
    const int wn = (BNout == 128) ? (wid & 1) : 0;

    const int r8 = lane >> 3;                   // row-within-8 (== r&7)
    const int sl = (lane & 7) ^ r8;             // logical k-slot this lane fetches

    f32x4 acc[FM][FN];
#pragma unroll
    for (int i = 0; i < FM; ++i)
#pragma unroll
        for (int j = 0; j < FN; ++j) acc[i][j] = (f32x4){0.f, 0.f, 0.f, 0.f};

    for (int kt = 0; kt < NKT; ++kt) {
        const int k0 = kt * BK;
        __syncthreads();                        // prior compute done reading LDS
        // ---- A tile: 16 wave-loads (4/wave), 1024 B each ----
#pragma unroll
        for (int i = 0; i < 4; ++i) {
            int r = (wid * 4 + i) * 8 + r8;
            int gr = m0 + r; if (gr >= M) gr = M - 1;
            load_lds16(&A[(size_t)gr * K + k0 + sl * 8], &As[(wid * 4 + i) * 512]);
        }
        // ---- B tile ----
#pragma unroll
        for (int i = 0; i < NBL; ++i) {
            int r = (wid * NBL + i) * 8 + r8;
            load_lds16(&Bt[(size_t)(n0 + r) * K + k0 + sl * 8],
                       &Bs[(wid * NBL + i) * 512]);
        }
        __syncthreads();                        // compiler drains vmcnt before barrier

        const int mrow = lane & 15;
        const int kg = lane >> 4;               // 0..3
#pragma unroll
        for (int kk = 0; kk < 2; ++kk) {
            short8v af[FM], bf[FN];
#pragma unroll
            for (int f = 0; f < FM; ++f) {
                int m = wm * WM + f * 16 + mrow;
                int s = kk * 4 + kg;
                af[f] = *reinterpret_cast<const short8v*>(
                    &As[m * 64 + ((s ^ (m & 7)) << 3)]);
            }
#pragma unroll
            for (int f = 0; f < FN; ++f) {
                int nr = wn * 64 + f * 16 + mrow;
                int s = kk * 4 + kg;
                bf[f] = *reinterpret_cast<const short8v*>(
                    &Bs[nr * 64 + ((s ^ (nr & 7)) << 3)]);
            }
#pragma unroll
            for (int i = 0; i < FM; ++i)
#pragma unroll
                for (int j = 0; j < FN; ++j)
                    acc[i][j] = __builtin_amdgcn_mfma_f32_16x16x32_bf16(
                        af[i], bf[j], acc[i][j], 0, 0, 0);
        }
    }

    // ---- store (interleaved for bn 0/1, plain for bn 2) ----
#pragma unroll
    for (int i = 0; i < FM; ++i)
#pragma unroll
        for (int j = 0; j < FN; ++j) {
            int cc = wn * 64 + j * 16 + (lane & 15);
#pragma unroll
            for (int e = 0; e < 4; ++e) {
                int row = m0 + wm * WM + i * 16 + (lane >> 4) * 4 + e;
                if (row >= M) continue;
                short v = f2b(acc[i][j][e]);
                if (bn == 2) {
                    xm[(size_t)row * BNout + cc] = v;
                } else if (BNout == 128) {
                    xlh[(size_t)row * 256 + (cc >> 1) * 4 + bn * 2 + (cc & 1)] = v;
                } else {
                    xlh[(size_t)row * 128 + cc * 2 + bn] = v;
                }
            }
        }
}

// ---------------------------------------------------------------------------
// CSR construction
// ---------------------------------------------------------------------------
__global__ __launch_bounds__(256) void hist_kernel(const int* __restrict__ row,
                                                   int* __restrict__ counts, int E) {
    int i = blockIdx.x * 256 + threadIdx.x;
    if (i < E) atomicAdd(&counts[row[i]], 1);
}

__global__ __launch_bounds__(256) void block_sums_kernel(const int* __restrict__ counts,
                                                         int* __restrict__ bsums, int n) {
    __shared__ int s[256];
    int tid = threadIdx.x;
    int i = blockIdx.x * 256 + tid;
    s[tid] = (i < n) ? counts[i] : 0;
    __syncthreads();
#pragma unroll
    for (int off = 128; off > 0; off >>= 1) {
        if (tid < off) s[tid] += s[tid + off];
        __syncthreads();
    }
    if (tid == 0) bsums[blockIdx.x] = s[0];
}

__global__ __launch_bounds__(64) void scan_bsums_kernel(int* __restrict__ bsums, int nb) {
    if (threadIdx.x == 0) {
        int a = 0;
        for (int i = 0; i < nb; ++i) {
            int t = bsums[i];
            bsums[i] = a;
            a += t;
        }
    }
}

__global__ __launch_bounds__(256) void scan_final_kernel(const int* __restrict__ counts,
                                                         const int* __restrict__ bsums,
                                                         int* __restrict__ rowptr,
                                                         int* __restrict__ cursor, int n) {
    __shared__ int s[256];
    int tid = threadIdx.x;
    int i = blockIdx.x * 256 + tid;
    int v = (i < n) ? counts[i] : 0;
    s[tid] = v;
    __syncthreads();
#pragma unroll
    for (int off = 1; off < 256; off <<= 1) {
        int t = (tid >= off) ? s[tid - off] : 0;
        __syncthreads();
        s[tid] += t;
        __syncthreads();
    }
    int excl = s[tid] - v + bsums[blockIdx.x];
    if (i < n) {
        rowptr[i] = excl;
        cursor[i] = excl;
        if (i == n - 1) rowptr[n] = excl + v;
    }
}

__global__ __launch_bounds__(256) void scatter_edges_kernel(const int* __restrict__ row,
                                                            const int* __restrict__ col,
                                                            const float* __restrict__ val,
                                                            int* __restrict__ cursor,
                                                            int* __restrict__ cols_s,
                                                            float* __restrict__ vals_s, int E) {
    int i = blockIdx.x * 256 + threadIdx.x;
    if (i < E) {
        int r = row[i];
        int p = atomicAdd(&cursor[r], 1);
        cols_s[p] = col[i];
        vals_s[p] = val[i];
    }
}

// ---------------------------------------------------------------------------
__device__ __forceinline__ float wave_sum(float v) {
#pragma unroll
    for (int off = 32; off > 0; off >>= 1) v += __shfl_xor(v, off, 64);
    return v;
}
__device__ __forceinline__ float wave_max(float v) {
#pragma unroll
    for (int off = 32; off > 0; off >>= 1) v = fmaxf(v, __shfl_xor(v, off, 64));
    return v;
}

// ---------------------------------------------------------------------------
// Layer-1 fused: dual CSR spmm + attention + combine -> h (bf16).
// Gather pipelined 4-deep.
// ---------------------------------------------------------------------------
__global__ __launch_bounds__(256) void spmm_att1(const int* __restrict__ rowptr,
                                                 const int* __restrict__ cols,
                                                 const float* __restrict__ vals,
                                                 const short* __restrict__ xlh,
                                                 const short* __restrict__ xm,
                                                 const float* __restrict__ a_low,
                                                 const float* __restrict__ a_high,
                                                 const float* __restrict__ a_mlp,
                                                 const float* __restrict__ av,
                                                 short* __restrict__ hb,
                                                 int n) {
    const int node = blockIdx.x * 4 + (threadIdx.x >> 6);
    const int lane = threadIdx.x & 63;
    if (node >= n) return;
    const uint2* XLH = (const uint2*)xlh;       // node stride 64 uint2
    const unsigned* XM = (const unsigned*)xm;

    const int s = rowptr[node];
    const int e = rowptr[node + 1];

    float l0 = 0.f, l1 = 0.f, h0 = 0.f, h1 = 0.f;
    for (int b = s; b < e; b += 64) {
        const int idx = b + lane;
        int c = 0;
        float v = 0.f;
        if (idx < e) { c = cols[idx]; v = vals[idx]; }
        const int cnt = min(64, e - b);
        for (int j = 0; j < cnt; j += 4) {
            const int j1 = min(j + 1, cnt - 1);
            const int j2 = min(j + 2, cnt - 1);
            const int j3 = min(j + 3, cnt - 1);
            const int c0 = __shfl(c, j, 64);
            const int c1 = __shfl(c, j1, 64);
            const int c2 = __shfl(c, j2, 64);
            const int c3 = __shfl(c, j3, 64);
            const float t0 = __shfl(v, j, 64);
            const float t1 = __shfl(v, j1, 64);
            const float t2 = __shfl(v, j2, 64);
            const float t3 = __shfl(v, j3, 64);
            const float v0 = t0;
            const float v1 = (j + 1 < cnt) ? t1 : 0.f;
            const float v2 = (j + 2 < cnt) ? t2 : 0.f;
            const float v3 = (j + 3 < cnt) ? t3 : 0.f;
            const uint2 p0 = XLH[(size_t)c0 * 64 + lane];
            const uint2 p1 = XLH[(size_t)c1 * 64 + lane];
            const uint2 p2 = XLH[(size_t)c2 * 64 + lane];
            const uint2 p3 = XLH[(size_t)c3 * 64 + lane];
            l0 += v0 * b2f_lo(p0.x); l1 += v0 * b2f_hi(p0.x);
            h0 += v0 * b2f_lo(p0.y); h1 += v0 * b2f_hi(p0.y);
            l0 += v1 * b2f_lo(p1.x); l1 += v1 * b2f_hi(p1.x);
            h0 += v1 * b2f_lo(p1.y); h1 += v1 * b2f_hi(p1.y);
            l0 += v2 * b2f_lo(p2.x); l1 += v2 * b2f_hi(p2.x);
            h0 += v2 * b2f_lo(p2.y); h1 += v2 * b2f_hi(p2.y);
            l0 += v3 * b2f_lo(p3.x); l1 += v3 * b2f_hi(p3.x);
            h0 += v3 * b2f_lo(p3.y); h1 += v3 * b2f_hi(p3.y);
        }
    }

    const uint2 self = XLH[(size_t)node * 64 + lane];
    const unsigned xmn = XM[(size_t)node * 64 + lane];
    float ol0 = fmaxf(l0, 0.f);
    float ol1 = fmaxf(l1, 0.f);
    float oh0 = fmaxf(b2f_lo(self.y) - h0, 0.f);
    float oh1 = fmaxf(b2f_hi(self.y) - h1, 0.f);
    float om0 = fmaxf(b2f_lo(xmn), 0.f);
    float om1 = fmaxf(b2f_hi(xmn), 0.f);

    const float2 aL = ((const float2*)a_low)[lane];
    const float2 aH = ((const float2*)a_high)[lane];
    const float2 aM = ((const float2*)a_mlp)[lane];
    float dl = wave_sum(ol0 * aL.x + ol1 * aL.y);
    float dh = wave_sum(oh0 * aH.x + oh1 * aH.y);
    float dm = wave_sum(om0 * aM.x + om1 * aM.y);

    const float g0 = 1.f / (1.f + expf(-dl));
    const float g1 = 1.f / (1.f + expf(-dh));
    const float g2 = 1.f / (1.f + expf(-dm));
    float s0 = (g0 * av[0] + g1 * av[3] + g2 * av[6]) * (1.f / 3.f);
    float s1 = (g0 * av[1] + g1 * av[4] + g2 * av[7]) * (1.f / 3.f);
    float s2 = (g0 * av[2] + g1 * av[5] + g2 * av[8]) * (1.f / 3.f);
    float mx = fmaxf(s0, fmaxf(s1, s2));
    float e0 = expf(s0 - mx), e1 = expf(s1 - mx), e2 = expf(s2 - mx);
    float inv = 1.f / (e0 + e1 + e2);
    float at0 = e0 * inv, at1 = e1 * inv, at2 = e2 * inv;

    float ho0 = 3.f * (at0 * ol0 + at1 * oh0 + at2 * om0);
    float ho1 = 3.f * (at0 * ol1 + at1 * oh1 + at2 * om1);
    unsigned pk = (unsigned)(unsigned short)f2b(ho0) |
                  ((unsigned)(unsigned short)f2b(ho1) << 16);
    ((unsigned*)hb)[(size_t)node * 64 + lane] = pk;
}

// ---------------------------------------------------------------------------
// Layer-2 fused: dual CSR spmm + attention + combine + log_softmax -> out.
// ---------------------------------------------------------------------------
__global__ __launch_bounds__(256) void spmm_att2(const int* __restrict__ rowptr,
                                                 const int* __restrict__ cols,
                                                 const float* __restrict__ vals,
                                                 const short* __restrict__ xlh,
                                                 const short* __restrict__ xm,
                                                 const float* __restrict__ a_low,
                                                 const float* __restrict__ a_high,
                                                 const float* __restrict__ a_mlp,
                                                 const float* __restrict__ av,
                                                 float* __restrict__ out,
                                                 int n) {
    const int node = blockIdx.x * 4 + (threadIdx.x >> 6);
    const int lane = threadIdx.x & 63;
    if (node >= n) return;
    const unsigned* XLH = (const unsigned*)xlh; // node stride 64 u32

    const int s = rowptr[node];
    const int e = rowptr[node + 1];

    float accl = 0.f, acch = 0.f;
    for (int b = s; b < e; b += 64) {
        const int idx = b + lane;
        int c = 0;
        float v = 0.f;
        if (idx < e) { c = cols[idx]; v = vals[idx]; }
        const int cnt = min(64, e - b);
        for (int j = 0; j < cnt; j += 4) {
            const int j1 = min(j + 1, cnt - 1);
            const int j2 = min(j + 2, cnt - 1);
            const int j3 = min(j + 3, cnt - 1);
            const int c0 = __shfl(c, j, 64);
            const int c1 = __shfl(c, j1, 64);
            const int c2 = __shfl(c, j2, 64);
            const int c3 = __shfl(c, j3, 64);
            const float t0 = __shfl(v, j, 64);
            const float t1 = __shfl(v, j1, 64);
            const float t2 = __shfl(v, j2, 64);
            const float t3 = __shfl(v, j3, 64);
            const float v0 = t0;
            const float v1 = (j + 1 < cnt) ? t1 : 0.f;
            const float v2 = (j + 2 < cnt) ? t2 : 0.f;
            const float v3 = (j + 3 < cnt) ? t3 : 0.f;
            const unsigned p0 = XLH[(size_t)c0 * 64 + lane];
            const unsigned p1 = XLH[(size_t)c1 * 64 + lane];
            const unsigned p2 = XLH[(size_t)c2 * 64 + lane];
            const unsigned p3 = XLH[(size_t)c3 * 64 + lane];
            accl += v0 * b2f_lo(p0); acch += v0 * b2f_hi(p0);
            accl += v1 * b2f_lo(p1); acch += v1 * b2f_hi(p1);
            accl += v2 * b2f_lo(p2); acch += v2 * b2f_hi(p2);
            accl += v3 * b2f_lo(p3); acch += v3 * b2f_hi(p3);
        }
    }

    const unsigned self = XLH[(size_t)node * 64 + lane];
    float ol = fmaxf(accl, 0.f);
    float oh = fmaxf(b2f_hi(self) - acch, 0.f);
    float om = fmaxf(b2f(xm[(size_t)node * 64 + lane]), 0.f);

    float dl = wave_sum(ol * a_low[lane]);
    float dh = wave_sum(oh * a_high[lane]);
    float dm = wave_sum(om * a_mlp[lane]);

    const float g0 = 1.f / (1.f + expf(-dl));
    const float g1 = 1.f / (1.f + expf(-dh));
    const float g2 = 1.f / (1.f + expf(-dm));
    float s0 = (g0 * av[0] + g1 * av[3] + g2 * av[6]) * (1.f / 3.f);
    float s1 = (g0 * av[1] + g1 * av[4] + g2 * av[7]) * (1.f / 3.f);
    float s2 = (g0 * av[2] + g1 * av[5] + g2 * av[8]) * (1.f / 3.f);
    float mx3 = fmaxf(s0, fmaxf(s1, s2));
    float e0 = expf(s0 - mx3), e1 = expf(s1 - mx3), e2 = expf(s2 - mx3);
    float inv = 1.f / (e0 + e1 + e2);
    float at0 = e0 * inv, at1 = e1 * inv, at2 = e2 * inv;

    float o = 3.f * (at0 * ol + at1 * oh + at2 * om);

    float m = wave_max(o);
    float ex = expf(o - m);
    float su = wave_sum(ex);
    out[(size_t)node * 64 + lane] = o - m - logf(su);
}

// ---------------------------------------------------------------------------
extern "C" void kernel_launch(void* const* d_in, const int* in_sizes, int n_in,
                              void* d_out, int out_size, void* d_ws, size_t ws_size,
                              hipStream_t stream) {
    const float* x    = (const float*)d_in[0];
    const int*   erow = (const int*)d_in[1];
    const int*   ecol = (const int*)d_in[2];
    const float* eval = (const float*)d_in[3];
    const float* Wl   = (const float*)d_in[4];
    const float* Wh   = (const float*)d_in[5];
    const float* Wm   = (const float*)d_in[6];
    const float* al   = (const float*)d_in[7];
    const float* ah   = (const float*)d_in[8];
    const float* am   = (const float*)d_in[9];
    const float* av   = (const float*)d_in[10];
    const float* Wl2  = (const float*)d_in[11];
    const float* Wh2  = (const float*)d_in[12];
    const float* Wm2  = (const float*)d_in[13];
    const float* al2  = (const float*)d_in[14];
    const float* ah2  = (const float*)d_in[15];
    const float* am2  = (const float*)d_in[16];
    const float* av2  = (const float*)d_in[17];
    float* out = (float*)d_out;

    const int E = in_sizes[1];
    const int N = NN;

    short* ws    = (short*)d_ws;
    short* xb    = ws;                          // N*512 bf16 (converted x)
    short* xlh1  = xb + (size_t)N * 512;        // N*256 (xl/xh pair-interleaved)
    short* xm1   = xlh1 + (size_t)N * 256;      // N*128
    short* hb    = xm1 + (size_t)N * 128;       // N*128
    short* Bt1   = hb + (size_t)N * 128;        // 384*512
    short* Bt2   = Bt1 + 384 * 512;             // 192*128
    int*   ip    = (int*)(Bt2 + 192 * 128);
    int*   counts = ip;                         // N
    int*   rowptr = ip + N;                     // N+1
    int*   cursor = ip + 2 * N + 1;             // N
    int*   bsums  = ip + 3 * N + 1;             // 256
    int*   cols_s = ip + 3 * N + 1 + 256;       // E
    float* vals_s = (float*)(cols_s + E);       // E

    // Layer-2 aliases (xlh1/xm1 regions dead after spmm_att1)
    short* xlh2 = xlh1;                         // N*128 (element-interleaved)
    short* xm2  = xlh1 + (size_t)N * 128;       // N*64

    const int NB = (N + 255) / 256;
    const int EB = (E + 255) / 256;
    const int node_blocks = (N + 3) / 4;
    const int MT = (N + 127) / 128;
    const int XCB = (N * F_IN / 8 + 255) / 256;

    // ---------------- conversion + CSR build + weight prep ----------------
    xconv<<<XCB, 256, 0, stream>>>(x, xb, N * F_IN / 8);
    hipMemsetAsync(counts, 0, (size_t)N * sizeof(int), stream);
    hist_kernel<<<EB, 256, 0, stream>>>(erow, counts, E);
    block_sums_kernel<<<NB, 256, 0, stream>>>(counts, bsums, N);
    scan_bsums_kernel<<<1, 64, 0, stream>>>(bsums, NB);
    scan_final_kernel<<<NB, 256, 0, stream>>>(counts, bsums, rowptr, cursor, N);
    scatter_edges_kernel<<<EB, 256, 0, stream>>>(erow, ecol, eval, cursor, cols_s, vals_s, E);
    wprep<F_IN, HH><<<(3 * HH * (F_IN / 8) + 255) / 256, 256, 0, stream>>>(Wl, Wh, Wm, Bt1);
    wprep<HH, CC><<<(3 * CC * (HH / 8) + 255) / 256, 256, 0, stream>>>(Wl2, Wh2, Wm2, Bt2);

    // ---------------- Layer 1 ----------------
    gemm_mfma<F_IN, HH><<<MT * 3, 256, 0, stream>>>(xb, Bt1, xlh1, xm1, N);
    spmm_att1<<<node_blocks, 256, 0, stream>>>(rowptr, cols_s, vals_s,
                                               xlh1, xm1, al, ah, am, av, hb, N);

    // ---------------- Layer 2 ----------------
    gemm_mfma<HH, CC><<<MT * 3, 256, 0, stream>>>(hb, Bt2, xlh2, xm2, N);
    spmm_att2<<<node_blocks, 256, 0, stream>>>(rowptr, cols_s, vals_s,
                                               xlh2, xm2, al2, ah2, am2, av2, out, N);
}

// Round 9
// 289.286 us; speedup vs baseline: 1.3137x; 1.0164x over previous
//
#include <hip/hip_runtime.h>
#include <hip/hip_bf16.h>

// Problem constants (reference file)
#define NN 50000
#define F_IN 512
#define HH 128
#define CC 64

typedef __attribute__((ext_vector_type(8))) short short8v;   // 8 bf16 (4 VGPRs)
typedef __attribute__((ext_vector_type(4))) float f32x4;     // MFMA accumulator

__device__ __forceinline__ short f2b(float f) {
    unsigned u = __builtin_bit_cast(unsigned, f);
    unsigned r = (u + 0x7fffu + ((u >> 16) & 1u)) >> 16;     // RNE
    return (short)r;
}
__device__ __forceinline__ float b2f(short s) {
    unsigned u = ((unsigned)(unsigned short)s) << 16;
    return __builtin_bit_cast(float, u);
}
__device__ __forceinline__ float b2f_lo(unsigned p) {        // low 16 bits
    return __builtin_bit_cast(float, p << 16);
}
__device__ __forceinline__ float b2f_hi(unsigned p) {        // high 16 bits
    return __builtin_bit_cast(float, p & 0xffff0000u);
}

// wave-uniform scalar load helpers (force SGPR via readfirstlane)
__device__ __forceinline__ int rfl_i(const int* __restrict__ p) {
    return __builtin_amdgcn_readfirstlane(*p);
}
__device__ __forceinline__ float rfl_f(const float* __restrict__ p) {
    int v = __builtin_amdgcn_readfirstlane(__builtin_bit_cast(int, *p));
    return __builtin_bit_cast(float, v);
}

// Bijective XCD swizzle (m204)
__device__ __forceinline__ int xcd_swz(int bid, int nwg) {
    int q = nwg >> 3, r = nwg & 7;
    int xcd = bid & 7, off = bid >> 3;
    return (xcd < r ? xcd * (q + 1) : r * (q + 1) + (xcd - r) * q) + off;
}

// async global->LDS, 16 B per lane; LDS dest = (wave-uniform base) + lane*16
__device__ __forceinline__ void load_lds16(const short* g, short* l) {
    __builtin_amdgcn_global_load_lds(
        (const __attribute__((address_space(1))) unsigned int*)g,
        (__attribute__((address_space(3))) unsigned int*)l,
        16, 0, 0);
}

// ---------------------------------------------------------------------------
// x f32 -> bf16 streaming conversion (one-time)
// ---------------------------------------------------------------------------
__global__ __launch_bounds__(256) void xconv(const float* __restrict__ x,
                                             short* __restrict__ xb, int n8) {
    int i = blockIdx.x * 256 + threadIdx.x;
    if (i >= n8) return;
    const float4* xp = (const float4*)x;
    const float4 a = xp[2 * i];
    const float4 b = xp[2 * i + 1];
    short8v o;
    o[0] = f2b(a.x); o[1] = f2b(a.y); o[2] = f2b(a.z); o[3] = f2b(a.w);
    o[4] = f2b(b.x); o[5] = f2b(b.y); o[6] = f2b(b.z); o[7] = f2b(b.w);
    *reinterpret_cast<short8v*>(&xb[(size_t)i * 8]) = o;
}

// ---------------------------------------------------------------------------
// Weight prep: Bt[n][k] = W_{n/OUTW}[k][n%OUTW]  (bf16, transposed + concat)
// ---------------------------------------------------------------------------
template <int K, int OUTW>
__global__ __launch_bounds__(256) void wprep(const float* __restrict__ W0,
                                             const float* __restrict__ W1,
                                             const float* __restrict__ W2,
                                             short* __restrict__ Bt) {
    const int id = blockIdx.x * 256 + threadIdx.x;
    const int nth = 3 * OUTW * (K / 8);
    if (id >= nth) return;
    const int n = id / (K / 8);
    const int kq = id % (K / 8);
    const int sel = n / OUTW;
    const int c = n % OUTW;
    const float* W = sel == 0 ? W0 : (sel == 1 ? W1 : W2);
    short v[8];
#pragma unroll
    for (int j = 0; j < 8; ++j) v[j] = f2b(W[(size_t)(kq * 8 + j) * OUTW + c]);
#pragma unroll
    for (int j = 0; j < 8; ++j) Bt[(size_t)n * K + kq * 8 + j] = v[j];
}

// ---------------------------------------------------------------------------
// MFMA GEMM with global_load_lds staging + XOR slot swizzle (r8 structure).
// ---------------------------------------------------------------------------
template <int K, int BNout>
__global__ __launch_bounds__(256) void gemm_mfma(const short* __restrict__ A,
                                                 const short* __restrict__ Bt,
                                                 short* __restrict__ xlh,
                                                 short* __restrict__ xm,
                                                 int M) {
    constexpr int BM = 128, BK = 64;
    constexpr int FM = (BNout == 128) ? 4 : 2;
    constexpr int FN = 4;
    constexpr int WM = FM * 16;                 // 64 or 32
    constexpr int NKT = K / BK;
    constexpr int NBL = BNout / 32;             // B wave-loads per wave (4 or 2)

    __shared__ short As[BM * BK];               // 16 KB
    __shared__ short Bs[BNout * BK];            // 16 or 8 KB

    const int tid = threadIdx.x;
    const int lane = tid & 63;
    const int wid = tid >> 6;
    const int wg = xcd_swz(blockIdx.x, gridDim.x);
    const int bm = wg / 3;
    const int bn = wg % 3;
    const int m0 = bm * BM;
    const int n0 = bn * BNout;
    const int wm = (BNout == 128) ? (wid >> 1) : wid;
    const int wn = (BNout == 128) ? (wid & 1) : 0;

    const int r8 = lane >> 3;                   // row-within-8 (== r&7)
    const int sl = (lane & 7) ^ r8;             // logical k-slot this lane fetches

    f32x4 acc[FM][FN];
#pragma unroll
    for (int i = 0; i < FM; ++i)
#pragma unroll
        for (int j = 0; j < FN; ++j) acc[i][j] = (f32x4){0.f, 0.f, 0.f, 0.f};

    for (int kt = 0; kt < NKT; ++kt) {
        const int k0 = kt * BK;
        __syncthreads();                        // prior compute done reading LDS
#pragma unroll
        for (int i = 0; i < 4; ++i) {
            int r = (wid * 4 + i) * 8 + r8;
            int gr = m0 + r; if (gr >= M) gr = M - 1;
            load_lds16(&A[(size_t)gr * K + k0 + sl * 8], &As[(wid * 4 + i) * 512]);
        }
#pragma unroll
        for (int i = 0; i < NBL; ++i) {
            int r = (wid * NBL + i) * 8 + r8;
            load_lds16(&Bt[(size_t)(n0 + r) * K + k0 + sl * 8],
                       &Bs[(wid * NBL + i) * 512]);
        }
        __syncthreads();                        // compiler drains vmcnt before barrier

        const int mrow = lane & 15;
        const int kg = lane >> 4;               // 0..3
#pragma unroll
        for (int kk = 0; kk < 2; ++kk) {
            short8v af[FM], bf[FN];
#pragma unroll
            for (int f = 0; f < FM; ++f) {
                int m = wm * WM + f * 16 + mrow;
                int s = kk * 4 + kg;
                af[f] = *reinterpret_cast<const short8v*>(
                    &As[m * 64 + ((s ^ (m & 7)) << 3)]);
            }
#pragma unroll
            for (int f = 0; f < FN; ++f) {
                int nr = wn * 64 + f * 16 + mrow;
                int s = kk * 4 + kg;
                bf[f] = *reinterpret_cast<const short8v*>(
                    &Bs[nr * 64 + ((s ^ (nr & 7)) << 3)]);
            }
#pragma unroll
            for (int i = 0; i < FM; ++i)
#pragma unroll
                for (int j = 0; j < FN; ++j)
                    acc[i][j] = __builtin_amdgcn_mfma_f32_16x16x32_bf16(
                        af[i], bf[j], acc[i][j], 0, 0, 0);
        }
    }

#pragma unroll
    for (int i = 0; i < FM; ++i)
#pragma unroll
        for (int j = 0; j < FN; ++j) {
            int cc = wn * 64 + j * 16 + (lane & 15);
#pragma unroll
            for (int e = 0; e < 4; ++e) {
                int row = m0 + wm * WM + i * 16 + (lane >> 4) * 4 + e;
                if (row >= M) continue;
                short v = f2b(acc[i][j][e]);
                if (bn == 2) {
                    xm[(size_t)row * BNout + cc] = v;
                } else if (BNout == 128) {
                    xlh[(size_t)row * 256 + (cc >> 1) * 4 + bn * 2 + (cc & 1)] = v;
                } else {
                    xlh[(size_t)row * 128 + cc * 2 + bn] = v;
                }
            }
        }
}

// ---------------------------------------------------------------------------
// CSR construction
// ---------------------------------------------------------------------------
__global__ __launch_bounds__(256) void hist_kernel(const int* __restrict__ row,
                                                   int* __restrict__ counts, int E) {
    int i = blockIdx.x * 256 + threadIdx.x;
    if (i < E) atomicAdd(&counts[row[i]], 1);
}

__global__ __launch_bounds__(256) void block_sums_kernel(const int* __restrict__ counts,
                                                         int* __restrict__ bsums, int n) {
    __shared__ int s[256];
    int tid = threadIdx.x;
    int i = blockIdx.x * 256 + tid;
    s[tid] = (i < n) ? counts[i] : 0;
    __syncthreads();
#pragma unroll
    for (int off = 128; off > 0; off >>= 1) {
        if (tid < off) s[tid] += s[tid + off];
        __syncthreads();
    }
    if (tid == 0) bsums[blockIdx.x] = s[0];
}

__global__ __launch_bounds__(64) void scan_bsums_kernel(int* __restrict__ bsums, int nb) {
    if (threadIdx.x == 0) {
        int a = 0;
        for (int i = 0; i < nb; ++i) {
            int t = bsums[i];
            bsums[i] = a;
            a += t;
        }
    }
}

__global__ __launch_bounds__(256) void scan_final_kernel(const int* __restrict__ counts,
                                                         const int* __restrict__ bsums,
                                                         int* __restrict__ rowptr,
                                                         int* __restrict__ cursor, int n) {
    __shared__ int s[256];
    int tid = threadIdx.x;
    int i = blockIdx.x * 256 + tid;
    int v = (i < n) ? counts[i] : 0;
    s[tid] = v;
    __syncthreads();
#pragma unroll
    for (int off = 1; off < 256; off <<= 1) {
        int t = (tid >= off) ? s[tid - off] : 0;
        __syncthreads();
        s[tid] += t;
        __syncthreads();
    }
    int excl = s[tid] - v + bsums[blockIdx.x];
    if (i < n) {
        rowptr[i] = excl;
        cursor[i] = excl;
        if (i == n - 1) rowptr[n] = excl + v;
    }
}

__global__ __launch_bounds__(256) void scatter_edges_kernel(const int* __restrict__ row,
                                                            const int* __restrict__ col,
                                                            const float* __restrict__ val,
                                                            int* __restrict__ cursor,
                                                            int* __restrict__ cols_s,
                                                            float* __restrict__ vals_s, int E) {
    int i = blockIdx.x * 256 + threadIdx.x;
    if (i < E) {
        int r = row[i];
        int p = atomicAdd(&cursor[r], 1);
        cols_s[p] = col[i];
        vals_s[p] = val[i];
    }
}

// ---------------------------------------------------------------------------
__device__ __forceinline__ float wave_sum(float v) {
#pragma unroll
    for (int off = 32; off > 0; off >>= 1) v += __shfl_xor(v, off, 64);
    return v;
}
__device__ __forceinline__ float wave_max(float v) {
#pragma unroll
    for (int off = 32; off > 0; off >>= 1) v = fmaxf(v, __shfl_xor(v, off, 64));
    return v;
}

// ---------------------------------------------------------------------------
// Layer-1 fused: dual CSR spmm + attention + combine -> h (bf16).
// Scalar-driven edge loop (cols/vals via SGPR), 8-deep gather pipeline.
// ---------------------------------------------------------------------------
__global__ __launch_bounds__(256) void spmm_att1(const int* __restrict__ rowptr,
                                                 const int* __restrict__ cols,
                                                 const float* __restrict__ vals,
                                                 const short* __restrict__ xlh,
                                                 const short* __restrict__ xm,
                                                 const float* __restrict__ a_low,
                                                 const float* __restrict__ a_high,
                                                 const float* __restrict__ a_mlp,
                                                 const float* __restrict__ av,
                                                 short* __restrict__ hb,
                                                 int n) {
    const int node = blockIdx.x * 4 + (threadIdx.x >> 6);
    const int lane = threadIdx.x & 63;
    if (node >= n) return;
    const uint2* XLH = (const uint2*)xlh;       // node stride 64 uint2
    const unsigned* XM = (const unsigned*)xm;

    const int s = __builtin_amdgcn_readfirstlane(rowptr[node]);
    const int e = __builtin_amdgcn_readfirstlane(rowptr[node + 1]);

    float l0 = 0.f, l1 = 0.f, h0 = 0.f, h1 = 0.f;
    for (int j = s; j < e; j += 8) {
        int   cq[8];
        float vq[8];
#pragma unroll
        for (int q = 0; q < 8; ++q) {
            const int jj = min(j + q, e - 1);           // scalar clamp
            cq[q] = rfl_i(&cols[jj]);
            const float t = rfl_f(&vals[jj]);
            vq[q] = (j + q < e) ? t : 0.f;              // scalar select
        }
        uint2 p[8];
#pragma unroll
        for (int q = 0; q < 8; ++q)
            p[q] = XLH[(size_t)cq[q] * 64 + lane];      // 8 gathers in flight
#pragma unroll
        for (int q = 0; q < 8; ++q) {
            l0 += vq[q] * b2f_lo(p[q].x); l1 += vq[q] * b2f_hi(p[q].x);
            h0 += vq[q] * b2f_lo(p[q].y); h1 += vq[q] * b2f_hi(p[q].y);
        }
    }

    const uint2 self = XLH[(size_t)node * 64 + lane];
    const unsigned xmn = XM[(size_t)node * 64 + lane];
    float ol0 = fmaxf(l0, 0.f);
    float ol1 = fmaxf(l1, 0.f);
    float oh0 = fmaxf(b2f_lo(self.y) - h0, 0.f);
    float oh1 = fmaxf(b2f_hi(self.y) - h1, 0.f);
    float om0 = fmaxf(b2f_lo(xmn), 0.f);
    float om1 = fmaxf(b2f_hi(xmn), 0.f);

    const float2 aL = ((const float2*)a_low)[lane];
    const float2 aH = ((const float2*)a_high)[lane];
    const float2 aM = ((const float2*)a_mlp)[lane];
    float dl = wave_sum(ol0 * aL.x + ol1 * aL.y);
    float dh = wave_sum(oh0 * aH.x + oh1 * aH.y);
    float dm = wave_sum(om0 * aM.x + om1 * aM.y);

    const float g0 = 1.f / (1.f + expf(-dl));
    const float g1 = 1.f / (1.f + expf(-dh));
    const float g2 = 1.f / (1.f + expf(-dm));
    float s0 = (g0 * av[0] + g1 * av[3] + g2 * av[6]) * (1.f / 3.f);
    float s1 = (g0 * av[1] + g1 * av[4] + g2 * av[7]) * (1.f / 3.f);
    float s2 = (g0 * av[2] + g1 * av[5] + g2 * av[8]) * (1.f / 3.f);
    float mx = fmaxf(s0, fmaxf(s1, s2));
    float e0 = expf(s0 - mx), e1 = expf(s1 - mx), e2 = expf(s2 - mx);
    float inv = 1.f / (e0 + e1 + e2);
    float at0 = e0 * inv, at1 = e1 * inv, at2 = e2 * inv;

    float ho0 = 3.f * (at0 * ol0 + at1 * oh0 + at2 * om0);
    float ho1 = 3.f * (at0 * ol1 + at1 * oh1 + at2 * om1);
    unsigned pk = (unsigned)(unsigned short)f2b(ho0) |
                  ((unsigned)(unsigned short)f2b(ho1) << 16);
    ((unsigned*)hb)[(size_t)node * 64 + lane] = pk;
}

// ---------------------------------------------------------------------------
// Layer-2 fused: dual CSR spmm + attention + combine + log_softmax -> out.
// Scalar-driven edge loop, 8-deep gather pipeline.
// ---------------------------------------------------------------------------
__global__ __launch_bounds__(256) void spmm_att2(const int* __restrict__ rowptr,
                                                 const int* __restrict__ cols,
                                                 const float* __restrict__ vals,
                                                 const short* __restrict__ xlh,
                                                 const short* __restrict__ xm,
                                                 const float* __restrict__ a_low,
                                                 const float* __restrict__ a_high,
                                                 const float* __restrict__ a_mlp,
                                                 const float* __restrict__ av,
                                                 float* __restrict__ out,
                                                 int n) {
    const int node = blockIdx.x * 4 + (threadIdx.x >> 6);
    const int lane = threadIdx.x & 63;
    if (node >= n) return;
    const unsigned* XLH = (const unsigned*)xlh; // node stride 64 u32

    const int s = __builtin_amdgcn_readfirstlane(rowptr[node]);
    const int e = __builtin_amdgcn_readfirstlane(rowptr[node + 1]);

    float accl = 0.f, acch = 0.f;
    for (int j = s; j < e; j += 8) {
        int   cq[8];
        float vq[8];
#pragma unroll
        for (int q = 0; q < 8; ++q) {
            const int jj = min(j + q, e - 1);
            cq[q] = rfl_i(&cols[jj]);
            const float t = rfl_f(&vals[jj]);
            vq[q] = (j + q < e) ? t : 0.f;
        }
        unsigned p[8];
#pragma unroll
        for (int q = 0; q < 8; ++q)
            p[q] = XLH[(size_t)cq[q] * 64 + lane];
#pragma unroll
        for (int q = 0; q < 8; ++q) {
            accl += vq[q] * b2f_lo(p[q]);
            acch += vq[q] * b2f_hi(p[q]);
        }
    }

    const unsigned self = XLH[(size_t)node * 64 + lane];
    float ol = fmaxf(accl, 0.f);
    float oh = fmaxf(b2f_hi(self) - acch, 0.f);
    float om = fmaxf(b2f(xm[(size_t)node * 64 + lane]), 0.f);

    float dl = wave_sum(ol * a_low[lane]);
    float dh = wave_sum(oh * a_high[lane]);
    float dm = wave_sum(om * a_mlp[lane]);

    const float g0 = 1.f / (1.f + expf(-dl));
    const float g1 = 1.f / (1.f + expf(-dh));
    const float g2 = 1.f / (1.f + expf(-dm));
    float s0 = (g0 * av[0] + g1 * av[3] + g2 * av[6]) * (1.f / 3.f);
    float s1 = (g0 * av[1] + g1 * av[4] + g2 * av[7]) * (1.f / 3.f);
    float s2 = (g0 * av[2] + g1 * av[5] + g2 * av[8]) * (1.f / 3.f);
    float mx3 = fmaxf(s0, fmaxf(s1, s2));
    float e0 = expf(s0 - mx3), e1 = expf(s1 - mx3), e2 = expf(s2 - mx3);
    float inv = 1.f / (e0 + e1 + e2);
    float at0 = e0 * inv, at1 = e1 * inv, at2 = e2 * inv;

    float o = 3.f * (at0 * ol + at1 * oh + at2 * om);

    float m = wave_max(o);
    float ex = expf(o - m);
    float su = wave_sum(ex);
    out[(size_t)node * 64 + lane] = o - m - logf(su);
}

// ---------------------------------------------------------------------------
extern "C" void kernel_launch(void* const* d_in, const int* in_sizes, int n_in,
                              void* d_out, int out_size, void* d_ws, size_t ws_size,
                              hipStream_t stream) {
    const float* x    = (const float*)d_in[0];
    const int*   erow = (const int*)d_in[1];
    const int*   ecol = (const int*)d_in[2];
    const float* eval = (const float*)d_in[3];
    const float* Wl   = (const float*)d_in[4];
    const float* Wh   = (const float*)d_in[5];
    const float* Wm   = (const float*)d_in[6];
    const float* al   = (const float*)d_in[7];
    const float* ah   = (const float*)d_in[8];
    const float* am   = (const float*)d_in[9];
    const float* av   = (const float*)d_in[10];
    const float* Wl2  = (const float*)d_in[11];
    const float* Wh2  = (const float*)d_in[12];
    const float* Wm2  = (const float*)d_in[13];
    const float* al2  = (const float*)d_in[14];
    const float* ah2  = (const float*)d_in[15];
    const float* am2  = (const float*)d_in[16];
    const float* av2  = (const float*)d_in[17];
    float* out = (float*)d_out;

    const int E = in_sizes[1];
    const int N = NN;

    short* ws    = (short*)d_ws;
    short* xb    = ws;                          // N*512 bf16 (converted x)
    short* xlh1  = xb + (size_t)N * 512;        // N*256 (xl/xh pair-interleaved)
    short* xm1   = xlh1 + (size_t)N * 256;      // N*128
    short* hb    = xm1 + (size_t)N * 128;       // N*128
    short* Bt1   = hb + (size_t)N * 128;        // 384*512
    short* Bt2   = Bt1 + 384 * 512;             // 192*128
    int*   ip    = (int*)(Bt2 + 192 * 128);
    int*   counts = ip;                         // N
    int*   rowptr = ip + N;                     // N+1
    int*   cursor = ip + 2 * N + 1;             // N
    int*   bsums  = ip + 3 * N + 1;             // 256
    int*   cols_s = ip + 3 * N + 1 + 256;       // E
    float* vals_s = (float*)(cols_s + E);       // E

    // Layer-2 aliases (xlh1/xm1 regions dead after spmm_att1)
    short* xlh2 = xlh1;                         // N*128 (element-interleaved)
    short* xm2  = xlh1 + (size_t)N * 128;       // N*64

    const int NB = (N + 255) / 256;
    const int EB = (E + 255) / 256;
    const int node_blocks = (N + 3) / 4;
    const int MT = (N + 127) / 128;
    const int XCB = (N * F_IN / 8 + 255) / 256;

    // ---------------- conversion + CSR build + weight prep ----------------
    xconv<<<XCB, 256, 0, stream>>>(x, xb, N * F_IN / 8);
    hipMemsetAsync(counts, 0, (size_t)N * sizeof(int), stream);
    hist_kernel<<<EB, 256, 0, stream>>>(erow, counts, E);
    block_sums_kernel<<<NB, 256, 0, stream>>>(counts, bsums, N);
    scan_bsums_kernel<<<1, 64, 0, stream>>>(bsums, NB);
    scan_final_kernel<<<NB, 256, 0, stream>>>(counts, bsums, rowptr, cursor, N);
    scatter_edges_kernel<<<EB, 256, 0, stream>>>(erow, ecol, eval, cursor, cols_s, vals_s, E);
    wprep<F_IN, HH><<<(3 * HH * (F_IN / 8) + 255) / 256, 256, 0, stream>>>(Wl, Wh, Wm, Bt1);
    wprep<HH, CC><<<(3 * CC * (HH / 8) + 255) / 256, 256, 0, stream>>>(Wl2, Wh2, Wm2, Bt2);

    // ---------------- Layer 1 ----------------
    gemm_mfma<F_IN, HH><<<MT * 3, 256, 0, stream>>>(xb, Bt1, xlh1, xm1, N);
    spmm_att1<<<node_blocks, 256, 0, stream>>>(rowptr, cols_s, vals_s,
                                               xlh1, xm1, al, ah, am, av, hb, N);

    // ---------------- Layer 2 ----------------
    gemm_mfma<HH, CC><<<MT * 3, 256, 0, stream>>>(hb, Bt2, xlh2, xm2, N);
    spmm_att2<<<node_blocks, 256, 0, stream>>>(rowptr, cols_s, vals_s,
                                               xlh2, xm2, al2, ah2, am2, av2, out, N);
}

// Round 10
// 288.620 us; speedup vs baseline: 1.3167x; 1.0023x over previous
//
#include <hip/hip_runtime.h>
#include <hip/hip_bf16.h>

// Problem constants (reference file)
#define NN 50000
#define F_IN 512
#define HH 128
#define CC 64

typedef __attribute__((ext_vector_type(8))) short short8v;   // 8 bf16 (4 VGPRs)
typedef __attribute__((ext_vector_type(4))) float f32x4;     // MFMA accumulator
typedef __attribute__((ext_vector_type(2))) float f32x2;

__device__ __forceinline__ short f2b(float f) {
    unsigned u = __builtin_bit_cast(unsigned, f);
    unsigned r = (u + 0x7fffu + ((u >> 16) & 1u)) >> 16;     // RNE
    return (short)r;
}
__device__ __forceinline__ float b2f(short s) {
    unsigned u = ((unsigned)(unsigned short)s) << 16;
    return __builtin_bit_cast(float, u);
}
__device__ __forceinline__ float b2f_lo(unsigned p) {
    return __builtin_bit_cast(float, p << 16);
}
__device__ __forceinline__ float b2f_hi(unsigned p) {
    return __builtin_bit_cast(float, p & 0xffff0000u);
}

// fp8 e4m3 (OCP) encode/decode via gfx950 HW converts
__device__ __forceinline__ unsigned char f2q(float f) {
    return (unsigned char)(__builtin_amdgcn_cvt_pk_fp8_f32(f, f, 0, false) & 0xff);
}
__device__ __forceinline__ f32x2 q2_lo(unsigned p) {   // bytes 0,1
    return __builtin_amdgcn_cvt_pk_f32_fp8(p, false);
}
__device__ __forceinline__ f32x2 q2_hi(unsigned p) {   // bytes 2,3
    return __builtin_amdgcn_cvt_pk_f32_fp8(p, true);
}

// wave-uniform scalar load helpers
__device__ __forceinline__ int rfl_i(const int* __restrict__ p) {
    return __builtin_amdgcn_readfirstlane(*p);
}
__device__ __forceinline__ float rfl_f(const float* __restrict__ p) {
    int v = __builtin_amdgcn_readfirstlane(__builtin_bit_cast(int, *p));
    return __builtin_bit_cast(float, v);
}

// Bijective XCD swizzle (m204)
__device__ __forceinline__ int xcd_swz(int bid, int nwg) {
    int q = nwg >> 3, r = nwg & 7;
    int xcd = bid & 7, off = bid >> 3;
    return (xcd < r ? xcd * (q + 1) : r * (q + 1) + (xcd - r) * q) + off;
}

// async global->LDS, 16 B per lane
__device__ __forceinline__ void load_lds16(const short* g, short* l) {
    __builtin_amdgcn_global_load_lds(
        (const __attribute__((address_space(1))) unsigned int*)g,
        (__attribute__((address_space(3))) unsigned int*)l,
        16, 0, 0);
}

// ---------------------------------------------------------------------------
// x f32 -> bf16 streaming conversion (one-time)
// ---------------------------------------------------------------------------
__global__ __launch_bounds__(256) void xconv(const float* __restrict__ x,
                                             short* __restrict__ xb, int n8) {
    int i = blockIdx.x * 256 + threadIdx.x;
    if (i >= n8) return;
    const float4* xp = (const float4*)x;
    const float4 a = xp[2 * i];
    const float4 b = xp[2 * i + 1];
    short8v o;
    o[0] = f2b(a.x); o[1] = f2b(a.y); o[2] = f2b(a.z); o[3] = f2b(a.w);
    o[4] = f2b(b.x); o[5] = f2b(b.y); o[6] = f2b(b.z); o[7] = f2b(b.w);
    *reinterpret_cast<short8v*>(&xb[(size_t)i * 8]) = o;
}

// ---------------------------------------------------------------------------
// Weight prep: Bt[n][k] = W_{n/OUTW}[k][n%OUTW]  (bf16, transposed + concat)
// ---------------------------------------------------------------------------
template <int K, int OUTW>
__global__ __launch_bounds__(256) void wprep(const float* __restrict__ W0,
                                             const float* __restrict__ W1,
                                             const float* __restrict__ W2,
                                             short* __restrict__ Bt) {
    const int id = blockIdx.x * 256 + threadIdx.x;
    const int nth = 3 * OUTW * (K / 8);
    if (id >= nth) return;
    const int n = id / (K / 8);
    const int kq = id % (K / 8);
    const int sel = n / OUTW;
    const int c = n % OUTW;
    const float* W = sel == 0 ? W0 : (sel == 1 ? W1 : W2);
    short v[8];
#pragma unroll
    for (int j = 0; j < 8; ++j) v[j] = f2b(W[(size_t)(kq * 8 + j) * OUTW + c]);
#pragma unroll
    for (int j = 0; j < 8; ++j) Bt[(size_t)n * K + kq * 8 + j] = v[j];
}

// ---------------------------------------------------------------------------
// MFMA GEMM with global_load_lds staging + XOR slot swizzle.
// Outputs: bn==0 -> fp8 xl into packed gather buf; bn==1 -> fp8 xh into
// gather buf + bf16 xh self; bn==2 -> bf16 xm.
// Layer1 (BNout=128) gather row: 64 dwords {xl0,xl1,xh0,xh1} per dword.
// Layer2 (BNout=64)  gather row: 64 ushorts {xl,xh}.
// ---------------------------------------------------------------------------
template <int K, int BNout>
__global__ __launch_bounds__(256) void gemm_mfma(const short* __restrict__ A,
                                                 const short* __restrict__ Bt,
                                                 unsigned char* __restrict__ xq,
                                                 short* __restrict__ xhs,
                                                 short* __restrict__ xm,
                                                 int M) {
    constexpr int BM = 128, BK = 64;
    constexpr int FM = (BNout == 128) ? 4 : 2;
    constexpr int FN = 4;
    constexpr int WM = FM * 16;
    constexpr int NKT = K / BK;
    constexpr int NBL = BNout / 32;

    __shared__ short As[BM * BK];
    __shared__ short Bs[BNout * BK];

    const int tid = threadIdx.x;
    const int lane = tid & 63;
    const int wid = tid >> 6;
    const int wg = xcd_swz(blockIdx.x, gridDim.x);
    const int bm = wg / 3;
    const int bn = wg % 3;
    const int m0 = bm * BM;
    const int n0 = bn * BNout;
    const int wm = (BNout == 128) ? (wid >> 1) : wid;
    const int wn = (BNout == 128) ? (wid & 1) : 0;

    const int r8 = lane >> 3;
    const int sl = (lane & 7) ^ r8;

    f32x4 acc[FM][FN];
#pragma unroll
    for (int i = 0; i < FM; ++i)
#pragma unroll
        for (int j = 0; j < FN; ++j) acc[i][j] = (f32x4){0.f, 0.f, 0.f, 0.f};

    for (int kt = 0; kt < NKT; ++kt) {
        const int k0 = kt * BK;
        __syncthreads();
#pragma unroll
        for (int i = 0; i < 4; ++i) {
            int r = (wid * 4 + i) * 8 + r8;
            int gr = m0 + r; if (gr >= M) gr = M - 1;
            load_lds16(&A[(size_t)gr * K + k0 + sl * 8], &As[(wid * 4 + i) * 512]);
        }
#pragma unroll
        for (int i = 0; i < NBL; ++i) {
            int r = (wid * NBL + i) * 8 + r8;
            load_lds16(&Bt[(size_t)(n0 + r) * K + k0 + sl * 8],
                       &Bs[(wid * NBL + i) * 512]);
        }
        __syncthreads();

        const int mrow = lane & 15;
        const int kg = lane >> 4;
#pragma unroll
        for (int kk = 0; kk < 2; ++kk) {
            short8v af[FM], bf[FN];
#pragma unroll
            for (int f = 0; f < FM; ++f) {
                int m = wm * WM + f * 16 + mrow;
                int s = kk * 4 + kg;
                af[f] = *reinterpret_cast<const short8v*>(
                    &As[m * 64 + ((s ^ (m & 7)) << 3)]);
            }
#pragma unroll
            for (int f = 0; f < FN; ++f) {
                int nr = wn * 64 + f * 16 + mrow;
                int s = kk * 4 + kg;
                bf[f] = *reinterpret_cast<const short8v*>(
                    &Bs[nr * 64 + ((s ^ (nr & 7)) << 3)]);
            }
#pragma unroll
            for (int i = 0; i < FM; ++i)
#pragma unroll
                for (int j = 0; j < FN; ++j)
                    acc[i][j] = __builtin_amdgcn_mfma_f32_16x16x32_bf16(
                        af[i], bf[j], acc[i][j], 0, 0, 0);
        }
    }

#pragma unroll
    for (int i = 0; i < FM; ++i)
#pragma unroll
        for (int j = 0; j < FN; ++j) {
            int cc = wn * 64 + j * 16 + (lane & 15);
#pragma unroll
            for (int e = 0; e < 4; ++e) {
                int row = m0 + wm * WM + i * 16 + (lane >> 4) * 4 + e;
                if (row >= M) continue;
                float v = acc[i][j][e];
                if (BNout == 128) {
                    if (bn == 0) {
                        xq[(size_t)row * 256 + ((cc >> 1) << 2) + (cc & 1)] = f2q(v);
                    } else if (bn == 1) {
                        xq[(size_t)row * 256 + ((cc >> 1) << 2) + 2 + (cc & 1)] = f2q(v);
                        xhs[(size_t)row * 128 + cc] = f2b(v);
                    } else {
                        xm[(size_t)row * 128 + cc] = f2b(v);
                    }
                } else {
                    if (bn == 0) {
                        xq[(size_t)row * 128 + cc * 2] = f2q(v);
                    } else if (bn == 1) {
                        xq[(size_t)row * 128 + cc * 2 + 1] = f2q(v);
                        xhs[(size_t)row * 64 + cc] = f2b(v);
                    } else {
                        xm[(size_t)row * 64 + cc] = f2b(v);
                    }
                }
            }
        }
}

// ---------------------------------------------------------------------------
// CSR construction
// ---------------------------------------------------------------------------
__global__ __launch_bounds__(256) void hist_kernel(const int* __restrict__ row,
                                                   int* __restrict__ counts, int E) {
    int i = blockIdx.x * 256 + threadIdx.x;
    if (i < E) atomicAdd(&counts[row[i]], 1);
}

__global__ __launch_bounds__(256) void block_sums_kernel(const int* __restrict__ counts,
                                                         int* __restrict__ bsums, int n) {
    __shared__ int s[256];
    int tid = threadIdx.x;
    int i = blockIdx.x * 256 + tid;
    s[tid] = (i < n) ? counts[i] : 0;
    __syncthreads();
#pragma unroll
    for (int off = 128; off > 0; off >>= 1) {
        if (tid < off) s[tid] += s[tid + off];
        __syncthreads();
    }
    if (tid == 0) bsums[blockIdx.x] = s[0];
}

__global__ __launch_bounds__(64) void scan_bsums_kernel(int* __restrict__ bsums, int nb) {
    if (threadIdx.x == 0) {
        int a = 0;
        for (int i = 0; i < nb; ++i) {
            int t = bsums[i];
            bsums[i] = a;
            a += t;
        }
    }
}

__global__ __launch_bounds__(256) void scan_final_kernel(const int* __restrict__ counts,
                                                         const int* __restrict__ bsums,
                                                         int* __restrict__ rowptr,
                                                         int* __restrict__ cursor, int n) {
    __shared__ int s[256];
    int tid = threadIdx.x;
    int i = blockIdx.x * 256 + tid;
    int v = (i < n) ? counts[i] : 0;
    s[tid] = v;
    __syncthreads();
#pragma unroll
    for (int off = 1; off < 256; off <<= 1) {
        int t = (tid >= off) ? s[tid - off] : 0;
        __syncthreads();
        s[tid] += t;
        __syncthreads();
    }
    int excl = s[tid] - v + bsums[blockIdx.x];
    if (i < n) {
        rowptr[i] = excl;
        cursor[i] = excl;
        if (i == n - 1) rowptr[n] = excl + v;
    }
}

__global__ __launch_bounds__(256) void scatter_edges_kernel(const int* __restrict__ row,
                                                            const int* __restrict__ col,
                                                            const float* __restrict__ val,
                                                            int* __restrict__ cursor,
                                                            int* __restrict__ cols_s,
                                                            float* __restrict__ vals_s, int E) {
    int i = blockIdx.x * 256 + threadIdx.x;
    if (i < E) {
        int r = row[i];
        int p = atomicAdd(&cursor[r], 1);
        cols_s[p] = col[i];
        vals_s[p] = val[i];
    }
}

// ---------------------------------------------------------------------------
__device__ __forceinline__ float wave_sum(float v) {
#pragma unroll
    for (int off = 32; off > 0; off >>= 1) v += __shfl_xor(v, off, 64);
    return v;
}
__device__ __forceinline__ float wave_max(float v) {
#pragma unroll
    for (int off = 32; off > 0; off >>= 1) v = fmaxf(v, __shfl_xor(v, off, 64));
    return v;
}

// ---------------------------------------------------------------------------
// Layer-1 fused: dual CSR spmm (fp8 gathers) + attention + combine -> h bf16.
// Gather: one dword/lane/edge = {xl0,xl1,xh0,xh1} fp8. Self terms bf16.
// ---------------------------------------------------------------------------
__global__ __launch_bounds__(256) void spmm_att1(const int* __restrict__ rowptr,
                                                 const int* __restrict__ cols,
                                                 const float* __restrict__ vals,
                                                 const unsigned char* __restrict__ xq,
                                                 const short* __restrict__ xhs,
                                                 const short* __restrict__ xm,
                                                 const float* __restrict__ a_low,
                                                 const float* __restrict__ a_high,
                                                 const float* __restrict__ a_mlp,
                                                 const float* __restrict__ av,
                                                 short* __restrict__ hb,
                                                 int n) {
    const int node = blockIdx.x * 4 + (threadIdx.x >> 6);
    const int lane = threadIdx.x & 63;
    if (node >= n) return;
    const unsigned* XQ = (const unsigned*)xq;    // [node][64] dwords
    const unsigned* XH = (const unsigned*)xhs;   // [node][64] bf16-pairs
    const unsigned* XM = (const unsigned*)xm;

    const int s = __builtin_amdgcn_readfirstlane(rowptr[node]);
    const int e = __builtin_amdgcn_readfirstlane(rowptr[node + 1]);

    float l0 = 0.f, l1 = 0.f, h0 = 0.f, h1 = 0.f;
    for (int j = s; j < e; j += 8) {
        int   cq[8];
        float vq[8];
#pragma unroll
        for (int q = 0; q < 8; ++q) {
            const int jj = min(j + q, e - 1);
            cq[q] = rfl_i(&cols[jj]);
            const float t = rfl_f(&vals[jj]);
            vq[q] = (j + q < e) ? t : 0.f;
        }
        unsigned p[8];
#pragma unroll
        for (int q = 0; q < 8; ++q)
            p[q] = XQ[(size_t)cq[q] * 64 + lane];
#pragma unroll
        for (int q = 0; q < 8; ++q) {
            const f32x2 lo = q2_lo(p[q]);
            const f32x2 hi = q2_hi(p[q]);
            l0 += vq[q] * lo.x; l1 += vq[q] * lo.y;
            h0 += vq[q] * hi.x; h1 += vq[q] * hi.y;
        }
    }

    const unsigned xhn = XH[(size_t)node * 64 + lane];
    const unsigned xmn = XM[(size_t)node * 64 + lane];
    float ol0 = fmaxf(l0, 0.f);
    float ol1 = fmaxf(l1, 0.f);
    float oh0 = fmaxf(b2f_lo(xhn) - h0, 0.f);
    float oh1 = fmaxf(b2f_hi(xhn) - h1, 0.f);
    float om0 = fmaxf(b2f_lo(xmn), 0.f);
    float om1 = fmaxf(b2f_hi(xmn), 0.f);

    const float2 aL = ((const float2*)a_low)[lane];
    const float2 aH = ((const float2*)a_high)[lane];
    const float2 aM = ((const float2*)a_mlp)[lane];
    float dl = wave_sum(ol0 * aL.x + ol1 * aL.y);
    float dh = wave_sum(oh0 * aH.x + oh1 * aH.y);
    float dm = wave_sum(om0 * aM.x + om1 * aM.y);

    const float g0 = 1.f / (1.f + expf(-dl));
    const float g1 = 1.f / (1.f + expf(-dh));
    const float g2 = 1.f / (1.f + expf(-dm));
    float s0 = (g0 * av[0] + g1 * av[3] + g2 * av[6]) * (1.f / 3.f);
    float s1 = (g0 * av[1] + g1 * av[4] + g2 * av[7]) * (1.f / 3.f);
    float s2 = (g0 * av[2] + g1 * av[5] + g2 * av[8]) * (1.f / 3.f);
    float mx = fmaxf(s0, fmaxf(s1, s2));
    float e0 = expf(s0 - mx), e1 = expf(s1 - mx), e2 = expf(s2 - mx);
    float inv = 1.f / (e0 + e1 + e2);
    float at0 = e0 * inv, at1 = e1 * inv, at2 = e2 * inv;

    float ho0 = 3.f * (at0 * ol0 + at1 * oh0 + at2 * om0);
    float ho1 = 3.f * (at0 * ol1 + at1 * oh1 + at2 * om1);
    unsigned pk = (unsigned)(unsigned short)f2b(ho0) |
                  ((unsigned)(unsigned short)f2b(ho1) << 16);
    ((unsigned*)hb)[(size_t)node * 64 + lane] = pk;
}

// ---------------------------------------------------------------------------
// Layer-2 fused: dual CSR spmm (fp8 ushort gathers) + attention + combine +
// log_softmax -> out. Self terms bf16.
// ---------------------------------------------------------------------------
__global__ __launch_bounds__(256) void spmm_att2(const int* __restrict__ rowptr,
                                                 const int* __restrict__ cols,
                                                 const float* __restrict__ vals,
                                                 const unsigned char* __restrict__ xq,
                                                 const short* __restrict__ xhs,
                                                 const short* __restrict__ xm,
                                                 const float* __restrict__ a_low,
                                                 const float* __restrict__ a_high,
                                                 const float* __restrict__ a_mlp,
                                                 const float* __restrict__ av,
                                                 float* __restrict__ out,
                                                 int n) {
    const int node = blockIdx.x * 4 + (threadIdx.x >> 6);
    const int lane = threadIdx.x & 63;
    if (node >= n) return;
    const unsigned short* XQ = (const unsigned short*)xq;  // [node][64] {xl,xh}

    const int s = __builtin_amdgcn_readfirstlane(rowptr[node]);
    const int e = __builtin_amdgcn_readfirstlane(rowptr[node + 1]);

    float accl = 0.f, acch = 0.f;
    for (int j = s; j < e; j += 8) {
        int   cq[8];
        float vq[8];
#pragma unroll
        for (int q = 0; q < 8; ++q) {
            const int jj = min(j + q, e - 1);
            cq[q] = rfl_i(&cols[jj]);
            const float t = rfl_f(&vals[jj]);
            vq[q] = (j + q < e) ? t : 0.f;
        }
        unsigned short p[8];
#pragma unroll
        for (int q = 0; q < 8; ++q)
            p[q] = XQ[(size_t)cq[q] * 64 + lane];
#pragma unroll
        for (int q = 0; q < 8; ++q) {
            const f32x2 d = q2_lo((unsigned)p[q]);
            accl += vq[q] * d.x;
            acch += vq[q] * d.y;
        }
    }

    float ol = fmaxf(accl, 0.f);
    float oh = fmaxf(b2f(xhs[(size_t)node * 64 + lane]) - acch, 0.f);
    float om = fmaxf(b2f(xm[(size_t)node * 64 + lane]), 0.f);

    float dl = wave_sum(ol * a_low[lane]);
    float dh = wave_sum(oh * a_high[lane]);
    float dm = wave_sum(om * a_mlp[lane]);

    const float g0 = 1.f / (1.f + expf(-dl));
    const float g1 = 1.f / (1.f + expf(-dh));
    const float g2 = 1.f / (1.f + expf(-dm));
    float s0 = (g0 * av[0] + g1 * av[3] + g2 * av[6]) * (1.f / 3.f);
    float s1 = (g0 * av[1] + g1 * av[4] + g2 * av[7]) * (1.f / 3.f);
    float s2 = (g0 * av[2] + g1 * av[5] + g2 * av[8]) * (1.f / 3.f);
    float mx3 = fmaxf(s0, fmaxf(s1, s2));
    float e0 = expf(s0 - mx3), e1 = expf(s1 - mx3), e2 = expf(s2 - mx3);
    float inv = 1.f / (e0 + e1 + e2);
    float at0 = e0 * inv, at1 = e1 * inv, at2 = e2 * inv;

    float o = 3.f * (at0 * ol + at1 * oh + at2 * om);

    float m = wave_max(o);
    float ex = expf(o - m);
    float su = wave_sum(ex);
    out[(size_t)node * 64 + lane] = o - m - logf(su);
}

// ---------------------------------------------------------------------------
extern "C" void kernel_launch(void* const* d_in, const int* in_sizes, int n_in,
                              void* d_out, int out_size, void* d_ws, size_t ws_size,
                              hipStream_t stream) {
    const float* x    = (const float*)d_in[0];
    const int*   erow = (const int*)d_in[1];
    const int*   ecol = (const int*)d_in[2];
    const float* eval = (const float*)d_in[3];
    const float* Wl   = (const float*)d_in[4];
    const float* Wh   = (const float*)d_in[5];
    const float* Wm   = (const float*)d_in[6];
    const float* al   = (const float*)d_in[7];
    const float* ah   = (const float*)d_in[8];
    const float* am   = (const float*)d_in[9];
    const float* av   = (const float*)d_in[10];
    const float* Wl2  = (const float*)d_in[11];
    const float* Wh2  = (const float*)d_in[12];
    const float* Wm2  = (const float*)d_in[13];
    const float* al2  = (const float*)d_in[14];
    const float* ah2  = (const float*)d_in[15];
    const float* am2  = (const float*)d_in[16];
    const float* av2  = (const float*)d_in[17];
    float* out = (float*)d_out;

    const int E = in_sizes[1];
    const int N = NN;

    short* ws    = (short*)d_ws;
    short* xb    = ws;                          // N*512 bf16 (converted x)
    unsigned char* xq1 = (unsigned char*)(xb + (size_t)N * 512);   // N*256 B fp8
    short* xh1s  = (short*)(xq1 + (size_t)N * 256);                // N*128 bf16
    short* xm1   = xh1s + (size_t)N * 128;       // N*128 bf16
    short* hb    = xm1 + (size_t)N * 128;        // N*128 bf16
    short* Bt1   = hb + (size_t)N * 128;         // 384*512
    short* Bt2   = Bt1 + 384 * 512;              // 192*128
    int*   ip    = (int*)(Bt2 + 192 * 128);
    int*   counts = ip;                          // N
    int*   rowptr = ip + N;                      // N+1
    int*   cursor = ip + 2 * N + 1;              // N
    int*   bsums  = ip + 3 * N + 1;              // 256
    int*   cols_s = ip + 3 * N + 1 + 256;        // E
    float* vals_s = (float*)(cols_s + E);        // E

    // Layer-2 aliases (xq1/xh1s/xm1 dead after spmm_att1)
    unsigned char* xq2 = xq1;                    // N*128 B fp8 {xl,xh}
    short* xh2s = xh1s;                          // N*64 bf16
    short* xm2  = xm1;                           // N*64 bf16

    const int NB = (N + 255) / 256;
    const int EB = (E + 255) / 256;
    const int node_blocks = (N + 3) / 4;
    const int MT = (N + 127) / 128;
    const int XCB = (N * F_IN / 8 + 255) / 256;

    // ---------------- conversion + CSR build + weight prep ----------------
    xconv<<<XCB, 256, 0, stream>>>(x, xb, N * F_IN / 8);
    hipMemsetAsync(counts, 0, (size_t)N * sizeof(int), stream);
    hist_kernel<<<EB, 256, 0, stream>>>(erow, counts, E);
    block_sums_kernel<<<NB, 256, 0, stream>>>(counts, bsums, N);
    scan_bsums_kernel<<<1, 64, 0, stream>>>(bsums, NB);
    scan_final_kernel<<<NB, 256, 0, stream>>>(counts, bsums, rowptr, cursor, N);
    scatter_edges_kernel<<<EB, 256, 0, stream>>>(erow, ecol, eval, cursor, cols_s, vals_s, E);
    wprep<F_IN, HH><<<(3 * HH * (F_IN / 8) + 255) / 256, 256, 0, stream>>>(Wl, Wh, Wm, Bt1);
    wprep<HH, CC><<<(3 * CC * (HH / 8) + 255) / 256, 256, 0, stream>>>(Wl2, Wh2, Wm2, Bt2);

    // ---------------- Layer 1 ----------------
    gemm_mfma<F_IN, HH><<<MT * 3, 256, 0, stream>>>(xb, Bt1, xq1, xh1s, xm1, N);
    spmm_att1<<<node_blocks, 256, 0, stream>>>(rowptr, cols_s, vals_s,
                                               xq1, xh1s, xm1, al, ah, am, av, hb, N);

    // ---------------- Layer 2 ----------------
    gemm_mfma<HH, CC><<<MT * 3, 256, 0, stream>>>(hb, Bt2, xq2, xh2s, xm2, N);
    spmm_att2<<<node_blocks, 256, 0, stream>>>(rowptr, cols_s, vals_s,
                                               xq2, xh2s, xm2, al2, ah2, am2, av2, out, N);
}

// Round 11
// 262.944 us; speedup vs baseline: 1.4453x; 1.0976x over previous
//
#include <hip/hip_runtime.h>
#include <hip/hip_bf16.h>

// Problem constants (reference file)
#define NN 50000
#define F_IN 512
#define HH 128
#define CC 64

typedef __attribute__((ext_vector_type(8))) short short8v;   // 8 bf16 (4 VGPRs)
typedef __attribute__((ext_vector_type(4))) float f32x4;     // MFMA accumulator
typedef __attribute__((ext_vector_type(2))) float f32x2;

__device__ __forceinline__ short f2b(float f) {
    unsigned u = __builtin_bit_cast(unsigned, f);
    unsigned r = (u + 0x7fffu + ((u >> 16) & 1u)) >> 16;     // RNE
    return (short)r;
}
__device__ __forceinline__ float b2f(short s) {
    unsigned u = ((unsigned)(unsigned short)s) << 16;
    return __builtin_bit_cast(float, u);
}
__device__ __forceinline__ float b2f_lo(unsigned p) {
    return __builtin_bit_cast(float, p << 16);
}
__device__ __forceinline__ float b2f_hi(unsigned p) {
    return __builtin_bit_cast(float, p & 0xffff0000u);
}

// fp8 e4m3 (OCP) decode via gfx950 HW converts
__device__ __forceinline__ f32x2 q2_lo(unsigned p) {   // bytes 0,1
    return __builtin_amdgcn_cvt_pk_f32_fp8(p, false);
}
__device__ __forceinline__ f32x2 q2_hi(unsigned p) {   // bytes 2,3
    return __builtin_amdgcn_cvt_pk_f32_fp8(p, true);
}

// wave-uniform scalar load helpers
__device__ __forceinline__ int rfl_i(const int* __restrict__ p) {
    return __builtin_amdgcn_readfirstlane(*p);
}
__device__ __forceinline__ float rfl_f(const float* __restrict__ p) {
    int v = __builtin_amdgcn_readfirstlane(__builtin_bit_cast(int, *p));
    return __builtin_bit_cast(float, v);
}

// Bijective XCD swizzle (m204)
__device__ __forceinline__ int xcd_swz(int bid, int nwg) {
    int q = nwg >> 3, r = nwg & 7;
    int xcd = bid & 7, off = bid >> 3;
    return (xcd < r ? xcd * (q + 1) : r * (q + 1) + (xcd - r) * q) + off;
}

// async global->LDS, 16 B per lane
__device__ __forceinline__ void load_lds16(const short* g, short* l) {
    __builtin_amdgcn_global_load_lds(
        (const __attribute__((address_space(1))) unsigned int*)g,
        (__attribute__((address_space(3))) unsigned int*)l,
        16, 0, 0);
}

// ---------------------------------------------------------------------------
// x f32 -> bf16 streaming conversion (one-time)
// ---------------------------------------------------------------------------
__global__ __launch_bounds__(256) void xconv(const float* __restrict__ x,
                                             short* __restrict__ xb, int n8) {
    int i = blockIdx.x * 256 + threadIdx.x;
    if (i >= n8) return;
    const float4* xp = (const float4*)x;
    const float4 a = xp[2 * i];
    const float4 b = xp[2 * i + 1];
    short8v o;
    o[0] = f2b(a.x); o[1] = f2b(a.y); o[2] = f2b(a.z); o[3] = f2b(a.w);
    o[4] = f2b(b.x); o[5] = f2b(b.y); o[6] = f2b(b.z); o[7] = f2b(b.w);
    *reinterpret_cast<short8v*>(&xb[(size_t)i * 8]) = o;
}

// ---------------------------------------------------------------------------
// Weight prep: Bt[n][k] = W_{n/OUTW}[k][n%OUTW]  (bf16, transposed + concat)
// ---------------------------------------------------------------------------
template <int K, int OUTW>
__global__ __launch_bounds__(256) void wprep(const float* __restrict__ W0,
                                             const float* __restrict__ W1,
                                             const float* __restrict__ W2,
                                             short* __restrict__ Bt) {
    const int id = blockIdx.x * 256 + threadIdx.x;
    const int nth = 3 * OUTW * (K / 8);
    if (id >= nth) return;
    const int n = id / (K / 8);
    const int kq = id % (K / 8);
    const int sel = n / OUTW;
    const int c = n % OUTW;
    const float* W = sel == 0 ? W0 : (sel == 1 ? W1 : W2);
    short v[8];
#pragma unroll
    for (int j = 0; j < 8; ++j) v[j] = f2b(W[(size_t)(kq * 8 + j) * OUTW + c]);
#pragma unroll
    for (int j = 0; j < 8; ++j) Bt[(size_t)n * K + kq * 8 + j] = v[j];
}

// ---------------------------------------------------------------------------
// MFMA GEMM with global_load_lds staging + XOR slot swizzle (r8 epilogue).
// Outputs: bn 0/1 -> bf16 interleaved xlh, bn 2 -> bf16 xm.
// ---------------------------------------------------------------------------
template <int K, int BNout>
__global__ __launch_bounds__(256) void gemm_mfma(const short* __restrict__ A,
                                                 const short* __restrict__ Bt,
                                                 short* __restrict__ xlh,
                                                 short* __restrict__ xm,
                                                 int M) {
    constexpr int BM = 128, BK = 64;
    constexpr int FM = (BNout == 128) ? 4 : 2;
    constexpr int FN = 4;
    constexpr int WM = FM * 16;
    constexpr int NKT = K / BK;
    constexpr int NBL = BNout / 32;

    __shared__ short As[BM * BK];
    __shared__ short Bs[BNout * BK];

    const int tid = threadIdx.x;
    const int lane = tid & 63;
    const int wid = tid >> 6;
    const int wg = xcd_swz(blockIdx.x, gridDim.x);
    const int bm = wg / 3;
    const int bn = wg % 3;
    const int m0 = bm * BM;
    const int n0 = bn * BNout;
    const int wm = (BNout == 128) ? (wid >> 1) : wid;
    const int wn = (BNout == 128) ? (wid & 1) : 0;

    const int r8 = lane >> 3;
    const int sl = (lane & 7) ^ r8;

    f32x4 acc[FM][FN];
#pragma unroll
    for (int i = 0; i < FM; ++i)
#pragma unroll
        for (int j = 0; j < FN; ++j) acc[i][j] = (f32x4){0.f, 0.f, 0.f, 0.f};

    for (int kt = 0; kt < NKT; ++kt) {
        const int k0 = kt * BK;
        __syncthreads();
#pragma unroll
        for (int i = 0; i < 4; ++i) {
            int r = (wid * 4 + i) * 8 + r8;
            int gr = m0 + r; if (gr >= M) gr = M - 1;
            load_lds16(&A[(size_t)gr * K + k0 + sl * 8], &As[(wid * 4 + i) * 512]);
        }
#pragma unroll
        for (int i = 0; i < NBL; ++i) {
            int r = (wid * NBL + i) * 8 + r8;
            load_lds16(&Bt[(size_t)(n0 + r) * K + k0 + sl * 8],
                       &Bs[(wid * NBL + i) * 512]);
        }
        __syncthreads();

        const int mrow = lane & 15;
        const int kg = lane >> 4;
#pragma unroll
        for (int kk = 0; kk < 2; ++kk) {
            short8v af[FM], bf[FN];
#pragma unroll
            for (int f = 0; f < FM; ++f) {
                int m = wm * WM + f * 16 + mrow;
                int s = kk * 4 + kg;
                af[f] = *reinterpret_cast<const short8v*>(
                    &As[m * 64 + ((s ^ (m & 7)) << 3)]);
            }
#pragma unroll
            for (int f = 0; f < FN; ++f) {
                int nr = wn * 64 + f * 16 + mrow;
                int s = kk * 4 + kg;
                bf[f] = *reinterpret_cast<const short8v*>(
                    &Bs[nr * 64 + ((s ^ (nr & 7)) << 3)]);
            }
#pragma unroll
            for (int i = 0; i < FM; ++i)
#pragma unroll
                for (int j = 0; j < FN; ++j)
                    acc[i][j] = __builtin_amdgcn_mfma_f32_16x16x32_bf16(
                        af[i], bf[j], acc[i][j], 0, 0, 0);
        }
    }

#pragma unroll
    for (int i = 0; i < FM; ++i)
#pragma unroll
        for (int j = 0; j < FN; ++j) {
            int cc = wn * 64 + j * 16 + (lane & 15);
#pragma unroll
            for (int e = 0; e < 4; ++e) {
                int row = m0 + wm * WM + i * 16 + (lane >> 4) * 4 + e;
                if (row >= M) continue;
                short v = f2b(acc[i][j][e]);
                if (bn == 2) {
                    xm[(size_t)row * BNout + cc] = v;
                } else if (BNout == 128) {
                    // pair-interleaved: [node][64 pairs][{xl0,xl1,xh0,xh1}]
                    xlh[(size_t)row * 256 + (cc >> 1) * 4 + bn * 2 + (cc & 1)] = v;
                } else {
                    // element-interleaved: [node][64][{xl,xh}]
                    xlh[(size_t)row * 128 + cc * 2 + bn] = v;
                }
            }
        }
}

// ---------------------------------------------------------------------------
// fp8 pack kernels (bf16 gather buffers -> fp8 gather buffers)
// ---------------------------------------------------------------------------
// Layer1: xlh1 pair-dwords {xl0|xl1, xh0|xh1} -> dword {xl0,xl1,xh0,xh1} fp8
__global__ __launch_bounds__(256) void pack8_1(const unsigned* __restrict__ xlh,
                                               unsigned* __restrict__ xq, int n) {
    int i = blockIdx.x * 256 + threadIdx.x;   // over N*64 pairs
    if (i >= n) return;
    const uint2 v = ((const uint2*)xlh)[i];
    unsigned r = __builtin_amdgcn_cvt_pk_fp8_f32(b2f_lo(v.x), b2f_hi(v.x), 0, false);
    r = __builtin_amdgcn_cvt_pk_fp8_f32(b2f_lo(v.y), b2f_hi(v.y), r, true);
    xq[i] = r;
}

// Layer2: xlh2 dwords {xl|xh} -> ushort {xl,xh} fp8 (2 at a time)
__global__ __launch_bounds__(256) void pack8_2(const unsigned* __restrict__ xlh,
                                               unsigned* __restrict__ xq, int n2) {
    int i = blockIdx.x * 256 + threadIdx.x;   // over N*32 dword-pairs
    if (i >= n2) return;
    const uint2 v = ((const uint2*)xlh)[i];
    unsigned lo = __builtin_amdgcn_cvt_pk_fp8_f32(b2f_lo(v.x), b2f_hi(v.x), 0, false);
    unsigned hi = __builtin_amdgcn_cvt_pk_fp8_f32(b2f_lo(v.y), b2f_hi(v.y), 0, false);
    xq[i] = (lo & 0xffffu) | (hi << 16);
}

// ---------------------------------------------------------------------------
// CSR construction
// ---------------------------------------------------------------------------
__global__ __launch_bounds__(256) void zero_counts(int* __restrict__ counts, int n) {
    int i = blockIdx.x * 256 + threadIdx.x;
    if (i < n) counts[i] = 0;
}

__global__ __launch_bounds__(256) void hist_kernel(const int* __restrict__ row,
                                                   int* __restrict__ counts, int E) {
    int i = blockIdx.x * 256 + threadIdx.x;
    if (i < E) atomicAdd(&counts[row[i]], 1);
}

__global__ __launch_bounds__(256) void block_sums_kernel(const int* __restrict__ counts,
                                                         int* __restrict__ bsums, int n) {
    __shared__ int s[256];
    int tid = threadIdx.x;
    int i = blockIdx.x * 256 + tid;
    s[tid] = (i < n) ? counts[i] : 0;
    __syncthreads();
#pragma unroll
    for (int off = 128; off > 0; off >>= 1) {
        if (tid < off) s[tid] += s[tid + off];
        __syncthreads();
    }
    if (tid == 0) bsums[blockIdx.x] = s[0];
}

// parallel exclusive scan of block sums (single 256-thread block, nb<=256)
__global__ __launch_bounds__(256) void scan_bsums_kernel(int* __restrict__ bsums, int nb) {
    __shared__ int s[256];
    int t = threadIdx.x;
    int v = (t < nb) ? bsums[t] : 0;
    s[t] = v;
    __syncthreads();
#pragma unroll
    for (int off = 1; off < 256; off <<= 1) {
        int u = (t >= off) ? s[t - off] : 0;
        __syncthreads();
        s[t] += u;
        __syncthreads();
    }
    if (t < nb) bsums[t] = s[t] - v;      // exclusive
}

__global__ __launch_bounds__(256) void scan_final_kernel(const int* __restrict__ counts,
                                                         const int* __restrict__ bsums,
                                                         int* __restrict__ rowptr,
                                                         int* __restrict__ cursor, int n) {
    __shared__ int s[256];
    int tid = threadIdx.x;
    int i = blockIdx.x * 256 + tid;
    int v = (i < n) ? counts[i] : 0;
    s[tid] = v;
    __syncthreads();
#pragma unroll
    for (int off = 1; off < 256; off <<= 1) {
        int t = (tid >= off) ? s[tid - off] : 0;
        __syncthreads();
        s[tid] += t;
        __syncthreads();
    }
    int excl = s[tid] - v + bsums[blockIdx.x];
    if (i < n) {
        rowptr[i] = excl;
        cursor[i] = excl;
        if (i == n - 1) rowptr[n] = excl + v;
    }
}

__global__ __launch_bounds__(256) void scatter_edges_kernel(const int* __restrict__ row,
                                                            const int* __restrict__ col,
                                                            const float* __restrict__ val,
                                                            int* __restrict__ cursor,
                                                            int* __restrict__ cols_s,
                                                            float* __restrict__ vals_s, int E) {
    int i = blockIdx.x * 256 + threadIdx.x;
    if (i < E) {
        int r = row[i];
        int p = atomicAdd(&cursor[r], 1);
        cols_s[p] = col[i];
        vals_s[p] = val[i];
    }
}

// ---------------------------------------------------------------------------
__device__ __forceinline__ float wave_sum(float v) {
#pragma unroll
    for (int off = 32; off > 0; off >>= 1) v += __shfl_xor(v, off, 64);
    return v;
}
__device__ __forceinline__ float wave_max(float v) {
#pragma unroll
    for (int off = 32; off > 0; off >>= 1) v = fmaxf(v, __shfl_xor(v, off, 64));
    return v;
}

// ---------------------------------------------------------------------------
// Layer-1 fused: dual CSR spmm (fp8 gathers) + attention + combine -> h bf16.
// Self terms read from bf16 buffers (xlh pair-interleaved, xm).
// ---------------------------------------------------------------------------
__global__ __launch_bounds__(256) void spmm_att1(const int* __restrict__ rowptr,
                                                 const int* __restrict__ cols,
                                                 const float* __restrict__ vals,
                                                 const unsigned* __restrict__ xq,
                                                 const short* __restrict__ xlh,
                                                 const short* __restrict__ xm,
                                                 const float* __restrict__ a_low,
                                                 const float* __restrict__ a_high,
                                                 const float* __restrict__ a_mlp,
                                                 const float* __restrict__ av,
                                                 short* __restrict__ hb,
                                                 int n) {
    const int node = blockIdx.x * 4 + (threadIdx.x >> 6);
    const int lane = threadIdx.x & 63;
    if (node >= n) return;
    const uint2* XLH = (const uint2*)xlh;        // [node][64] {xl-pair, xh-pair}
    const unsigned* XM = (const unsigned*)xm;

    const int s = __builtin_amdgcn_readfirstlane(rowptr[node]);
    const int e = __builtin_amdgcn_readfirstlane(rowptr[node + 1]);

    float l0 = 0.f, l1 = 0.f, h0 = 0.f, h1 = 0.f;
    for (int j = s; j < e; j += 8) {
        int   cq[8];
        float vq[8];
#pragma unroll
        for (int q = 0; q < 8; ++q) {
            const int jj = min(j + q, e - 1);
            cq[q] = rfl_i(&cols[jj]);
            const float t = rfl_f(&vals[jj]);
            vq[q] = (j + q < e) ? t : 0.f;
        }
        unsigned p[8];
#pragma unroll
        for (int q = 0; q < 8; ++q)
            p[q] = xq[(size_t)cq[q] * 64 + lane];
#pragma unroll
        for (int q = 0; q < 8; ++q) {
            const f32x2 lo = q2_lo(p[q]);
            const f32x2 hi = q2_hi(p[q]);
            l0 += vq[q] * lo.x; l1 += vq[q] * lo.y;
            h0 += vq[q] * hi.x; h1 += vq[q] * hi.y;
        }
    }

    const uint2 self = XLH[(size_t)node * 64 + lane];
    const unsigned xmn = XM[(size_t)node * 64 + lane];
    float ol0 = fmaxf(l0, 0.f);
    float ol1 = fmaxf(l1, 0.f);
    float oh0 = fmaxf(b2f_lo(self.y) - h0, 0.f);
    float oh1 = fmaxf(b2f_hi(self.y) - h1, 0.f);
    float om0 = fmaxf(b2f_lo(xmn), 0.f);
    float om1 = fmaxf(b2f_hi(xmn), 0.f);

    const float2 aL = ((const float2*)a_low)[lane];
    const float2 aH = ((const float2*)a_high)[lane];
    const float2 aM = ((const float2*)a_mlp)[lane];
    float dl = wave_sum(ol0 * aL.x + ol1 * aL.y);
    float dh = wave_sum(oh0 * aH.x + oh1 * aH.y);
    float dm = wave_sum(om0 * aM.x + om1 * aM.y);

    const float g0 = 1.f / (1.f + expf(-dl));
    const float g1 = 1.f / (1.f + expf(-dh));
    const float g2 = 1.f / (1.f + expf(-dm));
    float s0 = (g0 * av[0] + g1 * av[3] + g2 * av[6]) * (1.f / 3.f);
    float s1 = (g0 * av[1] + g1 * av[4] + g2 * av[7]) * (1.f / 3.f);
    float s2 = (g0 * av[2] + g1 * av[5] + g2 * av[8]) * (1.f / 3.f);
    float mx = fmaxf(s0, fmaxf(s1, s2));
    float e0 = expf(s0 - mx), e1 = expf(s1 - mx), e2 = expf(s2 - mx);
    float inv = 1.f / (e0 + e1 + e2);
    float at0 = e0 * inv, at1 = e1 * inv, at2 = e2 * inv;

    float ho0 = 3.f * (at0 * ol0 + at1 * oh0 + at2 * om0);
    float ho1 = 3.f * (at0 * ol1 + at1 * oh1 + at2 * om1);
    unsigned pk = (unsigned)(unsigned short)f2b(ho0) |
                  ((unsigned)(unsigned short)f2b(ho1) << 16);
    ((unsigned*)hb)[(size_t)node * 64 + lane] = pk;
}

// ---------------------------------------------------------------------------
// Layer-2 fused: dual CSR spmm (fp8 ushort gathers) + attention + combine +
// log_softmax -> out. Self terms from bf16 buffers.
// ---------------------------------------------------------------------------
__global__ __launch_bounds__(256) void spmm_att2(const int* __restrict__ rowptr,
                                                 const int* __restrict__ cols,
                                                 const float* __restrict__ vals,
                                                 const unsigned short* __restrict__ xq,
                                                 const short* __restrict__ xlh,
                                                 const short* __restrict__ xm,
                                                 const float* __restrict__ a_low,
                                                 const float* __restrict__ a_high,
                                                 const float* __restrict__ a_mlp,
                                                 const float* __restrict__ av,
                                                 float* __restrict__ out,
                                                 int n) {
    const int node = blockIdx.x * 4 + (threadIdx.x >> 6);
    const int lane = threadIdx.x & 63;
    if (node >= n) return;
    const unsigned* XLH = (const unsigned*)xlh;  // [node][64] {xl|xh} bf16

    const int s = __builtin_amdgcn_readfirstlane(rowptr[node]);
    const int e = __builtin_amdgcn_readfirstlane(rowptr[node + 1]);

    float accl = 0.f, acch = 0.f;
    for (int j = s; j < e; j += 8) {
        int   cq[8];
        float vq[8];
#pragma unroll
        for (int q = 0; q < 8; ++q) {
            const int jj = min(j + q, e - 1);
            cq[q] = rfl_i(&cols[jj]);
            const float t = rfl_f(&vals[jj]);
            vq[q] = (j + q < e) ? t : 0.f;
        }
        unsigned short p[8];
#pragma unroll
        for (int q = 0; q < 8; ++q)
            p[q] = xq[(size_t)cq[q] * 64 + lane];
#pragma unroll
        for (int q = 0; q < 8; ++q) {
            const f32x2 d = q2_lo((unsigned)p[q]);
            accl += vq[q] * d.x;
            acch += vq[q] * d.y;
        }
    }

    const unsigned self = XLH[(size_t)node * 64 + lane];
    float ol = fmaxf(accl, 0.f);
    float oh = fmaxf(b2f_hi(self) - acch, 0.f);
    float om = fmaxf(b2f(xm[(size_t)node * 64 + lane]), 0.f);

    float dl = wave_sum(ol * a_low[lane]);
    float dh = wave_sum(oh * a_high[lane]);
    float dm = wave_sum(om * a_mlp[lane]);

    const float g0 = 1.f / (1.f + expf(-dl));
    const float g1 = 1.f / (1.f + expf(-dh));
    const float g2 = 1.f / (1.f + expf(-dm));
    float s0 = (g0 * av[0] + g1 * av[3] + g2 * av[6]) * (1.f / 3.f);
    float s1 = (g0 * av[1] + g1 * av[4] + g2 * av[7]) * (1.f / 3.f);
    float s2 = (g0 * av[2] + g1 * av[5] + g2 * av[8]) * (1.f / 3.f);
    float mx3 = fmaxf(s0, fmaxf(s1, s2));
    float e0 = expf(s0 - mx3), e1 = expf(s1 - mx3), e2 = expf(s2 - mx3);
    float inv = 1.f / (e0 + e1 + e2);
    float at0 = e0 * inv, at1 = e1 * inv, at2 = e2 * inv;

    float o = 3.f * (at0 * ol + at1 * oh + at2 * om);

    float m = wave_max(o);
    float ex = expf(o - m);
    float su = wave_sum(ex);
    out[(size_t)node * 64 + lane] = o - m - logf(su);
}

// ---------------------------------------------------------------------------
extern "C" void kernel_launch(void* const* d_in, const int* in_sizes, int n_in,
                              void* d_out, int out_size, void* d_ws, size_t ws_size,
                              hipStream_t stream) {
    const float* x    = (const float*)d_in[0];
    const int*   erow = (const int*)d_in[1];
    const int*   ecol = (const int*)d_in[2];
    const float* eval = (const float*)d_in[3];
    const float* Wl   = (const float*)d_in[4];
    const float* Wh   = (const float*)d_in[5];
    const float* Wm   = (const float*)d_in[6];
    const float* al   = (const float*)d_in[7];
    const float* ah   = (const float*)d_in[8];
    const float* am   = (const float*)d_in[9];
    const float* av   = (const float*)d_in[10];
    const float* Wl2  = (const float*)d_in[11];
    const float* Wh2  = (const float*)d_in[12];
    const float* Wm2  = (const float*)d_in[13];
    const float* al2  = (const float*)d_in[14];
    const float* ah2  = (const float*)d_in[15];
    const float* am2  = (const float*)d_in[16];
    const float* av2  = (const float*)d_in[17];
    float* out = (float*)d_out;

    const int E = in_sizes[1];
    const int N = NN;

    short* ws    = (short*)d_ws;
    short* xb    = ws;                          // N*512 bf16 (converted x)
    short* xlh1  = xb + (size_t)N * 512;        // N*256 bf16 (pair-interleaved)
    short* xm1   = xlh1 + (size_t)N * 256;      // N*128 bf16
    short* hb    = xm1 + (size_t)N * 128;       // N*128 bf16
    short* Bt1   = hb + (size_t)N * 128;        // 384*512
    short* Bt2   = Bt1 + 384 * 512;             // 192*128
    int*   ip    = (int*)(Bt2 + 192 * 128);
    int*   counts = ip;                         // N
    int*   rowptr = ip + N;                     // N+1
    int*   cursor = ip + 2 * N + 1;             // N
    int*   bsums  = ip + 3 * N + 1;             // 256
    int*   cols_s = ip + 3 * N + 1 + 256;       // E
    float* vals_s = (float*)(cols_s + E);       // E

    // fp8 gather buffers alias the dead xb region (gemm1 finished before pack)
    unsigned* xq1 = (unsigned*)xb;              // N*64 dwords (12.8 MB)
    unsigned short* xq2 = (unsigned short*)(xb + (size_t)N * 128);  // N*64 ushorts

    // Layer-2 bf16 aliases (xlh1/xm1 dead after spmm_att1)
    short* xlh2 = xlh1;                         // N*128 bf16 (element-interleaved)
    short* xm2  = xm1;                          // N*64 bf16

    const int NB = (N + 255) / 256;
    const int EB = (E + 255) / 256;
    const int node_blocks = (N + 3) / 4;
    const int MT = (N + 127) / 128;
    const int XCB = (N * F_IN / 8 + 255) / 256;

    // ---------------- conversion + CSR build + weight prep ----------------
    xconv<<<XCB, 256, 0, stream>>>(x, xb, N * F_IN / 8);
    zero_counts<<<NB, 256, 0, stream>>>(counts, N);
    hist_kernel<<<EB, 256, 0, stream>>>(erow, counts, E);
    block_sums_kernel<<<NB, 256, 0, stream>>>(counts, bsums, N);
    scan_bsums_kernel<<<1, 256, 0, stream>>>(bsums, NB);
    scan_final_kernel<<<NB, 256, 0, stream>>>(counts, bsums, rowptr, cursor, N);
    scatter_edges_kernel<<<EB, 256, 0, stream>>>(erow, ecol, eval, cursor, cols_s, vals_s, E);
    wprep<F_IN, HH><<<(3 * HH * (F_IN / 8) + 255) / 256, 256, 0, stream>>>(Wl, Wh, Wm, Bt1);
    wprep<HH, CC><<<(3 * CC * (HH / 8) + 255) / 256, 256, 0, stream>>>(Wl2, Wh2, Wm2, Bt2);

    // ---------------- Layer 1 ----------------
    gemm_mfma<F_IN, HH><<<MT * 3, 256, 0, stream>>>(xb, Bt1, xlh1, xm1, N);
    pack8_1<<<(N * 64 + 255) / 256, 256, 0, stream>>>((const unsigned*)xlh1, xq1, N * 64);
    spmm_att1<<<node_blocks, 256, 0, stream>>>(rowptr, cols_s, vals_s,
                                               xq1, xlh1, xm1, al, ah, am, av, hb, N);

    // ---------------- Layer 2 ----------------
    gemm_mfma<HH, CC><<<MT * 3, 256, 0, stream>>>(hb, Bt2, xlh2, xm2, N);
    pack8_2<<<(N * 32 + 255) / 256, 256, 0, stream>>>((const unsigned*)xlh2,
                                                      (unsigned*)xq2, N * 32);
    spmm_att2<<<node_blocks, 256, 0, stream>>>(rowptr, cols_s, vals_s,
                                               xq2, xlh2, xm2, al2, ah2, am2, av2, out, N);
}

// Round 12
// 258.975 us; speedup vs baseline: 1.4674x; 1.0153x over previous
//
#include <hip/hip_runtime.h>
#include <hip/hip_bf16.h>

// Problem constants (reference file)
#define NN 50000
#define F_IN 512
#define HH 128
#define CC 64

typedef __attribute__((ext_vector_type(8))) short short8v;   // 8 bf16 (4 VGPRs)
typedef __attribute__((ext_vector_type(4))) float f32x4;     // MFMA accumulator
typedef __attribute__((ext_vector_type(2))) float f32x2;

__device__ __forceinline__ short f2b(float f) {
    unsigned u = __builtin_bit_cast(unsigned, f);
    unsigned r = (u + 0x7fffu + ((u >> 16) & 1u)) >> 16;     // RNE
    return (short)r;
}
__device__ __forceinline__ float b2f(short s) {
    unsigned u = ((unsigned)(unsigned short)s) << 16;
    return __builtin_bit_cast(float, u);
}
__device__ __forceinline__ float b2f_lo(unsigned p) {
    return __builtin_bit_cast(float, p << 16);
}
__device__ __forceinline__ float b2f_hi(unsigned p) {
    return __builtin_bit_cast(float, p & 0xffff0000u);
}

// fp8 e4m3 (OCP) decode via gfx950 HW converts
__device__ __forceinline__ f32x2 q2_lo(unsigned p) {   // bytes 0,1
    return __builtin_amdgcn_cvt_pk_f32_fp8(p, false);
}
__device__ __forceinline__ f32x2 q2_hi(unsigned p) {   // bytes 2,3
    return __builtin_amdgcn_cvt_pk_f32_fp8(p, true);
}

// Bijective XCD swizzle (m204)
__device__ __forceinline__ int xcd_swz(int bid, int nwg) {
    int q = nwg >> 3, r = nwg & 7;
    int xcd = bid & 7, off = bid >> 3;
    return (xcd < r ? xcd * (q + 1) : r * (q + 1) + (xcd - r) * q) + off;
}

// async global->LDS, 16 B per lane
__device__ __forceinline__ void load_lds16(const short* g, short* l) {
    __builtin_amdgcn_global_load_lds(
        (const __attribute__((address_space(1))) unsigned int*)g,
        (__attribute__((address_space(3))) unsigned int*)l,
        16, 0, 0);
}

// ---------------------------------------------------------------------------
// x f32 -> bf16 streaming conversion (one-time)
// ---------------------------------------------------------------------------
__global__ __launch_bounds__(256) void xconv(const float* __restrict__ x,
                                             short* __restrict__ xb, int n8) {
    int i = blockIdx.x * 256 + threadIdx.x;
    if (i >= n8) return;
    const float4* xp = (const float4*)x;
    const float4 a = xp[2 * i];
    const float4 b = xp[2 * i + 1];
    short8v o;
    o[0] = f2b(a.x); o[1] = f2b(a.y); o[2] = f2b(a.z); o[3] = f2b(a.w);
    o[4] = f2b(b.x); o[5] = f2b(b.y); o[6] = f2b(b.z); o[7] = f2b(b.w);
    *reinterpret_cast<short8v*>(&xb[(size_t)i * 8]) = o;
}

// ---------------------------------------------------------------------------
// Weight prep: Bt[n][k] = W_{n/OUTW}[k][n%OUTW]  (bf16, transposed + concat)
// ---------------------------------------------------------------------------
template <int K, int OUTW>
__global__ __launch_bounds__(256) void wprep(const float* __restrict__ W0,
                                             const float* __restrict__ W1,
                                             const float* __restrict__ W2,
                                             short* __restrict__ Bt) {
    const int id = blockIdx.x * 256 + threadIdx.x;
    const int nth = 3 * OUTW * (K / 8);
    if (id >= nth) return;
    const int n = id / (K / 8);
    const int kq = id % (K / 8);
    const int sel = n / OUTW;
    const int c = n % OUTW;
    const float* W = sel == 0 ? W0 : (sel == 1 ? W1 : W2);
    short v[8];
#pragma unroll
    for (int j = 0; j < 8; ++j) v[j] = f2b(W[(size_t)(kq * 8 + j) * OUTW + c]);
#pragma unroll
    for (int j = 0; j < 8; ++j) Bt[(size_t)n * K + kq * 8 + j] = v[j];
}

// ---------------------------------------------------------------------------
// MFMA GEMM with global_load_lds staging + XOR slot swizzle.
// Outputs: bn 0/1 -> bf16 interleaved xlh, bn 2 -> bf16 xm.
// ---------------------------------------------------------------------------
template <int K, int BNout>
__global__ __launch_bounds__(256) void gemm_mfma(const short* __restrict__ A,
                                                 const short* __restrict__ Bt,
                                                 short* __restrict__ xlh,
                                                 short* __restrict__ xm,
                                                 int M) {
    constexpr int BM = 128, BK = 64;
    constexpr int FM = (BNout == 128) ? 4 : 2;
    constexpr int FN = 4;
    constexpr int WM = FM * 16;
    constexpr int NKT = K / BK;
    constexpr int NBL = BNout / 32;

    __shared__ short As[BM * BK];
    __shared__ short Bs[BNout * BK];

    const int tid = threadIdx.x;
    const int lane = tid & 63;
    const int wid = tid >> 6;
    const int wg = xcd_swz(blockIdx.x, gridDim.x);
    const int bm = wg / 3;
    const int bn = wg % 3;
    const int m0 = bm * BM;
    const int n0 = bn * BNout;
    const int wm = (BNout == 128) ? (wid >> 1) : wid;
    const int wn = (BNout == 128) ? (wid & 1) : 0;

    const int r8 = lane >> 3;
    const int sl = (lane & 7) ^ r8;

    f32x4 acc[FM][FN];
#pragma unroll
    for (int i = 0; i < FM; ++i)
#pragma unroll
        for (int j = 0; j < FN; ++j) acc[i][j] = (f32x4){0.f, 0.f, 0.f, 0.f};

    for (int kt = 0; kt < NKT; ++kt) {
        const int k0 = kt * BK;
        __syncthreads();
#pragma unroll
        for (int i = 0; i < 4; ++i) {
            int r = (wid * 4 + i) * 8 + r8;
            int gr = m0 + r; if (gr >= M) gr = M - 1;
            load_lds16(&A[(size_t)gr * K + k0 + sl * 8], &As[(wid * 4 + i) * 512]);
        }
#pragma unroll
        for (int i = 0; i < NBL; ++i) {
            int r = (wid * NBL + i) * 8 + r8;
            load_lds16(&Bt[(size_t)(n0 + r) * K + k0 + sl * 8],
                       &Bs[(wid * NBL + i) * 512]);
        }
        __syncthreads();

        const int mrow = lane & 15;
        const int kg = lane >> 4;
#pragma unroll
        for (int kk = 0; kk < 2; ++kk) {
            short8v af[FM], bf[FN];
#pragma unroll
            for (int f = 0; f < FM; ++f) {
                int m = wm * WM + f * 16 + mrow;
                int s = kk * 4 + kg;
                af[f] = *reinterpret_cast<const short8v*>(
                    &As[m * 64 + ((s ^ (m & 7)) << 3)]);
            }
#pragma unroll
            for (int f = 0; f < FN; ++f) {
                int nr = wn * 64 + f * 16 + mrow;
                int s = kk * 4 + kg;
                bf[f] = *reinterpret_cast<const short8v*>(
                    &Bs[nr * 64 + ((s ^ (nr & 7)) << 3)]);
            }
#pragma unroll
            for (int i = 0; i < FM; ++i)
#pragma unroll
                for (int j = 0; j < FN; ++j)
                    acc[i][j] = __builtin_amdgcn_mfma_f32_16x16x32_bf16(
                        af[i], bf[j], acc[i][j], 0, 0, 0);
        }
    }

#pragma unroll
    for (int i = 0; i < FM; ++i)
#pragma unroll
        for (int j = 0; j < FN; ++j) {
            int cc = wn * 64 + j * 16 + (lane & 15);
#pragma unroll
            for (int e = 0; e < 4; ++e) {
                int row = m0 + wm * WM + i * 16 + (lane >> 4) * 4 + e;
                if (row >= M) continue;
                short v = f2b(acc[i][j][e]);
                if (bn == 2) {
                    xm[(size_t)row * BNout + cc] = v;
                } else if (BNout == 128) {
                    xlh[(size_t)row * 256 + (cc >> 1) * 4 + bn * 2 + (cc & 1)] = v;
                } else {
                    xlh[(size_t)row * 128 + cc * 2 + bn] = v;
                }
            }
        }
}

// ---------------------------------------------------------------------------
// fp8 pack kernels (bf16 gather buffers -> fp8 gather buffers)
// ---------------------------------------------------------------------------
__global__ __launch_bounds__(256) void pack8_1(const unsigned* __restrict__ xlh,
                                               unsigned* __restrict__ xq, int n) {
    int i = blockIdx.x * 256 + threadIdx.x;   // over N*64 pairs
    if (i >= n) return;
    const uint2 v = ((const uint2*)xlh)[i];
    unsigned r = __builtin_amdgcn_cvt_pk_fp8_f32(b2f_lo(v.x), b2f_hi(v.x), 0, false);
    r = __builtin_amdgcn_cvt_pk_fp8_f32(b2f_lo(v.y), b2f_hi(v.y), r, true);
    xq[i] = r;
}

__global__ __launch_bounds__(256) void pack8_2(const unsigned* __restrict__ xlh,
                                               unsigned* __restrict__ xq, int n2) {
    int i = blockIdx.x * 256 + threadIdx.x;   // over N*32 dword-pairs
    if (i >= n2) return;
    const uint2 v = ((const uint2*)xlh)[i];
    unsigned lo = __builtin_amdgcn_cvt_pk_fp8_f32(b2f_lo(v.x), b2f_hi(v.x), 0, false);
    unsigned hi = __builtin_amdgcn_cvt_pk_fp8_f32(b2f_lo(v.y), b2f_hi(v.y), 0, false);
    xq[i] = (lo & 0xffffu) | (hi << 16);
}

// ---------------------------------------------------------------------------
// CSR construction (interleaved int2 edge records)
// ---------------------------------------------------------------------------
__global__ __launch_bounds__(256) void zero_counts(int* __restrict__ counts, int n) {
    int i = blockIdx.x * 256 + threadIdx.x;
    if (i < n) counts[i] = 0;
}

__global__ __launch_bounds__(256) void hist_kernel(const int* __restrict__ row,
                                                   int* __restrict__ counts, int E) {
    int i = blockIdx.x * 256 + threadIdx.x;
    if (i < E) atomicAdd(&counts[row[i]], 1);
}

__global__ __launch_bounds__(256) void block_sums_kernel(const int* __restrict__ counts,
                                                         int* __restrict__ bsums, int n) {
    __shared__ int s[256];
    int tid = threadIdx.x;
    int i = blockIdx.x * 256 + tid;
    s[tid] = (i < n) ? counts[i] : 0;
    __syncthreads();
#pragma unroll
    for (int off = 128; off > 0; off >>= 1) {
        if (tid < off) s[tid] += s[tid + off];
        __syncthreads();
    }
    if (tid == 0) bsums[blockIdx.x] = s[0];
}

// parallel exclusive scan of block sums (single 256-thread block, nb<=256)
__global__ __launch_bounds__(256) void scan_bsums_kernel(int* __restrict__ bsums, int nb) {
    __shared__ int s[256];
    int t = threadIdx.x;
    int v = (t < nb) ? bsums[t] : 0;
    s[t] = v;
    __syncthreads();
#pragma unroll
    for (int off = 1; off < 256; off <<= 1) {
        int u = (t >= off) ? s[t - off] : 0;
        __syncthreads();
        s[t] += u;
        __syncthreads();
    }
    if (t < nb) bsums[t] = s[t] - v;      // exclusive
}

__global__ __launch_bounds__(256) void scan_final_kernel(const int* __restrict__ counts,
                                                         const int* __restrict__ bsums,
                                                         int* __restrict__ rowptr,
                                                         int* __restrict__ cursor, int n) {
    __shared__ int s[256];
    int tid = threadIdx.x;
    int i = blockIdx.x * 256 + tid;
    int v = (i < n) ? counts[i] : 0;
    s[tid] = v;
    __syncthreads();
#pragma unroll
    for (int off = 1; off < 256; off <<= 1) {
        int t = (tid >= off) ? s[tid - off] : 0;
        __syncthreads();
        s[tid] += t;
        __syncthreads();
    }
    int excl = s[tid] - v + bsums[blockIdx.x];
    if (i < n) {
        rowptr[i] = excl;
        cursor[i] = excl;
        if (i == n - 1) rowptr[n] = excl + v;
    }
}

__global__ __launch_bounds__(256) void scatter_edges_kernel(const int* __restrict__ row,
                                                            const int* __restrict__ col,
                                                            const float* __restrict__ val,
                                                            int* __restrict__ cursor,
                                                            int2* __restrict__ edges, int E) {
    int i = blockIdx.x * 256 + threadIdx.x;
    if (i < E) {
        int r = row[i];
        int p = atomicAdd(&cursor[r], 1);
        int2 rec;
        rec.x = col[i];
        rec.y = __builtin_bit_cast(int, val[i]);
        edges[p] = rec;                       // single 8B random store
    }
}

// ---------------------------------------------------------------------------
__device__ __forceinline__ float wave_sum(float v) {
#pragma unroll
    for (int off = 32; off > 0; off >>= 1) v += __shfl_xor(v, off, 64);
    return v;
}
__device__ __forceinline__ float wave_max(float v) {
#pragma unroll
    for (int off = 32; off > 0; off >>= 1) v = fmaxf(v, __shfl_xor(v, off, 64));
    return v;
}

// ---------------------------------------------------------------------------
// Layer-1 fused: dual CSR spmm (fp8 gathers) + attention + combine -> h bf16.
// Edge records int2 {col,val}: one broadcast 8B load per edge.
// ---------------------------------------------------------------------------
__global__ __launch_bounds__(256) void spmm_att1(const int* __restrict__ rowptr,
                                                 const int2* __restrict__ edges,
                                                 const unsigned* __restrict__ xq,
                                                 const short* __restrict__ xlh,
                                                 const short* __restrict__ xm,
                                                 const float* __restrict__ a_low,
                                                 const float* __restrict__ a_high,
                                                 const float* __restrict__ a_mlp,
                                                 const float* __restrict__ av,
                                                 short* __restrict__ hb,
                                                 int n) {
    const int node = blockIdx.x * 4 + (threadIdx.x >> 6);
    const int lane = threadIdx.x & 63;
    if (node >= n) return;
    const uint2* XLH = (const uint2*)xlh;        // [node][64] {xl-pair, xh-pair}
    const unsigned* XM = (const unsigned*)xm;

    const int s = __builtin_amdgcn_readfirstlane(rowptr[node]);
    const int e = __builtin_amdgcn_readfirstlane(rowptr[node + 1]);

    float l0 = 0.f, l1 = 0.f, h0 = 0.f, h1 = 0.f;
    for (int j = s; j < e; j += 8) {
        int   cq[8];
        float vq[8];
#pragma unroll
        for (int q = 0; q < 8; ++q) {
            const int jj = min(j + q, e - 1);
            const int2 rec = edges[jj];
            cq[q] = __builtin_amdgcn_readfirstlane(rec.x);
            int vb = __builtin_amdgcn_readfirstlane(rec.y);
            float t = __builtin_bit_cast(float, vb);
            vq[q] = (j + q < e) ? t : 0.f;
        }
        unsigned p[8];
#pragma unroll
        for (int q = 0; q < 8; ++q)
            p[q] = xq[(size_t)cq[q] * 64 + lane];
#pragma unroll
        for (int q = 0; q < 8; ++q) {
            const f32x2 lo = q2_lo(p[q]);
            const f32x2 hi = q2_hi(p[q]);
            l0 += vq[q] * lo.x; l1 += vq[q] * lo.y;
            h0 += vq[q] * hi.x; h1 += vq[q] * hi.y;
        }
    }

    const uint2 self = XLH[(size_t)node * 64 + lane];
    const unsigned xmn = XM[(size_t)node * 64 + lane];
    float ol0 = fmaxf(l0, 0.f);
    float ol1 = fmaxf(l1, 0.f);
    float oh0 = fmaxf(b2f_lo(self.y) - h0, 0.f);
    float oh1 = fmaxf(b2f_hi(self.y) - h1, 0.f);
    float om0 = fmaxf(b2f_lo(xmn), 0.f);
    float om1 = fmaxf(b2f_hi(xmn), 0.f);

    const float2 aL = ((const float2*)a_low)[lane];
    const float2 aH = ((const float2*)a_high)[lane];
    const float2 aM = ((const float2*)a_mlp)[lane];
    float dl = wave_sum(ol0 * aL.x + ol1 * aL.y);
    float dh = wave_sum(oh0 * aH.x + oh1 * aH.y);
    float dm = wave_sum(om0 * aM.x + om1 * aM.y);

    const float g0 = 1.f / (1.f + expf(-dl));
    const float g1 = 1.f / (1.f + expf(-dh));
    const float g2 = 1.f / (1.f + expf(-dm));
    float s0 = (g0 * av[0] + g1 * av[3] + g2 * av[6]) * (1.f / 3.f);
    float s1 = (g0 * av[1] + g1 * av[4] + g2 * av[7]) * (1.f / 3.f);
    float s2 = (g0 * av[2] + g1 * av[5] + g2 * av[8]) * (1.f / 3.f);
    float mx = fmaxf(s0, fmaxf(s1, s2));
    float e0 = expf(s0 - mx), e1 = expf(s1 - mx), e2 = expf(s2 - mx);
    float inv = 1.f / (e0 + e1 + e2);
    float at0 = e0 * inv, at1 = e1 * inv, at2 = e2 * inv;

    float ho0 = 3.f * (at0 * ol0 + at1 * oh0 + at2 * om0);
    float ho1 = 3.f * (at0 * ol1 + at1 * oh1 + at2 * om1);
    unsigned pk = (unsigned)(unsigned short)f2b(ho0) |
                  ((unsigned)(unsigned short)f2b(ho1) << 16);
    ((unsigned*)hb)[(size_t)node * 64 + lane] = pk;
}

// ---------------------------------------------------------------------------
// Layer-2 fused: dual CSR spmm (fp8 ushort gathers) + attention + combine +
// log_softmax -> out.
// ---------------------------------------------------------------------------
__global__ __launch_bounds__(256) void spmm_att2(const int* __restrict__ rowptr,
                                                 const int2* __restrict__ edges,
                                                 const unsigned short* __restrict__ xq,
                                                 const short* __restrict__ xlh,
                                                 const short* __restrict__ xm,
                                                 const float* __restrict__ a_low,
                                                 const float* __restrict__ a_high,
                                                 const float* __restrict__ a_mlp,
                                                 const float* __restrict__ av,
                                                 float* __restrict__ out,
                                                 int n) {
    const int node = blockIdx.x * 4 + (threadIdx.x >> 6);
    const int lane = threadIdx.x & 63;
    if (node >= n) return;
    const unsigned* XLH = (const unsigned*)xlh;  // [node][64] {xl|xh} bf16

    const int s = __builtin_amdgcn_readfirstlane(rowptr[node]);
    const int e = __builtin_amdgcn_readfirstlane(rowptr[node + 1]);

    float accl = 0.f, acch = 0.f;
    for (int j = s; j < e; j += 8) {
        int   cq[8];
        float vq[8];
#pragma unroll
        for (int q = 0; q < 8; ++q) {
            const int jj = min(j + q, e - 1);
            const int2 rec = edges[jj];
            cq[q] = __builtin_amdgcn_readfirstlane(rec.x);
            int vb = __builtin_amdgcn_readfirstlane(rec.y);
            float t = __builtin_bit_cast(float, vb);
            vq[q] = (j + q < e) ? t : 0.f;
        }
        unsigned short p[8];
#pragma unroll
        for (int q = 0; q < 8; ++q)
            p[q] = xq[(size_t)cq[q] * 64 + lane];
#pragma unroll
        for (int q = 0; q < 8; ++q) {
            const f32x2 d = q2_lo((unsigned)p[q]);
            accl += vq[q] * d.x;
            acch += vq[q] * d.y;
        }
    }

    const unsigned self = XLH[(size_t)node * 64 + lane];
    float ol = fmaxf(accl, 0.f);
    float oh = fmaxf(b2f_hi(self) - acch, 0.f);
    float om = fmaxf(b2f(xm[(size_t)node * 64 + lane]), 0.f);

    float dl = wave_sum(ol * a_low[lane]);
    float dh = wave_sum(oh * a_high[lane]);
    float dm = wave_sum(om * a_mlp[lane]);

    const float g0 = 1.f / (1.f + expf(-dl));
    const float g1 = 1.f / (1.f + expf(-dh));
    const float g2 = 1.f / (1.f + expf(-dm));
    float s0 = (g0 * av[0] + g1 * av[3] + g2 * av[6]) * (1.f / 3.f);
    float s1 = (g0 * av[1] + g1 * av[4] + g2 * av[7]) * (1.f / 3.f);
    float s2 = (g0 * av[2] + g1 * av[5] + g2 * av[8]) * (1.f / 3.f);
    float mx3 = fmaxf(s0, fmaxf(s1, s2));
    float e0 = expf(s0 - mx3), e1 = expf(s1 - mx3), e2 = expf(s2 - mx3);
    float inv = 1.f / (e0 + e1 + e2);
    float at0 = e0 * inv, at1 = e1 * inv, at2 = e2 * inv;

    float o = 3.f * (at0 * ol + at1 * oh + at2 * om);

    float m = wave_max(o);
    float ex = expf(o - m);
    float su = wave_sum(ex);
    out[(size_t)node * 64 + lane] = o - m - logf(su);
}

// ---------------------------------------------------------------------------
extern "C" void kernel_launch(void* const* d_in, const int* in_sizes, int n_in,
                              void* d_out, int out_size, void* d_ws, size_t ws_size,
                              hipStream_t stream) {
    const float* x    = (const float*)d_in[0];
    const int*   erow = (const int*)d_in[1];
    const int*   ecol = (const int*)d_in[2];
    const float* eval = (const float*)d_in[3];
    const float* Wl   = (const float*)d_in[4];
    const float* Wh   = (const float*)d_in[5];
    const float* Wm   = (const float*)d_in[6];
    const float* al   = (const float*)d_in[7];
    const float* ah   = (const float*)d_in[8];
    const float* am   = (const float*)d_in[9];
    const float* av   = (const float*)d_in[10];
    const float* Wl2  = (const float*)d_in[11];
    const float* Wh2  = (const float*)d_in[12];
    const float* Wm2  = (const float*)d_in[13];
    const float* al2  = (const float*)d_in[14];
    const float* ah2  = (const float*)d_in[15];
    const float* am2  = (const float*)d_in[16];
    const float* av2  = (const float*)d_in[17];
    float* out = (float*)d_out;

    const int E = in_sizes[1];
    const int N = NN;

    short* ws    = (short*)d_ws;
    short* xb    = ws;                          // N*512 bf16 (converted x)
    short* xlh1  = xb + (size_t)N * 512;        // N*256 bf16 (pair-interleaved)
    short* xm1   = xlh1 + (size_t)N * 256;      // N*128 bf16
    short* hb    = xm1 + (size_t)N * 128;       // N*128 bf16
    short* Bt1   = hb + (size_t)N * 128;        // 384*512
    short* Bt2   = Bt1 + 384 * 512;             // 192*128
    int*   ip    = (int*)(Bt2 + 192 * 128);
    int*   counts = ip;                         // N
    int*   rowptr = ip + N;                     // N+1
    int*   cursor = ip + 2 * N + 1;             // N
    int*   bsums  = ip + 3 * N + 1;             // 256
    int2*  edges  = (int2*)(((size_t)(ip + 3 * N + 1 + 256) + 15) & ~(size_t)15); // E int2

    // fp8 gather buffers alias the dead xb region
    unsigned* xq1 = (unsigned*)xb;              // N*64 dwords (12.8 MB)
    unsigned short* xq2 = (unsigned short*)(xb + (size_t)N * 128);  // N*64 ushorts

    // Layer-2 bf16 aliases (xlh1/xm1 dead after spmm_att1)
    short* xlh2 = xlh1;                         // N*128 bf16 (element-interleaved)
    short* xm2  = xm1;                          // N*64 bf16

    const int NB = (N + 255) / 256;
    const int EB = (E + 255) / 256;
    const int node_blocks = (N + 3) / 4;
    const int MT = (N + 127) / 128;
    const int XCB = (N * F_IN / 8 + 255) / 256;

    // ---------------- conversion + CSR build + weight prep ----------------
    xconv<<<XCB, 256, 0, stream>>>(x, xb, N * F_IN / 8);
    zero_counts<<<NB, 256, 0, stream>>>(counts, N);
    hist_kernel<<<EB, 256, 0, stream>>>(erow, counts, E);
    block_sums_kernel<<<NB, 256, 0, stream>>>(counts, bsums, N);
    scan_bsums_kernel<<<1, 256, 0, stream>>>(bsums, NB);
    scan_final_kernel<<<NB, 256, 0, stream>>>(counts, bsums, rowptr, cursor, N);
    scatter_edges_kernel<<<EB, 256, 0, stream>>>(erow, ecol, eval, cursor, edges, E);
    wprep<F_IN, HH><<<(3 * HH * (F_IN / 8) + 255) / 256, 256, 0, stream>>>(Wl, Wh, Wm, Bt1);
    wprep<HH, CC><<<(3 * CC * (HH / 8) + 255) / 256, 256, 0, stream>>>(Wl2, Wh2, Wm2, Bt2);

    // ---------------- Layer 1 ----------------
    gemm_mfma<F_IN, HH><<<MT * 3, 256, 0, stream>>>(xb, Bt1, xlh1, xm1, N);
    pack8_1<<<(N * 64 + 255) / 256, 256, 0, stream>>>((const unsigned*)xlh1, xq1, N * 64);
    spmm_att1<<<node_blocks, 256, 0, stream>>>(rowptr, edges,
                                               xq1, xlh1, xm1, al, ah, am, av, hb, N);

    // ---------------- Layer 2 ----------------
    gemm_mfma<HH, CC><<<MT * 3, 256, 0, stream>>>(hb, Bt2, xlh2, xm2, N);
    pack8_2<<<(N * 32 + 255) / 256, 256, 0, stream>>>((const unsigned*)xlh2,
                                                      (unsigned*)xq2, N * 32);
    spmm_att2<<<node_blocks, 256, 0, stream>>>(rowptr, edges,
                                               xq2, xlh2, xm2, al2, ah2, am2, av2, out, N);
}

// Round 13
// 242.776 us; speedup vs baseline: 1.5653x; 1.0667x over previous
//
#include <hip/hip_runtime.h>
#include <hip/hip_bf16.h>

// Problem constants (reference file)
#define NN 50000
#define F_IN 512
#define HH 128
#define CC 64

typedef __attribute__((ext_vector_type(8))) short short8v;   // 8 bf16 (4 VGPRs)
typedef __attribute__((ext_vector_type(4))) float f32x4;     // MFMA accumulator
typedef __attribute__((ext_vector_type(2))) float f32x2;

__device__ __forceinline__ short f2b(float f) {
    unsigned u = __builtin_bit_cast(unsigned, f);
    unsigned r = (u + 0x7fffu + ((u >> 16) & 1u)) >> 16;     // RNE
    return (short)r;
}
__device__ __forceinline__ float b2f(short s) {
    unsigned u = ((unsigned)(unsigned short)s) << 16;
    return __builtin_bit_cast(float, u);
}
__device__ __forceinline__ float b2f_lo(unsigned p) {
    return __builtin_bit_cast(float, p << 16);
}
__device__ __forceinline__ float b2f_hi(unsigned p) {
    return __builtin_bit_cast(float, p & 0xffff0000u);
}

// fp8 e4m3 (OCP) decode via gfx950 HW converts
__device__ __forceinline__ f32x2 q2_lo(unsigned p) {   // bytes 0,1
    return __builtin_amdgcn_cvt_pk_f32_fp8(p, false);
}
__device__ __forceinline__ f32x2 q2_hi(unsigned p) {   // bytes 2,3
    return __builtin_amdgcn_cvt_pk_f32_fp8(p, true);
}

// Bijective XCD swizzle (m204)
__device__ __forceinline__ int xcd_swz(int bid, int nwg) {
    int q = nwg >> 3, r = nwg & 7;
    int xcd = bid & 7, off = bid >> 3;
    return (xcd < r ? xcd * (q + 1) : r * (q + 1) + (xcd - r) * q) + off;
}

// async global->LDS, 16 B per lane
__device__ __forceinline__ void load_lds16(const short* g, short* l) {
    __builtin_amdgcn_global_load_lds(
        (const __attribute__((address_space(1))) unsigned int*)g,
        (__attribute__((address_space(3))) unsigned int*)l,
        16, 0, 0);
}

// ---------------------------------------------------------------------------
// Weight prep body
// ---------------------------------------------------------------------------
template <int K, int OUTW>
__device__ __forceinline__ void wprep_body(const float* __restrict__ W0,
                                           const float* __restrict__ W1,
                                           const float* __restrict__ W2,
                                           short* __restrict__ Bt, int id) {
    const int nth = 3 * OUTW * (K / 8);
    if (id >= nth) return;
    const int n = id / (K / 8);
    const int kq = id % (K / 8);
    const int sel = n / OUTW;
    const int c = n % OUTW;
    const float* W = sel == 0 ? W0 : (sel == 1 ? W1 : W2);
    short v[8];
#pragma unroll
    for (int j = 0; j < 8; ++j) v[j] = f2b(W[(size_t)(kq * 8 + j) * OUTW + c]);
#pragma unroll
    for (int j = 0; j < 8; ++j) Bt[(size_t)n * K + kq * 8 + j] = v[j];
}

// ---------------------------------------------------------------------------
// prep0: zero_counts + wprep(L1) + wprep(L2) in one launch
// ---------------------------------------------------------------------------
__global__ __launch_bounds__(256) void prep0(int* __restrict__ counts, int n,
                                             const float* __restrict__ Wl,
                                             const float* __restrict__ Wh,
                                             const float* __restrict__ Wm,
                                             short* __restrict__ Bt1,
                                             const float* __restrict__ Wl2,
                                             const float* __restrict__ Wh2,
                                             const float* __restrict__ Wm2,
                                             short* __restrict__ Bt2,
                                             int nZero, int nW1) {
    const int b = blockIdx.x;
    if (b < nZero) {
        int i = b * 256 + threadIdx.x;
        if (i < n) counts[i] = 0;
    } else if (b < nZero + nW1) {
        wprep_body<F_IN, HH>(Wl, Wh, Wm, Bt1, (b - nZero) * 256 + threadIdx.x);
    } else {
        wprep_body<HH, CC>(Wl2, Wh2, Wm2, Bt2, (b - nZero - nW1) * 256 + threadIdx.x);
    }
}

// ---------------------------------------------------------------------------
// hist_xconv: histogram atomics (latency) hidden under xconv (BW)
// ---------------------------------------------------------------------------
__global__ __launch_bounds__(256) void hist_xconv(const int* __restrict__ erow,
                                                  int* __restrict__ counts, int E,
                                                  const float* __restrict__ x,
                                                  short* __restrict__ xb, int n8,
                                                  int nHist) {
    const int b = blockIdx.x;
    if (b < nHist) {
        int i = b * 256 + threadIdx.x;
        if (i < E) atomicAdd(&counts[erow[i]], 1);
        return;
    }
    int i = (b - nHist) * 256 + threadIdx.x;
    if (i >= n8) return;
    const float4* xp = (const float4*)x;
    const float4 a = xp[2 * i];
    const float4 bb = xp[2 * i + 1];
    short8v o;
    o[0] = f2b(a.x); o[1] = f2b(a.y); o[2] = f2b(a.z); o[3] = f2b(a.w);
    o[4] = f2b(bb.x); o[5] = f2b(bb.y); o[6] = f2b(bb.z); o[7] = f2b(bb.w);
    *reinterpret_cast<short8v*>(&xb[(size_t)i * 8]) = o;
}

// ---------------------------------------------------------------------------
// Fused layer-1 GEMM + edge scatter. Gemm blocks [0, nGemm); scatter after.
// Gemm: MFMA + global_load_lds + XOR slot swizzle; outputs interleaved bf16.
// ---------------------------------------------------------------------------
template <int K, int BNout>
__global__ __launch_bounds__(256) void gemm_scatter(const short* __restrict__ A,
                                                    const short* __restrict__ Bt,
                                                    short* __restrict__ xlh,
                                                    short* __restrict__ xm,
                                                    int M, int nGemm,
                                                    const int* __restrict__ row,
                                                    const int* __restrict__ col,
                                                    const float* __restrict__ val,
                                                    int* __restrict__ cursor,
                                                    int2* __restrict__ edges, int E) {
    constexpr int BM = 128, BK = 64;
    constexpr int FM = (BNout == 128) ? 4 : 2;
    constexpr int FN = 4;
    constexpr int WM = FM * 16;
    constexpr int NKT = K / BK;
    constexpr int NBL = BNout / 32;

    __shared__ short As[BM * BK];
    __shared__ short Bs[BNout * BK];

    if ((int)blockIdx.x >= nGemm) {
        // ---- edge scatter path ----
        int i = ((int)blockIdx.x - nGemm) * 256 + threadIdx.x;
        if (i < E) {
            int r = row[i];
            int p = atomicAdd(&cursor[r], 1);
            int2 rec;
            rec.x = col[i];
            rec.y = __builtin_bit_cast(int, val[i]);
            edges[p] = rec;
        }
        return;
    }

    const int tid = threadIdx.x;
    const int lane = tid & 63;
    const int wid = tid >> 6;
    const int wg = xcd_swz(blockIdx.x, nGemm);
    const int bm = wg / 3;
    const int bn = wg % 3;
    const int m0 = bm * BM;
    const int n0 = bn * BNout;
    const int wm = (BNout == 128) ? (wid >> 1) : wid;
    const int wn = (BNout == 128) ? (wid & 1) : 0;

    const int r8 = lane >> 3;
    const int sl = (lane & 7) ^ r8;

    f32x4 acc[FM][FN];
#pragma unroll
    for (int i = 0; i < FM; ++i)
#pragma unroll
        for (int j = 0; j < FN; ++j) acc[i][j] = (f32x4){0.f, 0.f, 0.f, 0.f};

    for (int kt = 0; kt < NKT; ++kt) {
        const int k0 = kt * BK;
        __syncthreads();
#pragma unroll
        for (int i = 0; i < 4; ++i) {
            int r = (wid * 4 + i) * 8 + r8;
            int gr = m0 + r; if (gr >= M) gr = M - 1;
            load_lds16(&A[(size_t)gr * K + k0 + sl * 8], &As[(wid * 4 + i) * 512]);
        }
#pragma unroll
        for (int i = 0; i < NBL; ++i) {
            int r = (wid * NBL + i) * 8 + r8;
            load_lds16(&Bt[(size_t)(n0 + r) * K + k0 + sl * 8],
                       &Bs[(wid * NBL + i) * 512]);
        }
        __syncthreads();

        const int mrow = lane & 15;
        const int kg = lane >> 4;
#pragma unroll
        for (int kk = 0; kk < 2; ++kk) {
            short8v af[FM], bf[FN];
#pragma unroll
            for (int f = 0; f < FM; ++f) {
                int m = wm * WM + f * 16 + mrow;
                int s = kk * 4 + kg;
                af[f] = *reinterpret_cast<const short8v*>(
                    &As[m * 64 + ((s ^ (m & 7)) << 3)]);
            }
#pragma unroll
            for (int f = 0; f < FN; ++f) {
                int nr = wn * 64 + f * 16 + mrow;
                int s = kk * 4 + kg;
                bf[f] = *reinterpret_cast<const short8v*>(
                    &Bs[nr * 64 + ((s ^ (nr & 7)) << 3)]);
            }
#pragma unroll
            for (int i = 0; i < FM; ++i)
#pragma unroll
                for (int j = 0; j < FN; ++j)
                    acc[i][j] = __builtin_amdgcn_mfma_f32_16x16x32_bf16(
                        af[i], bf[j], acc[i][j], 0, 0, 0);
        }
    }

#pragma unroll
    for (int i = 0; i < FM; ++i)
#pragma unroll
        for (int j = 0; j < FN; ++j) {
            int cc = wn * 64 + j * 16 + (lane & 15);
#pragma unroll
            for (int e = 0; e < 4; ++e) {
                int rrow = m0 + wm * WM + i * 16 + (lane >> 4) * 4 + e;
                if (rrow >= M) continue;
                short v = f2b(acc[i][j][e]);
                if (bn == 2) {
                    xm[(size_t)rrow * BNout + cc] = v;
                } else if (BNout == 128) {
                    xlh[(size_t)rrow * 256 + (cc >> 1) * 4 + bn * 2 + (cc & 1)] = v;
                } else {
                    xlh[(size_t)rrow * 128 + cc * 2 + bn] = v;
                }
            }
        }
}

// ---------------------------------------------------------------------------
// Standalone layer-2 GEMM (same structure, no fusion partner)
// ---------------------------------------------------------------------------
template <int K, int BNout>
__global__ __launch_bounds__(256) void gemm_mfma(const short* __restrict__ A,
                                                 const short* __restrict__ Bt,
                                                 short* __restrict__ xlh,
                                                 short* __restrict__ xm,
                                                 int M) {
    constexpr int BM = 128, BK = 64;
    constexpr int FM = (BNout == 128) ? 4 : 2;
    constexpr int FN = 4;
    constexpr int WM = FM * 16;
    constexpr int NKT = K / BK;
    constexpr int NBL = BNout / 32;

    __shared__ short As[BM * BK];
    __shared__ short Bs[BNout * BK];

    const int tid = threadIdx.x;
    const int lane = tid & 63;
    const int wid = tid >> 6;
    const int wg = xcd_swz(blockIdx.x, gridDim.x);
    const int bm = wg / 3;
    const int bn = wg % 3;
    const int m0 = bm * BM;
    const int n0 = bn * BNout;
    const int wm = (BNout == 128) ? (wid >> 1) : wid;
    const int wn = (BNout == 128) ? (wid & 1) : 0;

    const int r8 = lane >> 3;
    const int sl = (lane & 7) ^ r8;

    f32x4 acc[FM][FN];
#pragma unroll
    for (int i = 0; i < FM; ++i)
#pragma unroll
        for (int j = 0; j < FN; ++j) acc[i][j] = (f32x4){0.f, 0.f, 0.f, 0.f};

    for (int kt = 0; kt < NKT; ++kt) {
        const int k0 = kt * BK;
        __syncthreads();
#pragma unroll
        for (int i = 0; i < 4; ++i) {
            int r = (wid * 4 + i) * 8 + r8;
            int gr = m0 + r; if (gr >= M) gr = M - 1;
            load_lds16(&A[(size_t)gr * K + k0 + sl * 8], &As[(wid * 4 + i) * 512]);
        }
#pragma unroll
        for (int i = 0; i < NBL; ++i) {
            int r = (wid * NBL + i) * 8 + r8;
            load_lds16(&Bt[(size_t)(n0 + r) * K + k0 + sl * 8],
                       &Bs[(wid * NBL + i) * 512]);
        }
        __syncthreads();

        const int mrow = lane & 15;
        const int kg = lane >> 4;
#pragma unroll
        for (int kk = 0; kk < 2; ++kk) {
            short8v af[FM], bf[FN];
#pragma unroll
            for (int f = 0; f < FM; ++f) {
                int m = wm * WM + f * 16 + mrow;
                int s = kk * 4 + kg;
                af[f] = *reinterpret_cast<const short8v*>(
                    &As[m * 64 + ((s ^ (m & 7)) << 3)]);
            }
#pragma unroll
            for (int f = 0; f < FN; ++f) {
                int nr = wn * 64 + f * 16 + mrow;
                int s = kk * 4 + kg;
                bf[f] = *reinterpret_cast<const short8v*>(
                    &Bs[nr * 64 + ((s ^ (nr & 7)) << 3)]);
            }
#pragma unroll
            for (int i = 0; i < FM; ++i)
#pragma unroll
                for (int j = 0; j < FN; ++j)
                    acc[i][j] = __builtin_amdgcn_mfma_f32_16x16x32_bf16(
                        af[i], bf[j], acc[i][j], 0, 0, 0);
        }
    }

#pragma unroll
    for (int i = 0; i < FM; ++i)
#pragma unroll
        for (int j = 0; j < FN; ++j) {
            int cc = wn * 64 + j * 16 + (lane & 15);
#pragma unroll
            for (int e = 0; e < 4; ++e) {
                int row = m0 + wm * WM + i * 16 + (lane >> 4) * 4 + e;
                if (row >= M) continue;
                short v = f2b(acc[i][j][e]);
                if (bn == 2) {
                    xm[(size_t)row * BNout + cc] = v;
                } else if (BNout == 128) {
                    xlh[(size_t)row * 256 + (cc >> 1) * 4 + bn * 2 + (cc & 1)] = v;
                } else {
                    xlh[(size_t)row * 128 + cc * 2 + bn] = v;
                }
            }
        }
}

// ---------------------------------------------------------------------------
// fp8 pack kernels (bf16 gather buffers -> fp8 gather buffers)
// ---------------------------------------------------------------------------
__global__ __launch_bounds__(256) void pack8_1(const unsigned* __restrict__ xlh,
                                               unsigned* __restrict__ xq, int n) {
    int i = blockIdx.x * 256 + threadIdx.x;   // over N*64 pairs
    if (i >= n) return;
    const uint2 v = ((const uint2*)xlh)[i];
    unsigned r = __builtin_amdgcn_cvt_pk_fp8_f32(b2f_lo(v.x), b2f_hi(v.x), 0, false);
    r = __builtin_amdgcn_cvt_pk_fp8_f32(b2f_lo(v.y), b2f_hi(v.y), r, true);
    xq[i] = r;
}

__global__ __launch_bounds__(256) void pack8_2(const unsigned* __restrict__ xlh,
                                               unsigned* __restrict__ xq, int n2) {
    int i = blockIdx.x * 256 + threadIdx.x;   // over N*32 dword-pairs
    if (i >= n2) return;
    const uint2 v = ((const uint2*)xlh)[i];
    unsigned lo = __builtin_amdgcn_cvt_pk_fp8_f32(b2f_lo(v.x), b2f_hi(v.x), 0, false);
    unsigned hi = __builtin_amdgcn_cvt_pk_fp8_f32(b2f_lo(v.y), b2f_hi(v.y), 0, false);
    xq[i] = (lo & 0xffffu) | (hi << 16);
}

// ---------------------------------------------------------------------------
// CSR scan chain
// ---------------------------------------------------------------------------
__global__ __launch_bounds__(256) void block_sums_kernel(const int* __restrict__ counts,
                                                         int* __restrict__ bsums, int n) {
    __shared__ int s[256];
    int tid = threadIdx.x;
    int i = blockIdx.x * 256 + tid;
    s[tid] = (i < n) ? counts[i] : 0;
    __syncthreads();
#pragma unroll
    for (int off = 128; off > 0; off >>= 1) {
        if (tid < off) s[tid] += s[tid + off];
        __syncthreads();
    }
    if (tid == 0) bsums[blockIdx.x] = s[0];
}

__global__ __launch_bounds__(256) void scan_bsums_kernel(int* __restrict__ bsums, int nb) {
    __shared__ int s[256];
    int t = threadIdx.x;
    int v = (t < nb) ? bsums[t] : 0;
    s[t] = v;
    __syncthreads();
#pragma unroll
    for (int off = 1; off < 256; off <<= 1) {
        int u = (t >= off) ? s[t - off] : 0;
        __syncthreads();
        s[t] += u;
        __syncthreads();
    }
    if (t < nb) bsums[t] = s[t] - v;      // exclusive
}

__global__ __launch_bounds__(256) void scan_final_kernel(const int* __restrict__ counts,
                                                         const int* __restrict__ bsums,
                                                         int* __restrict__ rowptr,
                                                         int* __restrict__ cursor, int n) {
    __shared__ int s[256];
    int tid = threadIdx.x;
    int i = blockIdx.x * 256 + tid;
    int v = (i < n) ? counts[i] : 0;
    s[tid] = v;
    __syncthreads();
#pragma unroll
    for (int off = 1; off < 256; off <<= 1) {
        int t = (tid >= off) ? s[tid - off] : 0;
        __syncthreads();
        s[tid] += t;
        __syncthreads();
    }
    int excl = s[tid] - v + bsums[blockIdx.x];
    if (i < n) {
        rowptr[i] = excl;
        cursor[i] = excl;
        if (i == n - 1) rowptr[n] = excl + v;
    }
}

// ---------------------------------------------------------------------------
__device__ __forceinline__ float wave_sum(float v) {
#pragma unroll
    for (int off = 32; off > 0; off >>= 1) v += __shfl_xor(v, off, 64);
    return v;
}
__device__ __forceinline__ float wave_max(float v) {
#pragma unroll
    for (int off = 32; off > 0; off >>= 1) v = fmaxf(v, __shfl_xor(v, off, 64));
    return v;
}

// ---------------------------------------------------------------------------
// Layer-1 fused: dual CSR spmm (fp8 gathers) + attention + combine -> h bf16.
// ---------------------------------------------------------------------------
__global__ __launch_bounds__(256) void spmm_att1(const int* __restrict__ rowptr,
                                                 const int2* __restrict__ edges,
                                                 const unsigned* __restrict__ xq,
                                                 const short* __restrict__ xlh,
                                                 const short* __restrict__ xm,
                                                 const float* __restrict__ a_low,
                                                 const float* __restrict__ a_high,
                                                 const float* __restrict__ a_mlp,
                                                 const float* __restrict__ av,
                                                 short* __restrict__ hb,
                                                 int n) {
    const int node = blockIdx.x * 4 + (threadIdx.x >> 6);
    const int lane = threadIdx.x & 63;
    if (node >= n) return;
    const uint2* XLH = (const uint2*)xlh;        // [node][64] {xl-pair, xh-pair}
    const unsigned* XM = (const unsigned*)xm;

    const int s = __builtin_amdgcn_readfirstlane(rowptr[node]);
    const int e = __builtin_amdgcn_readfirstlane(rowptr[node + 1]);

    float l0 = 0.f, l1 = 0.f, h0 = 0.f, h1 = 0.f;
    for (int j = s; j < e; j += 8) {
        int   cq[8];
        float vq[8];
#pragma unroll
        for (int q = 0; q < 8; ++q) {
            const int jj = min(j + q, e - 1);
            const int2 rec = edges[jj];
            cq[q] = __builtin_amdgcn_readfirstlane(rec.x);
            int vb = __builtin_amdgcn_readfirstlane(rec.y);
            float t = __builtin_bit_cast(float, vb);
            vq[q] = (j + q < e) ? t : 0.f;
        }
        unsigned p[8];
#pragma unroll
        for (int q = 0; q < 8; ++q)
            p[q] = xq[(size_t)cq[q] * 64 + lane];
#pragma unroll
        for (int q = 0; q < 8; ++q) {
            const f32x2 lo = q2_lo(p[q]);
            const f32x2 hi = q2_hi(p[q]);
            l0 += vq[q] * lo.x; l1 += vq[q] * lo.y;
            h0 += vq[q] * hi.x; h1 += vq[q] * hi.y;
        }
    }

    const uint2 self = XLH[(size_t)node * 64 + lane];
    const unsigned xmn = XM[(size_t)node * 64 + lane];
    float ol0 = fmaxf(l0, 0.f);
    float ol1 = fmaxf(l1, 0.f);
    float oh0 = fmaxf(b2f_lo(self.y) - h0, 0.f);
    float oh1 = fmaxf(b2f_hi(self.y) - h1, 0.f);
    float om0 = fmaxf(b2f_lo(xmn), 0.f);
    float om1 = fmaxf(b2f_hi(xmn), 0.f);

    const float2 aL = ((const float2*)a_low)[lane];
    const float2 aH = ((const float2*)a_high)[lane];
    const float2 aM = ((const float2*)a_mlp)[lane];
    float dl = wave_sum(ol0 * aL.x + ol1 * aL.y);
    float dh = wave_sum(oh0 * aH.x + oh1 * aH.y);
    float dm = wave_sum(om0 * aM.x + om1 * aM.y);

    const float g0 = 1.f / (1.f + expf(-dl));
    const float g1 = 1.f / (1.f + expf(-dh));
    const float g2 = 1.f / (1.f + expf(-dm));
    float s0 = (g0 * av[0] + g1 * av[3] + g2 * av[6]) * (1.f / 3.f);
    float s1 = (g0 * av[1] + g1 * av[4] + g2 * av[7]) * (1.f / 3.f);
    float s2 = (g0 * av[2] + g1 * av[5] + g2 * av[8]) * (1.f / 3.f);
    float mx = fmaxf(s0, fmaxf(s1, s2));
    float e0 = expf(s0 - mx), e1 = expf(s1 - mx), e2 = expf(s2 - mx);
    float inv = 1.f / (e0 + e1 + e2);
    float at0 = e0 * inv, at1 = e1 * inv, at2 = e2 * inv;

    float ho0 = 3.f * (at0 * ol0 + at1 * oh0 + at2 * om0);
    float ho1 = 3.f * (at0 * ol1 + at1 * oh1 + at2 * om1);
    unsigned pk = (unsigned)(unsigned short)f2b(ho0) |
                  ((unsigned)(unsigned short)f2b(ho1) << 16);
    ((unsigned*)hb)[(size_t)node * 64 + lane] = pk;
}

// ---------------------------------------------------------------------------
// Layer-2 fused: dual CSR spmm (fp8 ushort gathers) + attention + combine +
// log_softmax -> out.
// ---------------------------------------------------------------------------
__global__ __launch_bounds__(256) void spmm_att2(const int* __restrict__ rowptr,
                                                 const int2* __restrict__ edges,
                                                 const unsigned short* __restrict__ xq,
                                                 const short* __restrict__ xlh,
                                                 const short* __restrict__ xm,
                                                 const float* __restrict__ a_low,
                                                 const float* __restrict__ a_high,
                                                 const float* __restrict__ a_mlp,
                                                 const float* __restrict__ av,
                                                 float* __restrict__ out,
                                                 int n) {
    const int node = blockIdx.x * 4 + (threadIdx.x >> 6);
    const int lane = threadIdx.x & 63;
    if (node >= n) return;
    const unsigned* XLH = (const unsigned*)xlh;  // [node][64] {xl|xh} bf16

    const int s = __builtin_amdgcn_readfirstlane(rowptr[node]);
    const int e = __builtin_amdgcn_readfirstlane(rowptr[node + 1]);

    float accl = 0.f, acch = 0.f;
    for (int j = s; j < e; j += 8) {
        int   cq[8];
        float vq[8];
#pragma unroll
        for (int q = 0; q < 8; ++q) {
            const int jj = min(j + q, e - 1);
            const int2 rec = edges[jj];
            cq[q] = __builtin_amdgcn_readfirstlane(rec.x);
            int vb = __builtin_amdgcn_readfirstlane(rec.y);
            float t = __builtin_bit_cast(float, vb);
            vq[q] = (j + q < e) ? t : 0.f;
        }
        unsigned short p[8];
#pragma unroll
        for (int q = 0; q < 8; ++q)
            p[q] = xq[(size_t)cq[q] * 64 + lane];
#pragma unroll
        for (int q = 0; q < 8; ++q) {
            const f32x2 d = q2_lo((unsigned)p[q]);
            accl += vq[q] * d.x;
            acch += vq[q] * d.y;
        }
    }

    const unsigned self = XLH[(size_t)node * 64 + lane];
    float ol = fmaxf(accl, 0.f);
    float oh = fmaxf(b2f_hi(self) - acch, 0.f);
    float om = fmaxf(b2f(xm[(size_t)node * 64 + lane]), 0.f);

    float dl = wave_sum(ol * a_low[lane]);
    float dh = wave_sum(oh * a_high[lane]);
    float dm = wave_sum(om * a_mlp[lane]);

    const float g0 = 1.f / (1.f + expf(-dl));
    const float g1 = 1.f / (1.f + expf(-dh));
    const float g2 = 1.f / (1.f + expf(-dm));
    float s0 = (g0 * av[0] + g1 * av[3] + g2 * av[6]) * (1.f / 3.f);
    float s1 = (g0 * av[1] + g1 * av[4] + g2 * av[7]) * (1.f / 3.f);
    float s2 = (g0 * av[2] + g1 * av[5] + g2 * av[8]) * (1.f / 3.f);
    float mx3 = fmaxf(s0, fmaxf(s1, s2));
    float e0 = expf(s0 - mx3), e1 = expf(s1 - mx3), e2 = expf(s2 - mx3);
    float inv = 1.f / (e0 + e1 + e2);
    float at0 = e0 * inv, at1 = e1 * inv, at2 = e2 * inv;

    float o = 3.f * (at0 * ol + at1 * oh + at2 * om);

    float m = wave_max(o);
    float ex = expf(o - m);
    float su = wave_sum(ex);
    out[(size_t)node * 64 + lane] = o - m - logf(su);
}

// ---------------------------------------------------------------------------
extern "C" void kernel_launch(void* const* d_in, const int* in_sizes, int n_in,
                              void* d_out, int out_size, void* d_ws, size_t ws_size,
                              hipStream_t stream) {
    const float* x    = (const float*)d_in[0];
    const int*   erow = (const int*)d_in[1];
    const int*   ecol = (const int*)d_in[2];
    const float* eval = (const float*)d_in[3];
    const float* Wl   = (const float*)d_in[4];
    const float* Wh   = (const float*)d_in[5];
    const float* Wm   = (const float*)d_in[6];
    const float* al   = (const float*)d_in[7];
    const float* ah   = (const float*)d_in[8];
    const float* am   = (const float*)d_in[9];
    const float* av   = (const float*)d_in[10];
    const float* Wl2  = (const float*)d_in[11];
    const float* Wh2  = (const float*)d_in[12];
    const float* Wm2  = (const float*)d_in[13];
    const float* al2  = (const float*)d_in[14];
    const float* ah2  = (const float*)d_in[15];
    const float* am2  = (const float*)d_in[16];
    const float* av2  = (const float*)d_in[17];
    float* out = (float*)d_out;

    const int E = in_sizes[1];
    const int N = NN;

    short* ws    = (short*)d_ws;
    short* xb    = ws;                          // N*512 bf16 (converted x)
    short* xlh1  = xb + (size_t)N * 512;        // N*256 bf16 (pair-interleaved)
    short* xm1   = xlh1 + (size_t)N * 256;      // N*128 bf16
    short* hb    = xm1 + (size_t)N * 128;       // N*128 bf16
    short* Bt1   = hb + (size_t)N * 128;        // 384*512
    short* Bt2   = Bt1 + 384 * 512;             // 192*128
    int*   ip    = (int*)(Bt2 + 192 * 128);
    int*   counts = ip;                         // N
    int*   rowptr = ip + N;                     // N+1
    int*   cursor = ip + 2 * N + 1;             // N
    int*   bsums  = ip + 3 * N + 1;             // 256
    int2*  edges  = (int2*)(((size_t)(ip + 3 * N + 1 + 256) + 15) & ~(size_t)15); // E int2

    // fp8 gather buffers alias the dead xb region
    unsigned* xq1 = (unsigned*)xb;              // N*64 dwords (12.8 MB)
    unsigned short* xq2 = (unsigned short*)(xb + (size_t)N * 128);  // N*64 ushorts

    // Layer-2 bf16 aliases (xlh1/xm1 dead after spmm_att1)
    short* xlh2 = xlh1;                         // N*128 bf16 (element-interleaved)
    short* xm2  = xm1;                          // N*64 bf16

    const int NB = (N + 255) / 256;
    const int EB = (E + 255) / 256;
    const int node_blocks = (N + 3) / 4;
    const int MT = (N + 127) / 128;
    const int XCB = (N * F_IN / 8 + 255) / 256;
    const int W1B = (3 * HH * (F_IN / 8) + 255) / 256;
    const int W2B = (3 * CC * (HH / 8) + 255) / 256;
    const int nGemm1 = MT * 3;

    // ---------------- prep (fused) + CSR scan chain ----------------
    prep0<<<NB + W1B + W2B, 256, 0, stream>>>(counts, N, Wl, Wh, Wm, Bt1,
                                              Wl2, Wh2, Wm2, Bt2, NB, W1B);
    hist_xconv<<<EB + XCB, 256, 0, stream>>>(erow, counts, E, x, xb,
                                             N * F_IN / 8, EB);
    block_sums_kernel<<<NB, 256, 0, stream>>>(counts, bsums, N);
    scan_bsums_kernel<<<1, 256, 0, stream>>>(bsums, NB);
    scan_final_kernel<<<NB, 256, 0, stream>>>(counts, bsums, rowptr, cursor, N);

    // ---------------- Layer 1 (gemm fused with edge scatter) ----------------
    gemm_scatter<F_IN, HH><<<nGemm1 + EB, 256, 0, stream>>>(
        xb, Bt1, xlh1, xm1, N, nGemm1, erow, ecol, eval, cursor, edges, E);
    pack8_1<<<(N * 64 + 255) / 256, 256, 0, stream>>>((const unsigned*)xlh1, xq1, N * 64);
    spmm_att1<<<node_blocks, 256, 0, stream>>>(rowptr, edges,
                                               xq1, xlh1, xm1, al, ah, am, av, hb, N);

    // ---------------- Layer 2 ----------------
    gemm_mfma<HH, CC><<<MT * 3, 256, 0, stream>>>(hb, Bt2, xlh2, xm2, N);
    pack8_2<<<(N * 32 + 255) / 256, 256, 0, stream>>>((const unsigned*)xlh2,
                                                      (unsigned*)xq2, N * 32);
    spmm_att2<<<node_blocks, 256, 0, stream>>>(rowptr, edges,
                                               xq2, xlh2, xm2, al2, ah2, am2, av2, out, N);
}

// Round 14
// 224.873 us; speedup vs baseline: 1.6899x; 1.0796x over previous
//
#include <hip/hip_runtime.h>
#include <hip/hip_bf16.h>

// Problem constants (reference file)
#define NN 50000
#define F_IN 512
#define HH 128
#define CC 64

typedef __attribute__((ext_vector_type(8))) short short8v;   // 8 bf16 (4 VGPRs)
typedef __attribute__((ext_vector_type(4))) float f32x4;     // MFMA accumulator
typedef __attribute__((ext_vector_type(2))) float f32x2;

__device__ __forceinline__ short f2b(float f) {
    unsigned u = __builtin_bit_cast(unsigned, f);
    unsigned r = (u + 0x7fffu + ((u >> 16) & 1u)) >> 16;     // RNE
    return (short)r;
}
__device__ __forceinline__ float b2f(short s) {
    unsigned u = ((unsigned)(unsigned short)s) << 16;
    return __builtin_bit_cast(float, u);
}
__device__ __forceinline__ float b2f_lo(unsigned p) {
    return __builtin_bit_cast(float, p << 16);
}
__device__ __forceinline__ float b2f_hi(unsigned p) {
    return __builtin_bit_cast(float, p & 0xffff0000u);
}

// fp8 e4m3 (OCP) decode via gfx950 HW converts
__device__ __forceinline__ f32x2 q2_lo(unsigned p) {   // bytes 0,1
    return __builtin_amdgcn_cvt_pk_f32_fp8(p, false);
}
__device__ __forceinline__ f32x2 q2_hi(unsigned p) {   // bytes 2,3
    return __builtin_amdgcn_cvt_pk_f32_fp8(p, true);
}

// Bijective XCD swizzle (m204)
__device__ __forceinline__ int xcd_swz(int bid, int nwg) {
    int q = nwg >> 3, r = nwg & 7;
    int xcd = bid & 7, off = bid >> 3;
    return (xcd < r ? xcd * (q + 1) : r * (q + 1) + (xcd - r) * q) + off;
}

// async global->LDS, 16 B per lane
__device__ __forceinline__ void load_lds16(const short* g, short* l) {
    __builtin_amdgcn_global_load_lds(
        (const __attribute__((address_space(1))) unsigned int*)g,
        (__attribute__((address_space(3))) unsigned int*)l,
        16, 0, 0);
}

// ---------------------------------------------------------------------------
// Weight prep body
// ---------------------------------------------------------------------------
template <int K, int OUTW>
__device__ __forceinline__ void wprep_body(const float* __restrict__ W0,
                                           const float* __restrict__ W1,
                                           const float* __restrict__ W2,
                                           short* __restrict__ Bt, int id) {
    const int nth = 3 * OUTW * (K / 8);
    if (id >= nth) return;
    const int n = id / (K / 8);
    const int kq = id % (K / 8);
    const int sel = n / OUTW;
    const int c = n % OUTW;
    const float* W = sel == 0 ? W0 : (sel == 1 ? W1 : W2);
    short v[8];
#pragma unroll
    for (int j = 0; j < 8; ++j) v[j] = f2b(W[(size_t)(kq * 8 + j) * OUTW + c]);
#pragma unroll
    for (int j = 0; j < 8; ++j) Bt[(size_t)n * K + kq * 8 + j] = v[j];
}

// ---------------------------------------------------------------------------
// prep0: zero_counts + wprep(L1) + wprep(L2) in one launch
// ---------------------------------------------------------------------------
__global__ __launch_bounds__(256) void prep0(int* __restrict__ counts, int n,
                                             const float* __restrict__ Wl,
                                             const float* __restrict__ Wh,
                                             const float* __restrict__ Wm,
                                             short* __restrict__ Bt1,
                                             const float* __restrict__ Wl2,
                                             const float* __restrict__ Wh2,
                                             const float* __restrict__ Wm2,
                                             short* __restrict__ Bt2,
                                             int nZero, int nW1) {
    const int b = blockIdx.x;
    if (b < nZero) {
        int i = b * 256 + threadIdx.x;
        if (i < n) counts[i] = 0;
    } else if (b < nZero + nW1) {
        wprep_body<F_IN, HH>(Wl, Wh, Wm, Bt1, (b - nZero) * 256 + threadIdx.x);
    } else {
        wprep_body<HH, CC>(Wl2, Wh2, Wm2, Bt2, (b - nZero - nW1) * 256 + threadIdx.x);
    }
}

// ---------------------------------------------------------------------------
// hist_xconv: histogram atomics interleaved under BW-bound xconv (Bresenham)
// ---------------------------------------------------------------------------
__global__ __launch_bounds__(256) void hist_xconv(const int* __restrict__ erow,
                                                  int* __restrict__ counts, int E,
                                                  const float* __restrict__ x,
                                                  short* __restrict__ xb, int n8,
                                                  int nHist) {
    const int b = blockIdx.x;
    const int total = gridDim.x;
    const long hb4 = ((long)b * nHist) / total;
    const long ha4 = ((long)(b + 1) * nHist) / total;
    if (ha4 != hb4) {
        int i = (int)hb4 * 256 + threadIdx.x;
        if (i < E) atomicAdd(&counts[erow[i]], 1);
        return;
    }
    int i = (b - (int)hb4) * 256 + threadIdx.x;
    if (i >= n8) return;
    const float4* xp = (const float4*)x;
    const float4 a = xp[2 * i];
    const float4 bb = xp[2 * i + 1];
    short8v o;
    o[0] = f2b(a.x); o[1] = f2b(a.y); o[2] = f2b(a.z); o[3] = f2b(a.w);
    o[4] = f2b(bb.x); o[5] = f2b(bb.y); o[6] = f2b(bb.z); o[7] = f2b(bb.w);
    *reinterpret_cast<short8v*>(&xb[(size_t)i * 8]) = o;
}

// ---------------------------------------------------------------------------
// Fused layer-1 GEMM + edge scatter, roles interleaved via Bresenham on the
// XCD-swizzled id: scatter spreads across dispatch order AND XCDs; gemm tile
// ids stay contiguous within each XCD chunk (A-panel L2 locality kept).
// ---------------------------------------------------------------------------
template <int K, int BNout>
__global__ __launch_bounds__(256) void gemm_scatter(const short* __restrict__ A,
                                                    const short* __restrict__ Bt,
                                                    short* __restrict__ xlh,
                                                    short* __restrict__ xm,
                                                    int M, int nGemm,
                                                    const int* __restrict__ row,
                                                    const int* __restrict__ col,
                                                    const float* __restrict__ val,
                                                    int* __restrict__ cursor,
                                                    int2* __restrict__ edges, int E,
                                                    int nScat) {
    constexpr int BM = 128, BK = 64;
    constexpr int FM = (BNout == 128) ? 4 : 2;
    constexpr int FN = 4;
    constexpr int WM = FM * 16;
    constexpr int NKT = K / BK;
    constexpr int NBL = BNout / 32;

    __shared__ short As[BM * BK];
    __shared__ short Bs[BNout * BK];

    const int total = nGemm + nScat;
    const int swz = xcd_swz(blockIdx.x, total);
    const long ns_b = ((long)swz * nScat) / total;
    const long ns_a = ((long)(swz + 1) * nScat) / total;

    if (ns_a != ns_b) {
        // ---- edge scatter block (index ns_b) ----
        int i = (int)ns_b * 256 + threadIdx.x;
        if (i < E) {
            int r = row[i];
            int p = atomicAdd(&cursor[r], 1);
            int2 rec;
            rec.x = col[i];
            rec.y = __builtin_bit_cast(int, val[i]);
            edges[p] = rec;
        }
        return;
    }

    const int tid = threadIdx.x;
    const int lane = tid & 63;
    const int wid = tid >> 6;
    const int wg = swz - (int)ns_b;             // gemm tile id, chunk-contiguous
    const int bm = wg / 3;
    const int bn = wg % 3;
    const int m0 = bm * BM;
    const int n0 = bn * BNout;
    const int wm = (BNout == 128) ? (wid >> 1) : wid;
    const int wn = (BNout == 128) ? (wid & 1) : 0;

    const int r8 = lane >> 3;
    const int sl = (lane & 7) ^ r8;

    f32x4 acc[FM][FN];
#pragma unroll
    for (int i = 0; i < FM; ++i)
#pragma unroll
        for (int j = 0; j < FN; ++j) acc[i][j] = (f32x4){0.f, 0.f, 0.f, 0.f};

    for (int kt = 0; kt < NKT; ++kt) {
        const int k0 = kt * BK;
        __syncthreads();
#pragma unroll
        for (int i = 0; i < 4; ++i) {
            int r = (wid * 4 + i) * 8 + r8;
            int gr = m0 + r; if (gr >= M) gr = M - 1;
            load_lds16(&A[(size_t)gr * K + k0 + sl * 8], &As[(wid * 4 + i) * 512]);
        }
#pragma unroll
        for (int i = 0; i < NBL; ++i) {
            int r = (wid * NBL + i) * 8 + r8;
            load_lds16(&Bt[(size_t)(n0 + r) * K + k0 + sl * 8],
                       &Bs[(wid * NBL + i) * 512]);
        }
        __syncthreads();

        const int mrow = lane & 15;
        const int kg = lane >> 4;
#pragma unroll
        for (int kk = 0; kk < 2; ++kk) {
            short8v af[FM], bf[FN];
#pragma unroll
            for (int f = 0; f < FM; ++f) {
                int m = wm * WM + f * 16 + mrow;
                int s = kk * 4 + kg;
                af[f] = *reinterpret_cast<const short8v*>(
                    &As[m * 64 + ((s ^ (m & 7)) << 3)]);
            }
#pragma unroll
            for (int f = 0; f < FN; ++f) {
                int nr = wn * 64 + f * 16 + mrow;
                int s = kk * 4 + kg;
                bf[f] = *reinterpret_cast<const short8v*>(
                    &Bs[nr * 64 + ((s ^ (nr & 7)) << 3)]);
            }
#pragma unroll
            for (int i = 0; i < FM; ++i)
#pragma unroll
                for (int j = 0; j < FN; ++j)
                    acc[i][j] = __builtin_amdgcn_mfma_f32_16x16x32_bf16(
                        af[i], bf[j], acc[i][j], 0, 0, 0);
        }
    }

#pragma unroll
    for (int i = 0; i < FM; ++i)
#pragma unroll
        for (int j = 0; j < FN; ++j) {
            int cc = wn * 64 + j * 16 + (lane & 15);
#pragma unroll
            for (int e = 0; e < 4; ++e) {
                int rrow = m0 + wm * WM + i * 16 + (lane >> 4) * 4 + e;
                if (rrow >= M) continue;
                short v = f2b(acc[i][j][e]);
                if (bn == 2) {
                    xm[(size_t)rrow * BNout + cc] = v;
                } else if (BNout == 128) {
                    xlh[(size_t)rrow * 256 + (cc >> 1) * 4 + bn * 2 + (cc & 1)] = v;
                } else {
                    xlh[(size_t)rrow * 128 + cc * 2 + bn] = v;
                }
            }
        }
}

// ---------------------------------------------------------------------------
// Standalone layer-2 GEMM
// ---------------------------------------------------------------------------
template <int K, int BNout>
__global__ __launch_bounds__(256) void gemm_mfma(const short* __restrict__ A,
                                                 const short* __restrict__ Bt,
                                                 short* __restrict__ xlh,
                                                 short* __restrict__ xm,
                                                 int M) {
    constexpr int BM = 128, BK = 64;
    constexpr int FM = (BNout == 128) ? 4 : 2;
    constexpr int FN = 4;
    constexpr int WM = FM * 16;
    constexpr int NKT = K / BK;
    constexpr int NBL = BNout / 32;

    __shared__ short As[BM * BK];
    __shared__ short Bs[BNout * BK];

    const int tid = threadIdx.x;
    const int lane = tid & 63;
    const int wid = tid >> 6;
    const int wg = xcd_swz(blockIdx.x, gridDim.x);
    const int bm = wg / 3;
    const int bn = wg % 3;
    const int m0 = bm * BM;
    const int n0 = bn * BNout;
    const int wm = (BNout == 128) ? (wid >> 1) : wid;
    const int wn = (BNout == 128) ? (wid & 1) : 0;

    const int r8 = lane >> 3;
    const int sl = (lane & 7) ^ r8;

    f32x4 acc[FM][FN];
#pragma unroll
    for (int i = 0; i < FM; ++i)
#pragma unroll
        for (int j = 0; j < FN; ++j) acc[i][j] = (f32x4){0.f, 0.f, 0.f, 0.f};

    for (int kt = 0; kt < NKT; ++kt) {
        const int k0 = kt * BK;
        __syncthreads();
#pragma unroll
        for (int i = 0; i < 4; ++i) {
            int r = (wid * 4 + i) * 8 + r8;
            int gr = m0 + r; if (gr >= M) gr = M - 1;
            load_lds16(&A[(size_t)gr * K + k0 + sl * 8], &As[(wid * 4 + i) * 512]);
        }
#pragma unroll
        for (int i = 0; i < NBL; ++i) {
            int r = (wid * NBL + i) * 8 + r8;
            load_lds16(&Bt[(size_t)(n0 + r) * K + k0 + sl * 8],
                       &Bs[(wid * NBL + i) * 512]);
        }
        __syncthreads();

        const int mrow = lane & 15;
        const int kg = lane >> 4;
#pragma unroll
        for (int kk = 0; kk < 2; ++kk) {
            short8v af[FM], bf[FN];
#pragma unroll
            for (int f = 0; f < FM; ++f) {
                int m = wm * WM + f * 16 + mrow;
                int s = kk * 4 + kg;
                af[f] = *reinterpret_cast<const short8v*>(
                    &As[m * 64 + ((s ^ (m & 7)) << 3)]);
            }
#pragma unroll
            for (int f = 0; f < FN; ++f) {
                int nr = wn * 64 + f * 16 + mrow;
                int s = kk * 4 + kg;
                bf[f] = *reinterpret_cast<const short8v*>(
                    &Bs[nr * 64 + ((s ^ (nr & 7)) << 3)]);
            }
#pragma unroll
            for (int i = 0; i < FM; ++i)
#pragma unroll
                for (int j = 0; j < FN; ++j)
                    acc[i][j] = __builtin_amdgcn_mfma_f32_16x16x32_bf16(
                        af[i], bf[j], acc[i][j], 0, 0, 0);
        }
    }

#pragma unroll
    for (int i = 0; i < FM; ++i)
#pragma unroll
        for (int j = 0; j < FN; ++j) {
            int cc = wn * 64 + j * 16 + (lane & 15);
#pragma unroll
            for (int e = 0; e < 4; ++e) {
                int row = m0 + wm * WM + i * 16 + (lane >> 4) * 4 + e;
                if (row >= M) continue;
                short v = f2b(acc[i][j][e]);
                if (bn == 2) {
                    xm[(size_t)row * BNout + cc] = v;
                } else if (BNout == 128) {
                    xlh[(size_t)row * 256 + (cc >> 1) * 4 + bn * 2 + (cc & 1)] = v;
                } else {
                    xlh[(size_t)row * 128 + cc * 2 + bn] = v;
                }
            }
        }
}

// ---------------------------------------------------------------------------
// fp8 pack kernels (bf16 gather buffers -> fp8 gather buffers)
// ---------------------------------------------------------------------------
__global__ __launch_bounds__(256) void pack8_1(const unsigned* __restrict__ xlh,
                                               unsigned* __restrict__ xq, int n) {
    int i = blockIdx.x * 256 + threadIdx.x;   // over N*64 pairs
    if (i >= n) return;
    const uint2 v = ((const uint2*)xlh)[i];
    unsigned r = __builtin_amdgcn_cvt_pk_fp8_f32(b2f_lo(v.x), b2f_hi(v.x), 0, false);
    r = __builtin_amdgcn_cvt_pk_fp8_f32(b2f_lo(v.y), b2f_hi(v.y), r, true);
    xq[i] = r;
}

__global__ __launch_bounds__(256) void pack8_2(const unsigned* __restrict__ xlh,
                                               unsigned* __restrict__ xq, int n2) {
    int i = blockIdx.x * 256 + threadIdx.x;   // over N*32 dword-pairs
    if (i >= n2) return;
    const uint2 v = ((const uint2*)xlh)[i];
    unsigned lo = __builtin_amdgcn_cvt_pk_fp8_f32(b2f_lo(v.x), b2f_hi(v.x), 0, false);
    unsigned hi = __builtin_amdgcn_cvt_pk_fp8_f32(b2f_lo(v.y), b2f_hi(v.y), 0, false);
    xq[i] = (lo & 0xffffu) | (hi << 16);
}

// ---------------------------------------------------------------------------
// CSR scan chain
// ---------------------------------------------------------------------------
__global__ __launch_bounds__(256) void block_sums_kernel(const int* __restrict__ counts,
                                                         int* __restrict__ bsums, int n) {
    __shared__ int s[256];
    int tid = threadIdx.x;
    int i = blockIdx.x * 256 + tid;
    s[tid] = (i < n) ? counts[i] : 0;
    __syncthreads();
#pragma unroll
    for (int off = 128; off > 0; off >>= 1) {
        if (tid < off) s[tid] += s[tid + off];
        __syncthreads();
    }
    if (tid == 0) bsums[blockIdx.x] = s[0];
}

__global__ __launch_bounds__(256) void scan_bsums_kernel(int* __restrict__ bsums, int nb) {
    __shared__ int s[256];
    int t = threadIdx.x;
    int v = (t < nb) ? bsums[t] : 0;
    s[t] = v;
    __syncthreads();
#pragma unroll
    for (int off = 1; off < 256; off <<= 1) {
        int u = (t >= off) ? s[t - off] : 0;
        __syncthreads();
        s[t] += u;
        __syncthreads();
    }
    if (t < nb) bsums[t] = s[t] - v;      // exclusive
}

__global__ __launch_bounds__(256) void scan_final_kernel(const int* __restrict__ counts,
                                                         const int* __restrict__ bsums,
                                                         int* __restrict__ rowptr,
                                                         int* __restrict__ cursor, int n) {
    __shared__ int s[256];
    int tid = threadIdx.x;
    int i = blockIdx.x * 256 + tid;
    int v = (i < n) ? counts[i] : 0;
    s[tid] = v;
    __syncthreads();
#pragma unroll
    for (int off = 1; off < 256; off <<= 1) {
        int t = (tid >= off) ? s[tid - off] : 0;
        __syncthreads();
        s[tid] += t;
        __syncthreads();
    }
    int excl = s[tid] - v + bsums[blockIdx.x];
    if (i < n) {
        rowptr[i] = excl;
        cursor[i] = excl;
        if (i == n - 1) rowptr[n] = excl + v;
    }
}

// ---------------------------------------------------------------------------
__device__ __forceinline__ float wave_sum(float v) {
#pragma unroll
    for (int off = 32; off > 0; off >>= 1) v += __shfl_xor(v, off, 64);
    return v;
}
__device__ __forceinline__ float wave_max(float v) {
#pragma unroll
    for (int off = 32; off > 0; off >>= 1) v = fmaxf(v, __shfl_xor(v, off, 64));
    return v;
}

// ---------------------------------------------------------------------------
// Layer-1 fused: dual CSR spmm (fp8 gathers) + attention + combine -> h bf16.
// ---------------------------------------------------------------------------
__global__ __launch_bounds__(256) void spmm_att1(const int* __restrict__ rowptr,
                                                 const int2* __restrict__ edges,
                                                 const unsigned* __restrict__ xq,
                                                 const short* __restrict__ xlh,
                                                 const short* __restrict__ xm,
                                                 const float* __restrict__ a_low,
                                                 const float* __restrict__ a_high,
                                                 const float* __restrict__ a_mlp,
                                                 const float* __restrict__ av,
                                                 short* __restrict__ hb,
                                                 int n) {
    const int node = blockIdx.x * 4 + (threadIdx.x >> 6);
    const int lane = threadIdx.x & 63;
    if (node >= n) return;
    const uint2* XLH = (const uint2*)xlh;        // [node][64] {xl-pair, xh-pair}
    const unsigned* XM = (const unsigned*)xm;

    const int s = __builtin_amdgcn_readfirstlane(rowptr[node]);
    const int e = __builtin_amdgcn_readfirstlane(rowptr[node + 1]);

    float l0 = 0.f, l1 = 0.f, h0 = 0.f, h1 = 0.f;
    for (int j = s; j < e; j += 8) {
        int   cq[8];
        float vq[8];
#pragma unroll
        for (int q = 0; q < 8; ++q) {
            const int jj = min(j + q, e - 1);
            const int2 rec = edges[jj];
            cq[q] = __builtin_amdgcn_readfirstlane(rec.x);
            int vb = __builtin_amdgcn_readfirstlane(rec.y);
            float t = __builtin_bit_cast(float, vb);
            vq[q] = (j + q < e) ? t : 0.f;
        }
        unsigned p[8];
#pragma unroll
        for (int q = 0; q < 8; ++q)
            p[q] = xq[(size_t)cq[q] * 64 + lane];
#pragma unroll
        for (int q = 0; q < 8; ++q) {
            const f32x2 lo = q2_lo(p[q]);
            const f32x2 hi = q2_hi(p[q]);
            l0 += vq[q] * lo.x; l1 += vq[q] * lo.y;
            h0 += vq[q] * hi.x; h1 += vq[q] * hi.y;
        }
    }

    const uint2 self = XLH[(size_t)node * 64 + lane];
    const unsigned xmn = XM[(size_t)node * 64 + lane];
    float ol0 = fmaxf(l0, 0.f);
    float ol1 = fmaxf(l1, 0.f);
    float oh0 = fmaxf(b2f_lo(self.y) - h0, 0.f);
    float oh1 = fmaxf(b2f_hi(self.y) - h1, 0.f);
    float om0 = fmaxf(b2f_lo(xmn), 0.f);
    float om1 = fmaxf(b2f_hi(xmn), 0.f);

    const float2 aL = ((const float2*)a_low)[lane];
    const float2 aH = ((const float2*)a_high)[lane];
    const float2 aM = ((const float2*)a_mlp)[lane];
    float dl = wave_sum(ol0 * aL.x + ol1 * aL.y);
    float dh = wave_sum(oh0 * aH.x + oh1 * aH.y);
    float dm = wave_sum(om0 * aM.x + om1 * aM.y);

    const float g0 = 1.f / (1.f + expf(-dl));
    const float g1 = 1.f / (1.f + expf(-dh));
    const float g2 = 1.f / (1.f + expf(-dm));
    float s0 = (g0 * av[0] + g1 * av[3] + g2 * av[6]) * (1.f / 3.f);
    float s1 = (g0 * av[1] + g1 * av[4] + g2 * av[7]) * (1.f / 3.f);
    float s2 = (g0 * av[2] + g1 * av[5] + g2 * av[8]) * (1.f / 3.f);
    float mx = fmaxf(s0, fmaxf(s1, s2));
    float e0 = expf(s0 - mx), e1 = expf(s1 - mx), e2 = expf(s2 - mx);
    float inv = 1.f / (e0 + e1 + e2);
    float at0 = e0 * inv, at1 = e1 * inv, at2 = e2 * inv;

    float ho0 = 3.f * (at0 * ol0 + at1 * oh0 + at2 * om0);
    float ho1 = 3.f * (at0 * ol1 + at1 * oh1 + at2 * om1);
    unsigned pk = (unsigned)(unsigned short)f2b(ho0) |
                  ((unsigned)(unsigned short)f2b(ho1) << 16);
    ((unsigned*)hb)[(size_t)node * 64 + lane] = pk;
}

// ---------------------------------------------------------------------------
// Layer-2 fused: dual CSR spmm (fp8 ushort gathers) + attention + combine +
// log_softmax -> out.
// ---------------------------------------------------------------------------
__global__ __launch_bounds__(256) void spmm_att2(const int* __restrict__ rowptr,
                                                 const int2* __restrict__ edges,
                                                 const unsigned short* __restrict__ xq,
                                                 const short* __restrict__ xlh,
                                                 const short* __restrict__ xm,
                                                 const float* __restrict__ a_low,
                                                 const float* __restrict__ a_high,
                                                 const float* __restrict__ a_mlp,
                                                 const float* __restrict__ av,
                                                 float* __restrict__ out,
                                                 int n) {
    const int node = blockIdx.x * 4 + (threadIdx.x >> 6);
    const int lane = threadIdx.x & 63;
    if (node >= n) return;
    const unsigned* XLH = (const unsigned*)xlh;  // [node][64] {xl|xh} bf16

    const int s = __builtin_amdgcn_readfirstlane(rowptr[node]);
    const int e = __builtin_amdgcn_readfirstlane(rowptr[node + 1]);

    float accl = 0.f, acch = 0.f;
    for (int j = s; j < e; j += 8) {
        int   cq[8];
        float vq[8];
#pragma unroll
        for (int q = 0; q < 8; ++q) {
            const int jj = min(j + q, e - 1);
            const int2 rec = edges[jj];
            cq[q] = __builtin_amdgcn_readfirstlane(rec.x);
            int vb = __builtin_amdgcn_readfirstlane(rec.y);
            float t = __builtin_bit_cast(float, vb);
            vq[q] = (j + q < e) ? t : 0.f;
        }
        unsigned short p[8];
#pragma unroll
        for (int q = 0; q < 8; ++q)
            p[q] = xq[(size_t)cq[q] * 64 + lane];
#pragma unroll
        for (int q = 0; q < 8; ++q) {
            const f32x2 d = q2_lo((unsigned)p[q]);
            accl += vq[q] * d.x;
            acch += vq[q] * d.y;
        }
    }

    const unsigned self = XLH[(size_t)node * 64 + lane];
    float ol = fmaxf(accl, 0.f);
    float oh = fmaxf(b2f_hi(self) - acch, 0.f);
    float om = fmaxf(b2f(xm[(size_t)node * 64 + lane]), 0.f);

    float dl = wave_sum(ol * a_low[lane]);
    float dh = wave_sum(oh * a_high[lane]);
    float dm = wave_sum(om * a_mlp[lane]);

    const float g0 = 1.f / (1.f + expf(-dl));
    const float g1 = 1.f / (1.f + expf(-dh));
    const float g2 = 1.f / (1.f + expf(-dm));
    float s0 = (g0 * av[0] + g1 * av[3] + g2 * av[6]) * (1.f / 3.f);
    float s1 = (g0 * av[1] + g1 * av[4] + g2 * av[7]) * (1.f / 3.f);
    float s2 = (g0 * av[2] + g1 * av[5] + g2 * av[8]) * (1.f / 3.f);
    float mx3 = fmaxf(s0, fmaxf(s1, s2));
    float e0 = expf(s0 - mx3), e1 = expf(s1 - mx3), e2 = expf(s2 - mx3);
    float inv = 1.f / (e0 + e1 + e2);
    float at0 = e0 * inv, at1 = e1 * inv, at2 = e2 * inv;

    float o = 3.f * (at0 * ol + at1 * oh + at2 * om);

    float m = wave_max(o);
    float ex = expf(o - m);
    float su = wave_sum(ex);
    out[(size_t)node * 64 + lane] = o - m - logf(su);
}

// ---------------------------------------------------------------------------
extern "C" void kernel_launch(void* const* d_in, const int* in_sizes, int n_in,
                              void* d_out, int out_size, void* d_ws, size_t ws_size,
                              hipStream_t stream) {
    const float* x    = (const float*)d_in[0];
    const int*   erow = (const int*)d_in[1];
    const int*   ecol = (const int*)d_in[2];
    const float* eval = (const float*)d_in[3];
    const float* Wl   = (const float*)d_in[4];
    const float* Wh   = (const float*)d_in[5];
    const float* Wm   = (const float*)d_in[6];
    const float* al   = (const float*)d_in[7];
    const float* ah   = (const float*)d_in[8];
    const float* am   = (const float*)d_in[9];
    const float* av   = (const float*)d_in[10];
    const float* Wl2  = (const float*)d_in[11];
    const float* Wh2  = (const float*)d_in[12];
    const float* Wm2  = (const float*)d_in[13];
    const float* al2  = (const float*)d_in[14];
    const float* ah2  = (const float*)d_in[15];
    const float* am2  = (const float*)d_in[16];
    const float* av2  = (const float*)d_in[17];
    float* out = (float*)d_out;

    const int E = in_sizes[1];
    const int N = NN;

    short* ws    = (short*)d_ws;
    short* xb    = ws;                          // N*512 bf16 (converted x)
    short* xlh1  = xb + (size_t)N * 512;        // N*256 bf16 (pair-interleaved)
    short* xm1   = xlh1 + (size_t)N * 256;      // N*128 bf16
    short* hb    = xm1 + (size_t)N * 128;       // N*128 bf16
    short* Bt1   = hb + (size_t)N * 128;        // 384*512
    short* Bt2   = Bt1 + 384 * 512;             // 192*128
    int*   ip    = (int*)(Bt2 + 192 * 128);
    int*   counts = ip;                         // N
    int*   rowptr = ip + N;                     // N+1
    int*   cursor = ip + 2 * N + 1;             // N
    int*   bsums  = ip + 3 * N + 1;             // 256
    int2*  edges  = (int2*)(((size_t)(ip + 3 * N + 1 + 256) + 15) & ~(size_t)15); // E int2

    // fp8 gather buffers alias the dead xb region
    unsigned* xq1 = (unsigned*)xb;              // N*64 dwords (12.8 MB)
    unsigned short* xq2 = (unsigned short*)(xb + (size_t)N * 128);  // N*64 ushorts

    // Layer-2 bf16 aliases (xlh1/xm1 dead after spmm_att1)
    short* xlh2 = xlh1;                         // N*128 bf16 (element-interleaved)
    short* xm2  = xm1;                          // N*64 bf16

    const int NB = (N + 255) / 256;
    const int EB = (E + 255) / 256;
    const int node_blocks = (N + 3) / 4;
    const int MT = (N + 127) / 128;
    const int XCB = (N * F_IN / 8 + 255) / 256;
    const int W1B = (3 * HH * (F_IN / 8) + 255) / 256;
    const int W2B = (3 * CC * (HH / 8) + 255) / 256;
    const int nGemm1 = MT * 3;

    // ---------------- prep (fused) + CSR scan chain ----------------
    prep0<<<NB + W1B + W2B, 256, 0, stream>>>(counts, N, Wl, Wh, Wm, Bt1,
                                              Wl2, Wh2, Wm2, Bt2, NB, W1B);
    hist_xconv<<<EB + XCB, 256, 0, stream>>>(erow, counts, E, x, xb,
                                             N * F_IN / 8, EB);
    block_sums_kernel<<<NB, 256, 0, stream>>>(counts, bsums, N);
    scan_bsums_kernel<<<1, 256, 0, stream>>>(bsums, NB);
    scan_final_kernel<<<NB, 256, 0, stream>>>(counts, bsums, rowptr, cursor, N);

    // ---------------- Layer 1 (gemm interleaved with edge scatter) ----------
    gemm_scatter<F_IN, HH><<<nGemm1 + EB, 256, 0, stream>>>(
        xb, Bt1, xlh1, xm1, N, nGemm1, erow, ecol, eval, cursor, edges, E, EB);
    pack8_1<<<(N * 64 + 255) / 256, 256, 0, stream>>>((const unsigned*)xlh1, xq1, N * 64);
    spmm_att1<<<node_blocks, 256, 0, stream>>>(rowptr, edges,
                                               xq1, xlh1, xm1, al, ah, am, av, hb, N);

    // ---------------- Layer 2 ----------------
    gemm_mfma<HH, CC><<<MT * 3, 256, 0, stream>>>(hb, Bt2, xlh2, xm2, N);
    pack8_2<<<(N * 32 + 255) / 256, 256, 0, stream>>>((const unsigned*)xlh2,
                                                      (unsigned*)xq2, N * 32);
    spmm_att2<<<node_blocks, 256, 0, stream>>>(rowptr, edges,
                                               xq2, xlh2, xm2, al2, ah2, am2, av2, out, N);
}

// Round 15
// 206.081 us; speedup vs baseline: 1.8440x; 1.0912x over previous
//
#include <hip/hip_runtime.h>
#include <hip/hip_bf16.h>

// Problem constants (reference file)
#define NN 50000
#define F_IN 512
#define HH 128
#define CC 64

typedef __attribute__((ext_vector_type(8))) short short8v;   // 8 bf16 (4 VGPRs)
typedef __attribute__((ext_vector_type(4))) float f32x4;     // MFMA accumulator
typedef __attribute__((ext_vector_type(2))) float f32x2;

__device__ __forceinline__ short f2b(float f) {
    unsigned u = __builtin_bit_cast(unsigned, f);
    unsigned r = (u + 0x7fffu + ((u >> 16) & 1u)) >> 16;     // RNE
    return (short)r;
}
__device__ __forceinline__ float b2f(short s) {
    unsigned u = ((unsigned)(unsigned short)s) << 16;
    return __builtin_bit_cast(float, u);
}
__device__ __forceinline__ float b2f_lo(unsigned p) {
    return __builtin_bit_cast(float, p << 16);
}
__device__ __forceinline__ float b2f_hi(unsigned p) {
    return __builtin_bit_cast(float, p & 0xffff0000u);
}

// fp8 e4m3 (OCP) decode via gfx950 HW converts
__device__ __forceinline__ f32x2 q2_lo(unsigned p) {   // bytes 0,1
    return __builtin_amdgcn_cvt_pk_f32_fp8(p, false);
}
__device__ __forceinline__ f32x2 q2_hi(unsigned p) {   // bytes 2,3
    return __builtin_amdgcn_cvt_pk_f32_fp8(p, true);
}

// Bijective XCD swizzle (m204)
__device__ __forceinline__ int xcd_swz(int bid, int nwg) {
    int q = nwg >> 3, r = nwg & 7;
    int xcd = bid & 7, off = bid >> 3;
    return (xcd < r ? xcd * (q + 1) : r * (q + 1) + (xcd - r) * q) + off;
}

// async global->LDS, 16 B per lane
__device__ __forceinline__ void load_lds16(const short* g, short* l) {
    __builtin_amdgcn_global_load_lds(
        (const __attribute__((address_space(1))) unsigned int*)g,
        (__attribute__((address_space(3))) unsigned int*)l,
        16, 0, 0);
}

// ---------------------------------------------------------------------------
// Weight prep body
// ---------------------------------------------------------------------------
template <int K, int OUTW>
__device__ __forceinline__ void wprep_body(const float* __restrict__ W0,
                                           const float* __restrict__ W1,
                                           const float* __restrict__ W2,
                                           short* __restrict__ Bt, int id) {
    const int nth = 3 * OUTW * (K / 8);
    if (id >= nth) return;
    const int n = id / (K / 8);
    const int kq = id % (K / 8);
    const int sel = n / OUTW;
    const int c = n % OUTW;
    const float* W = sel == 0 ? W0 : (sel == 1 ? W1 : W2);
    short v[8];
#pragma unroll
    for (int j = 0; j < 8; ++j) v[j] = f2b(W[(size_t)(kq * 8 + j) * OUTW + c]);
#pragma unroll
    for (int j = 0; j < 8; ++j) Bt[(size_t)n * K + kq * 8 + j] = v[j];
}

// ---------------------------------------------------------------------------
// prep0: zero_counts + wprep(L1) + wprep(L2) in one launch
// ---------------------------------------------------------------------------
__global__ __launch_bounds__(256) void prep0(int* __restrict__ counts, int n,
                                             const float* __restrict__ Wl,
                                             const float* __restrict__ Wh,
                                             const float* __restrict__ Wm,
                                             short* __restrict__ Bt1,
                                             const float* __restrict__ Wl2,
                                             const float* __restrict__ Wh2,
                                             const float* __restrict__ Wm2,
                                             short* __restrict__ Bt2,
                                             int nZero, int nW1) {
    const int b = blockIdx.x;
    if (b < nZero) {
        int i = b * 256 + threadIdx.x;
        if (i < n) counts[i] = 0;
    } else if (b < nZero + nW1) {
        wprep_body<F_IN, HH>(Wl, Wh, Wm, Bt1, (b - nZero) * 256 + threadIdx.x);
    } else {
        wprep_body<HH, CC>(Wl2, Wh2, Wm2, Bt2, (b - nZero - nW1) * 256 + threadIdx.x);
    }
}

// ---------------------------------------------------------------------------
// hist_xconv: histogram atomics interleaved under BW-bound xconv (Bresenham)
// ---------------------------------------------------------------------------
__global__ __launch_bounds__(256) void hist_xconv(const int* __restrict__ erow,
                                                  int* __restrict__ counts, int E,
                                                  const float* __restrict__ x,
                                                  short* __restrict__ xb, int n8,
                                                  int nHist) {
    const int b = blockIdx.x;
    const int total = gridDim.x;
    const long hb4 = ((long)b * nHist) / total;
    const long ha4 = ((long)(b + 1) * nHist) / total;
    if (ha4 != hb4) {
        int i = (int)hb4 * 256 + threadIdx.x;
        if (i < E) atomicAdd(&counts[erow[i]], 1);
        return;
    }
    int i = (b - (int)hb4) * 256 + threadIdx.x;
    if (i >= n8) return;
    const float4* xp = (const float4*)x;
    const float4 a = xp[2 * i];
    const float4 bb = xp[2 * i + 1];
    short8v o;
    o[0] = f2b(a.x); o[1] = f2b(a.y); o[2] = f2b(a.z); o[3] = f2b(a.w);
    o[4] = f2b(bb.x); o[5] = f2b(bb.y); o[6] = f2b(bb.z); o[7] = f2b(bb.w);
    *reinterpret_cast<short8v*>(&xb[(size_t)i * 8]) = o;
}

// ---------------------------------------------------------------------------
// GEMM body: MFMA + global_load_lds + XOR slot swizzle + LDS-staged coalesced
// epilogue into per-bn output plane (xl / xh / xm, each row-major [M][BNout]).
// ---------------------------------------------------------------------------
template <int K, int BNout>
__device__ __forceinline__ void gemm_body(const short* __restrict__ A,
                                          const short* __restrict__ Bt,
                                          short* __restrict__ xl,
                                          short* __restrict__ xh,
                                          short* __restrict__ xm,
                                          int M, int wg, short* smem) {
    constexpr int BM = 128, BK = 64;
    constexpr int FM = (BNout == 128) ? 4 : 2;
    constexpr int FN = 4;
    constexpr int WM = FM * 16;
    constexpr int NKT = K / BK;
    constexpr int NBL = BNout / 32;

    short* As = smem;                    // BM*BK
    short* Bs = smem + BM * BK;          // BNout*BK

    const int tid = threadIdx.x;
    const int lane = tid & 63;
    const int wid = tid >> 6;
    const int bm = wg / 3;
    const int bn = wg % 3;
    const int m0 = bm * BM;
    const int n0 = bn * BNout;
    const int wm = (BNout == 128) ? (wid >> 1) : wid;
    const int wn = (BNout == 128) ? (wid & 1) : 0;

    const int r8 = lane >> 3;
    const int sl = (lane & 7) ^ r8;

    f32x4 acc[FM][FN];
#pragma unroll
    for (int i = 0; i < FM; ++i)
#pragma unroll
        for (int j = 0; j < FN; ++j) acc[i][j] = (f32x4){0.f, 0.f, 0.f, 0.f};

    for (int kt = 0; kt < NKT; ++kt) {
        const int k0 = kt * BK;
        __syncthreads();
#pragma unroll
        for (int i = 0; i < 4; ++i) {
            int r = (wid * 4 + i) * 8 + r8;
            int gr = m0 + r; if (gr >= M) gr = M - 1;
            load_lds16(&A[(size_t)gr * K + k0 + sl * 8], &As[(wid * 4 + i) * 512]);
        }
#pragma unroll
        for (int i = 0; i < NBL; ++i) {
            int r = (wid * NBL + i) * 8 + r8;
            load_lds16(&Bt[(size_t)(n0 + r) * K + k0 + sl * 8],
                       &Bs[(wid * NBL + i) * 512]);
        }
        __syncthreads();

        const int mrow = lane & 15;
        const int kg = lane >> 4;
#pragma unroll
        for (int kk = 0; kk < 2; ++kk) {
            short8v af[FM], bf[FN];
#pragma unroll
            for (int f = 0; f < FM; ++f) {
                int m = wm * WM + f * 16 + mrow;
                int s = kk * 4 + kg;
                af[f] = *reinterpret_cast<const short8v*>(
                    &As[m * 64 + ((s ^ (m & 7)) << 3)]);
            }
#pragma unroll
            for (int f = 0; f < FN; ++f) {
                int nr = wn * 64 + f * 16 + mrow;
                int s = kk * 4 + kg;
                bf[f] = *reinterpret_cast<const short8v*>(
                    &Bs[nr * 64 + ((s ^ (nr & 7)) << 3)]);
            }
#pragma unroll
            for (int i = 0; i < FM; ++i)
#pragma unroll
                for (int j = 0; j < FN; ++j)
                    acc[i][j] = __builtin_amdgcn_mfma_f32_16x16x32_bf16(
                        af[i], bf[j], acc[i][j], 0, 0, 0);
        }
    }

    // ---- LDS-staged coalesced epilogue ----
    __syncthreads();                     // done reading As/Bs
#pragma unroll
    for (int i = 0; i < FM; ++i)
#pragma unroll
        for (int j = 0; j < FN; ++j) {
            int cc = wn * 64 + j * 16 + (lane & 15);
#pragma unroll
            for (int e = 0; e < 4; ++e) {
                int r = wm * WM + i * 16 + (lane >> 4) * 4 + e;
                smem[r * BNout + cc] = f2b(acc[i][j][e]);
            }
        }
    __syncthreads();

    short* plane = (bn == 0) ? xl : ((bn == 1) ? xh : xm);
    constexpr int CH = BM * BNout / 8;   // int4 chunks in the tile
#pragma unroll
    for (int p = 0; p < CH / 256; ++p) {
        int idx = p * 256 + tid;
        int r = idx / (BNout / 8);
        int c8 = idx % (BNout / 8);
        int grow = m0 + r;
        if (grow < M)
            *reinterpret_cast<int4*>(&plane[(size_t)grow * BNout + c8 * 8]) =
                *reinterpret_cast<const int4*>(&smem[r * BNout + c8 * 8]);
    }
}

// ---------------------------------------------------------------------------
// Fused layer-1 GEMM + edge scatter (Bresenham-interleaved roles)
// ---------------------------------------------------------------------------
template <int K, int BNout>
__global__ __launch_bounds__(256) void gemm_scatter(const short* __restrict__ A,
                                                    const short* __restrict__ Bt,
                                                    short* __restrict__ xl,
                                                    short* __restrict__ xh,
                                                    short* __restrict__ xm,
                                                    int M, int nGemm,
                                                    const int* __restrict__ row,
                                                    const int* __restrict__ col,
                                                    const float* __restrict__ val,
                                                    int* __restrict__ cursor,
                                                    int2* __restrict__ edges, int E,
                                                    int nScat) {
    __shared__ short smem[128 * 64 + BNout * 64];

    const int total = nGemm + nScat;
    const int swz = xcd_swz(blockIdx.x, total);
    const long ns_b = ((long)swz * nScat) / total;
    const long ns_a = ((long)(swz + 1) * nScat) / total;

    if (ns_a != ns_b) {
        int i = (int)ns_b * 256 + threadIdx.x;
        if (i < E) {
            int r = row[i];
            int p = atomicAdd(&cursor[r], 1);
            int2 rec;
            rec.x = col[i];
            rec.y = __builtin_bit_cast(int, val[i]);
            edges[p] = rec;
        }
        return;
    }
    gemm_body<K, BNout>(A, Bt, xl, xh, xm, M, swz - (int)ns_b, smem);
}

// ---------------------------------------------------------------------------
// Standalone layer-2 GEMM
// ---------------------------------------------------------------------------
template <int K, int BNout>
__global__ __launch_bounds__(256) void gemm_mfma(const short* __restrict__ A,
                                                 const short* __restrict__ Bt,
                                                 short* __restrict__ xl,
                                                 short* __restrict__ xh,
                                                 short* __restrict__ xm,
                                                 int M) {
    __shared__ short smem[128 * 64 + BNout * 64];
    gemm_body<K, BNout>(A, Bt, xl, xh, xm, M, xcd_swz(blockIdx.x, gridDim.x), smem);
}

// ---------------------------------------------------------------------------
// fp8 pack kernels (bf16 planes -> fp8 gather buffers)
// ---------------------------------------------------------------------------
// Layer1: word p of xl plane {xl0|xl1} + word p of xh plane {xh0|xh1}
//         -> dword {xl0,xl1,xh0,xh1} fp8
__global__ __launch_bounds__(256) void pack8_1(const unsigned* __restrict__ xl,
                                               const unsigned* __restrict__ xh,
                                               unsigned* __restrict__ xq, int n) {
    int i = blockIdx.x * 256 + threadIdx.x;   // over N*64 pair-words
    if (i >= n) return;
    const unsigned vx = xl[i];
    const unsigned vh = xh[i];
    unsigned r = __builtin_amdgcn_cvt_pk_fp8_f32(b2f_lo(vx), b2f_hi(vx), 0, false);
    r = __builtin_amdgcn_cvt_pk_fp8_f32(b2f_lo(vh), b2f_hi(vh), r, true);
    xq[i] = r;
}

// Layer2: word i of xl2 {xl0|xl1} + word i of xh2 {xh0|xh1}
//         -> dword of 2 ushorts {xl0,xh0},{xl1,xh1} fp8
__global__ __launch_bounds__(256) void pack8_2(const unsigned* __restrict__ xl,
                                               const unsigned* __restrict__ xh,
                                               unsigned* __restrict__ xq, int n) {
    int i = blockIdx.x * 256 + threadIdx.x;   // over N*32 words
    if (i >= n) return;
    const unsigned vx = xl[i];
    const unsigned vh = xh[i];
    unsigned r = __builtin_amdgcn_cvt_pk_fp8_f32(b2f_lo(vx), b2f_lo(vh), 0, false);
    r = __builtin_amdgcn_cvt_pk_fp8_f32(b2f_hi(vx), b2f_hi(vh), r, true);
    xq[i] = r;
}

// ---------------------------------------------------------------------------
// CSR scan chain
// ---------------------------------------------------------------------------
__global__ __launch_bounds__(256) void block_sums_kernel(const int* __restrict__ counts,
                                                         int* __restrict__ bsums, int n) {
    __shared__ int s[256];
    int tid = threadIdx.x;
    int i = blockIdx.x * 256 + tid;
    s[tid] = (i < n) ? counts[i] : 0;
    __syncthreads();
#pragma unroll
    for (int off = 128; off > 0; off >>= 1) {
        if (tid < off) s[tid] += s[tid + off];
        __syncthreads();
    }
    if (tid == 0) bsums[blockIdx.x] = s[0];
}

__global__ __launch_bounds__(256) void scan_bsums_kernel(int* __restrict__ bsums, int nb) {
    __shared__ int s[256];
    int t = threadIdx.x;
    int v = (t < nb) ? bsums[t] : 0;
    s[t] = v;
    __syncthreads();
#pragma unroll
    for (int off = 1; off < 256; off <<= 1) {
        int u = (t >= off) ? s[t - off] : 0;
        __syncthreads();
        s[t] += u;
        __syncthreads();
    }
    if (t < nb) bsums[t] = s[t] - v;      // exclusive
}

__global__ __launch_bounds__(256) void scan_final_kernel(const int* __restrict__ counts,
                                                         const int* __restrict__ bsums,
                                                         int* __restrict__ rowptr,
                                                         int* __restrict__ cursor, int n) {
    __shared__ int s[256];
    int tid = threadIdx.x;
    int i = blockIdx.x * 256 + tid;
    int v = (i < n) ? counts[i] : 0;
    s[tid] = v;
    __syncthreads();
#pragma unroll
    for (int off = 1; off < 256; off <<= 1) {
        int t = (tid >= off) ? s[tid - off] : 0;
        __syncthreads();
        s[tid] += t;
        __syncthreads();
    }
    int excl = s[tid] - v + bsums[blockIdx.x];
    if (i < n) {
        rowptr[i] = excl;
        cursor[i] = excl;
        if (i == n - 1) rowptr[n] = excl + v;
    }
}

// ---------------------------------------------------------------------------
__device__ __forceinline__ float wave_sum(float v) {
#pragma unroll
    for (int off = 32; off > 0; off >>= 1) v += __shfl_xor(v, off, 64);
    return v;
}
__device__ __forceinline__ float wave_max(float v) {
#pragma unroll
    for (int off = 32; off > 0; off >>= 1) v = fmaxf(v, __shfl_xor(v, off, 64));
    return v;
}

// ---------------------------------------------------------------------------
// Layer-1 fused: dual CSR spmm (fp8 gathers) + attention + combine -> h bf16.
// Self terms from xh/xm planes (bf16).
// ---------------------------------------------------------------------------
__global__ __launch_bounds__(256) void spmm_att1(const int* __restrict__ rowptr,
                                                 const int2* __restrict__ edges,
                                                 const unsigned* __restrict__ xq,
                                                 const unsigned* __restrict__ xhp,
                                                 const unsigned* __restrict__ xmp,
                                                 const float* __restrict__ a_low,
                                                 const float* __restrict__ a_high,
                                                 const float* __restrict__ a_mlp,
                                                 const float* __restrict__ av,
                                                 short* __restrict__ hb,
                                                 int n) {
    const int node = blockIdx.x * 4 + (threadIdx.x >> 6);
    const int lane = threadIdx.x & 63;
    if (node >= n) return;

    const int s = __builtin_amdgcn_readfirstlane(rowptr[node]);
    const int e = __builtin_amdgcn_readfirstlane(rowptr[node + 1]);

    float l0 = 0.f, l1 = 0.f, h0 = 0.f, h1 = 0.f;
    for (int j = s; j < e; j += 8) {
        int   cq[8];
        float vq[8];
#pragma unroll
        for (int q = 0; q < 8; ++q) {
            const int jj = min(j + q, e - 1);
            const int2 rec = edges[jj];
            cq[q] = __builtin_amdgcn_readfirstlane(rec.x);
            int vb = __builtin_amdgcn_readfirstlane(rec.y);
            float t = __builtin_bit_cast(float, vb);
            vq[q] = (j + q < e) ? t : 0.f;
        }
        unsigned p[8];
#pragma unroll
        for (int q = 0; q < 8; ++q)
            p[q] = xq[(size_t)cq[q] * 64 + lane];
#pragma unroll
        for (int q = 0; q < 8; ++q) {
            const f32x2 lo = q2_lo(p[q]);
            const f32x2 hi = q2_hi(p[q]);
            l0 += vq[q] * lo.x; l1 += vq[q] * lo.y;
            h0 += vq[q] * hi.x; h1 += vq[q] * hi.y;
        }
    }

    const unsigned xhn = xhp[(size_t)node * 64 + lane];
    const unsigned xmn = xmp[(size_t)node * 64 + lane];
    float ol0 = fmaxf(l0, 0.f);
    float ol1 = fmaxf(l1, 0.f);
    float oh0 = fmaxf(b2f_lo(xhn) - h0, 0.f);
    float oh1 = fmaxf(b2f_hi(xhn) - h1, 0.f);
    float om0 = fmaxf(b2f_lo(xmn), 0.f);
    float om1 = fmaxf(b2f_hi(xmn), 0.f);

    const float2 aL = ((const float2*)a_low)[lane];
    const float2 aH = ((const float2*)a_high)[lane];
    const float2 aM = ((const float2*)a_mlp)[lane];
    float dl = wave_sum(ol0 * aL.x + ol1 * aL.y);
    float dh = wave_sum(oh0 * aH.x + oh1 * aH.y);
    float dm = wave_sum(om0 * aM.x + om1 * aM.y);

    const float g0 = 1.f / (1.f + expf(-dl));
    const float g1 = 1.f / (1.f + expf(-dh));
    const float g2 = 1.f / (1.f + expf(-dm));
    float s0 = (g0 * av[0] + g1 * av[3] + g2 * av[6]) * (1.f / 3.f);
    float s1 = (g0 * av[1] + g1 * av[4] + g2 * av[7]) * (1.f / 3.f);
    float s2 = (g0 * av[2] + g1 * av[5] + g2 * av[8]) * (1.f / 3.f);
    float mx = fmaxf(s0, fmaxf(s1, s2));
    float e0 = expf(s0 - mx), e1 = expf(s1 - mx), e2 = expf(s2 - mx);
    float inv = 1.f / (e0 + e1 + e2);
    float at0 = e0 * inv, at1 = e1 * inv, at2 = e2 * inv;

    float ho0 = 3.f * (at0 * ol0 + at1 * oh0 + at2 * om0);
    float ho1 = 3.f * (at0 * ol1 + at1 * oh1 + at2 * om1);
    unsigned pk = (unsigned)(unsigned short)f2b(ho0) |
                  ((unsigned)(unsigned short)f2b(ho1) << 16);
    ((unsigned*)hb)[(size_t)node * 64 + lane] = pk;
}

// ---------------------------------------------------------------------------
// Layer-2 fused: dual CSR spmm (fp8 ushort gathers) + attention + combine +
// log_softmax -> out. Self terms from xh2/xm2 planes.
// ---------------------------------------------------------------------------
__global__ __launch_bounds__(256) void spmm_att2(const int* __restrict__ rowptr,
                                                 const int2* __restrict__ edges,
                                                 const unsigned short* __restrict__ xq,
                                                 const short* __restrict__ xhp,
                                                 const short* __restrict__ xmp,
                                                 const float* __restrict__ a_low,
                                                 const float* __restrict__ a_high,
                                                 const float* __restrict__ a_mlp,
                                                 const float* __restrict__ av,
                                                 float* __restrict__ out,
                                                 int n) {
    const int node = blockIdx.x * 4 + (threadIdx.x >> 6);
    const int lane = threadIdx.x & 63;
    if (node >= n) return;

    const int s = __builtin_amdgcn_readfirstlane(rowptr[node]);
    const int e = __builtin_amdgcn_readfirstlane(rowptr[node + 1]);

    float accl = 0.f, acch = 0.f;
    for (int j = s; j < e; j += 8) {
        int   cq[8];
        float vq[8];
#pragma unroll
        for (int q = 0; q < 8; ++q) {
            const int jj = min(j + q, e - 1);
            const int2 rec = edges[jj];
            cq[q] = __builtin_amdgcn_readfirstlane(rec.x);
            int vb = __builtin_amdgcn_readfirstlane(rec.y);
            float t = __builtin_bit_cast(float, vb);
            vq[q] = (j + q < e) ? t : 0.f;
        }
        unsigned short p[8];
#pragma unroll
        for (int q = 0; q < 8; ++q)
            p[q] = xq[(size_t)cq[q] * 64 + lane];
#pragma unroll
        for (int q = 0; q < 8; ++q) {
            const f32x2 d = q2_lo((unsigned)p[q]);
            accl += vq[q] * d.x;
            acch += vq[q] * d.y;
        }
    }

    float ol = fmaxf(accl, 0.f);
    float oh = fmaxf(b2f(xhp[(size_t)node * 64 + lane]) - acch, 0.f);
    float om = fmaxf(b2f(xmp[(size_t)node * 64 + lane]), 0.f);

    float dl = wave_sum(ol * a_low[lane]);
    float dh = wave_sum(oh * a_high[lane]);
    float dm = wave_sum(om * a_mlp[lane]);

    const float g0 = 1.f / (1.f + expf(-dl));
    const float g1 = 1.f / (1.f + expf(-dh));
    const float g2 = 1.f / (1.f + expf(-dm));
    float s0 = (g0 * av[0] + g1 * av[3] + g2 * av[6]) * (1.f / 3.f);
    float s1 = (g0 * av[1] + g1 * av[4] + g2 * av[7]) * (1.f / 3.f);
    float s2 = (g0 * av[2] + g1 * av[5] + g2 * av[8]) * (1.f / 3.f);
    float mx3 = fmaxf(s0, fmaxf(s1, s2));
    float e0 = expf(s0 - mx3), e1 = expf(s1 - mx3), e2 = expf(s2 - mx3);
    float inv = 1.f / (e0 + e1 + e2);
    float at0 = e0 * inv, at1 = e1 * inv, at2 = e2 * inv;

    float o = 3.f * (at0 * ol + at1 * oh + at2 * om);

    float m = wave_max(o);
    float ex = expf(o - m);
    float su = wave_sum(ex);
    out[(size_t)node * 64 + lane] = o - m - logf(su);
}

// ---------------------------------------------------------------------------
extern "C" void kernel_launch(void* const* d_in, const int* in_sizes, int n_in,
                              void* d_out, int out_size, void* d_ws, size_t ws_size,
                              hipStream_t stream) {
    const float* x    = (const float*)d_in[0];
    const int*   erow = (const int*)d_in[1];
    const int*   ecol = (const int*)d_in[2];
    const float* eval = (const float*)d_in[3];
    const float* Wl   = (const float*)d_in[4];
    const float* Wh   = (const float*)d_in[5];
    const float* Wm   = (const float*)d_in[6];
    const float* al   = (const float*)d_in[7];
    const float* ah   = (const float*)d_in[8];
    const float* am   = (const float*)d_in[9];
    const float* av   = (const float*)d_in[10];
    const float* Wl2  = (const float*)d_in[11];
    const float* Wh2  = (const float*)d_in[12];
    const float* Wm2  = (const float*)d_in[13];
    const float* al2  = (const float*)d_in[14];
    const float* ah2  = (const float*)d_in[15];
    const float* am2  = (const float*)d_in[16];
    const float* av2  = (const float*)d_in[17];
    float* out = (float*)d_out;

    const int E = in_sizes[1];
    const int N = NN;

    short* ws    = (short*)d_ws;
    short* xb    = ws;                          // N*512 bf16 (converted x)
    short* xl1   = xb + (size_t)N * 512;        // N*128 bf16 plane
    short* xh1   = xl1 + (size_t)N * 128;       // N*128 bf16 plane
    short* xm1   = xh1 + (size_t)N * 128;       // N*128 bf16 plane
    short* hb    = xm1 + (size_t)N * 128;       // N*128 bf16
    short* Bt1   = hb + (size_t)N * 128;        // 384*512
    short* Bt2   = Bt1 + 384 * 512;             // 192*128
    int*   ip    = (int*)(Bt2 + 192 * 128);
    int*   counts = ip;                         // N
    int*   rowptr = ip + N;                     // N+1
    int*   cursor = ip + 2 * N + 1;             // N
    int*   bsums  = ip + 3 * N + 1;             // 256
    int2*  edges  = (int2*)(((size_t)(ip + 3 * N + 1 + 256) + 15) & ~(size_t)15); // E int2

    // fp8 gather buffers alias the dead xb region
    unsigned* xq1 = (unsigned*)xb;              // N*64 dwords (12.8 MB)
    unsigned short* xq2 = (unsigned short*)(xb + (size_t)N * 128);  // N*64 ushorts

    // Layer-2 plane aliases (xl1/xh1/xm1 dead after pack8_1 + spmm_att1)
    short* xl2 = xl1;                           // N*64 bf16
    short* xh2 = xl1 + (size_t)N * 64;          // N*64 bf16
    short* xm2 = xl1 + (size_t)N * 128;         // N*64 bf16

    const int NB = (N + 255) / 256;
    const int EB = (E + 255) / 256;
    const int node_blocks = (N + 3) / 4;
    const int MT = (N + 127) / 128;
    const int XCB = (N * F_IN / 8 + 255) / 256;
    const int W1B = (3 * HH * (F_IN / 8) + 255) / 256;
    const int W2B = (3 * CC * (HH / 8) + 255) / 256;
    const int nGemm1 = MT * 3;

    // ---------------- prep (fused) + CSR scan chain ----------------
    prep0<<<NB + W1B + W2B, 256, 0, stream>>>(counts, N, Wl, Wh, Wm, Bt1,
                                              Wl2, Wh2, Wm2, Bt2, NB, W1B);
    hist_xconv<<<EB + XCB, 256, 0, stream>>>(erow, counts, E, x, xb,
                                             N * F_IN / 8, EB);
    block_sums_kernel<<<NB, 256, 0, stream>>>(counts, bsums, N);
    scan_bsums_kernel<<<1, 256, 0, stream>>>(bsums, NB);
    scan_final_kernel<<<NB, 256, 0, stream>>>(counts, bsums, rowptr, cursor, N);

    // ---------------- Layer 1 (gemm interleaved with edge scatter) ----------
    gemm_scatter<F_IN, HH><<<nGemm1 + EB, 256, 0, stream>>>(
        xb, Bt1, xl1, xh1, xm1, N, nGemm1, erow, ecol, eval, cursor, edges, E, EB);
    pack8_1<<<(N * 64 + 255) / 256, 256, 0, stream>>>((const unsigned*)xl1,
                                                      (const unsigned*)xh1, xq1, N * 64);
    spmm_att1<<<node_blocks, 256, 0, stream>>>(rowptr, edges, xq1,
                                               (const unsigned*)xh1,
                                               (const unsigned*)xm1,
                                               al, ah, am, av, hb, N);

    // ---------------- Layer 2 ----------------
    gemm_mfma<HH, CC><<<MT * 3, 256, 0, stream>>>(hb, Bt2, xl2, xh2, xm2, N);
    pack8_2<<<(N * 32 + 255) / 256, 256, 0, stream>>>((const unsigned*)xl2,
                                                      (const unsigned*)xh2,
                                                      (unsigned*)xq2, N * 32);
    spmm_att2<<<node_blocks, 256, 0, stream>>>(rowptr, edges, xq2, xh2, xm2,
                                               al2, ah2, am2, av2, out, N);
}

// Round 16
// 195.874 us; speedup vs baseline: 1.9401x; 1.0521x over previous
//
#include <hip/hip_runtime.h>
#include <hip/hip_bf16.h>

// Problem constants (reference file)
#define NN 50000
#define F_IN 512
#define HH 128
#define CC 64

typedef __attribute__((ext_vector_type(8))) short short8v;   // 8 bf16 (4 VGPRs)
typedef __attribute__((ext_vector_type(4))) float f32x4;     // MFMA accumulator
typedef __attribute__((ext_vector_type(2))) float f32x2;

__device__ __forceinline__ short f2b(float f) {
    unsigned u = __builtin_bit_cast(unsigned, f);
    unsigned r = (u + 0x7fffu + ((u >> 16) & 1u)) >> 16;     // RNE
    return (short)r;
}
__device__ __forceinline__ float b2f(short s) {
    unsigned u = ((unsigned)(unsigned short)s) << 16;
    return __builtin_bit_cast(float, u);
}
__device__ __forceinline__ float b2f_lo(unsigned p) {
    return __builtin_bit_cast(float, p << 16);
}
__device__ __forceinline__ float b2f_hi(unsigned p) {
    return __builtin_bit_cast(float, p & 0xffff0000u);
}

// fp8 e4m3 (OCP) decode via gfx950 HW converts
__device__ __forceinline__ f32x2 q2_lo(unsigned p) {   // bytes 0,1
    return __builtin_amdgcn_cvt_pk_f32_fp8(p, false);
}
__device__ __forceinline__ f32x2 q2_hi(unsigned p) {   // bytes 2,3
    return __builtin_amdgcn_cvt_pk_f32_fp8(p, true);
}

// Bijective XCD swizzle (m204)
__device__ __forceinline__ int xcd_swz(int bid, int nwg) {
    int q = nwg >> 3, r = nwg & 7;
    int xcd = bid & 7, off = bid >> 3;
    return (xcd < r ? xcd * (q + 1) : r * (q + 1) + (xcd - r) * q) + off;
}

// async global->LDS, 16 B per lane
__device__ __forceinline__ void load_lds16(const short* g, short* l) {
    __builtin_amdgcn_global_load_lds(
        (const __attribute__((address_space(1))) unsigned int*)g,
        (__attribute__((address_space(3))) unsigned int*)l,
        16, 0, 0);
}

// ---------------------------------------------------------------------------
// Weight prep body: interleaved column-tiles.
// Tile t<2 covers {xl feats t*HB..t*HB+HB-1 (local 0..HB-1),
//                  xh feats t*HB..        (local HB..OUTW-1)}; tile 2 = xm.
// ---------------------------------------------------------------------------
template <int K, int OUTW>
__device__ __forceinline__ void wprep_body(const float* __restrict__ W0,
                                           const float* __restrict__ W1,
                                           const float* __restrict__ W2,
                                           short* __restrict__ Bt, int id) {
    const int nth = 3 * OUTW * (K / 8);
    if (id >= nth) return;
    const int n = id / (K / 8);
    const int kq = id % (K / 8);
    constexpr int HB = OUTW / 2;
    const int t = n / OUTW;
    const int r = n % OUTW;
    int sel, c;
    if (t < 2) { sel = (r >= HB) ? 1 : 0; c = t * HB + (r % HB); }
    else       { sel = 2; c = r; }
    const float* W = sel == 0 ? W0 : (sel == 1 ? W1 : W2);
    short v[8];
#pragma unroll
    for (int j = 0; j < 8; ++j) v[j] = f2b(W[(size_t)(kq * 8 + j) * OUTW + c]);
#pragma unroll
    for (int j = 0; j < 8; ++j) Bt[(size_t)n * K + kq * 8 + j] = v[j];
}

// ---------------------------------------------------------------------------
// prep0: zero_counts + wprep(L1) + wprep(L2) in one launch
// ---------------------------------------------------------------------------
__global__ __launch_bounds__(256) void prep0(int* __restrict__ counts, int n,
                                             const float* __restrict__ Wl,
                                             const float* __restrict__ Wh,
                                             const float* __restrict__ Wm,
                                             short* __restrict__ Bt1,
                                             const float* __restrict__ Wl2,
                                             const float* __restrict__ Wh2,
                                             const float* __restrict__ Wm2,
                                             short* __restrict__ Bt2,
                                             int nZero, int nW1) {
    const int b = blockIdx.x;
    if (b < nZero) {
        int i = b * 256 + threadIdx.x;
        if (i < n) counts[i] = 0;
    } else if (b < nZero + nW1) {
        wprep_body<F_IN, HH>(Wl, Wh, Wm, Bt1, (b - nZero) * 256 + threadIdx.x);
    } else {
        wprep_body<HH, CC>(Wl2, Wh2, Wm2, Bt2, (b - nZero - nW1) * 256 + threadIdx.x);
    }
}

// ---------------------------------------------------------------------------
// hist_xconv: histogram atomics interleaved under BW-bound xconv (Bresenham)
// ---------------------------------------------------------------------------
__global__ __launch_bounds__(256) void hist_xconv(const int* __restrict__ erow,
                                                  int* __restrict__ counts, int E,
                                                  const float* __restrict__ x,
                                                  short* __restrict__ xb, int n8,
                                                  int nHist) {
    const int b = blockIdx.x;
    const int total = gridDim.x;
    const long hb4 = ((long)b * nHist) / total;
    const long ha4 = ((long)(b + 1) * nHist) / total;
    if (ha4 != hb4) {
        int i = (int)hb4 * 256 + threadIdx.x;
        if (i < E) atomicAdd(&counts[erow[i]], 1);
        return;
    }
    int i = (b - (int)hb4) * 256 + threadIdx.x;
    if (i >= n8) return;
    const float4* xp = (const float4*)x;
    const float4 a = xp[2 * i];
    const float4 bb = xp[2 * i + 1];
    short8v o;
    o[0] = f2b(a.x); o[1] = f2b(a.y); o[2] = f2b(a.z); o[3] = f2b(a.w);
    o[4] = f2b(bb.x); o[5] = f2b(bb.y); o[6] = f2b(bb.z); o[7] = f2b(bb.w);
    *reinterpret_cast<short8v*>(&xb[(size_t)i * 8]) = o;
}

// ---------------------------------------------------------------------------
// GEMM body: MFMA + global_load_lds + XOR slot swizzle + LDS-staged epilogue.
// bn<2: writes xh bf16 half-plane + fp8 gather words directly.
// bn==2: writes xm bf16 plane.
// ---------------------------------------------------------------------------
template <int K, int BNout>
__device__ __forceinline__ void gemm_body(const short* __restrict__ A,
                                          const short* __restrict__ Bt,
                                          unsigned* __restrict__ xq,
                                          short* __restrict__ xh,
                                          short* __restrict__ xm,
                                          int M, int wg, short* smem) {
    constexpr int BM = 128, BK = 64;
    constexpr int FM = (BNout == 128) ? 4 : 2;
    constexpr int FN = 4;
    constexpr int WM = FM * 16;
    constexpr int NKT = K / BK;
    constexpr int NBL = BNout / 32;
    constexpr int HB = BNout / 2;

    short* As = smem;                    // BM*BK
    short* Bs = smem + BM * BK;          // BNout*BK

    const int tid = threadIdx.x;
    const int lane = tid & 63;
    const int wid = tid >> 6;
    const int bm = wg / 3;
    const int bn = wg % 3;
    const int m0 = bm * BM;
    const int n0 = bn * BNout;
    const int wm = (BNout == 128) ? (wid >> 1) : wid;
    const int wn = (BNout == 128) ? (wid & 1) : 0;

    const int r8 = lane >> 3;
    const int sl = (lane & 7) ^ r8;

    f32x4 acc[FM][FN];
#pragma unroll
    for (int i = 0; i < FM; ++i)
#pragma unroll
        for (int j = 0; j < FN; ++j) acc[i][j] = (f32x4){0.f, 0.f, 0.f, 0.f};

    for (int kt = 0; kt < NKT; ++kt) {
        const int k0 = kt * BK;
        __syncthreads();
#pragma unroll
        for (int i = 0; i < 4; ++i) {
            int r = (wid * 4 + i) * 8 + r8;
            int gr = m0 + r; if (gr >= M) gr = M - 1;
            load_lds16(&A[(size_t)gr * K + k0 + sl * 8], &As[(wid * 4 + i) * 512]);
        }
#pragma unroll
        for (int i = 0; i < NBL; ++i) {
            int r = (wid * NBL + i) * 8 + r8;
            load_lds16(&Bt[(size_t)(n0 + r) * K + k0 + sl * 8],
                       &Bs[(wid * NBL + i) * 512]);
        }
        __syncthreads();

        const int mrow = lane & 15;
        const int kg = lane >> 4;
#pragma unroll
        for (int kk = 0; kk < 2; ++kk) {
            short8v af[FM], bf[FN];
#pragma unroll
            for (int f = 0; f < FM; ++f) {
                int m = wm * WM + f * 16 + mrow;
                int s = kk * 4 + kg;
                af[f] = *reinterpret_cast<const short8v*>(
                    &As[m * 64 + ((s ^ (m & 7)) << 3)]);
            }
#pragma unroll
            for (int f = 0; f < FN; ++f) {
                int nr = wn * 64 + f * 16 + mrow;
                int s = kk * 4 + kg;
                bf[f] = *reinterpret_cast<const short8v*>(
                    &Bs[nr * 64 + ((s ^ (nr & 7)) << 3)]);
            }
#pragma unroll
            for (int i = 0; i < FM; ++i)
#pragma unroll
                for (int j = 0; j < FN; ++j)
                    acc[i][j] = __builtin_amdgcn_mfma_f32_16x16x32_bf16(
                        af[i], bf[j], acc[i][j], 0, 0, 0);
        }
    }

    // ---- stage accumulator tile into LDS (bf16) ----
    __syncthreads();
#pragma unroll
    for (int i = 0; i < FM; ++i)
#pragma unroll
        for (int j = 0; j < FN; ++j) {
            int cc = wn * 64 + j * 16 + (lane & 15);
#pragma unroll
            for (int e = 0; e < 4; ++e) {
                int r = wm * WM + i * 16 + (lane >> 4) * 4 + e;
                smem[r * BNout + cc] = f2b(acc[i][j][e]);
            }
        }
    __syncthreads();

    if (bn == 2) {
        // xm plane, full BNout cols, int4-coalesced
        constexpr int CH = BM * BNout / 8;
#pragma unroll
        for (int p = 0; p < CH / 256; ++p) {
            int idx = p * 256 + tid;
            int r = idx / (BNout / 8);
            int c8 = idx % (BNout / 8);
            int grow = m0 + r;
            if (grow < M)
                *reinterpret_cast<int4*>(&xm[(size_t)grow * BNout + c8 * 8]) =
                    *reinterpret_cast<const int4*>(&smem[r * BNout + c8 * 8]);
        }
    } else {
        // xh bf16 half-plane (local cols HB..BNout-1 are xh feats bn*HB..)
#pragma unroll
        for (int p = 0; p < (BM * (HB / 8)) / 256; ++p) {
            int idx = p * 256 + tid;
            int r = idx / (HB / 8);
            int c8 = idx % (HB / 8);
            int grow = m0 + r;
            if (grow < M)
                *reinterpret_cast<int4*>(&xh[(size_t)grow * BNout + bn * HB + c8 * 8]) =
                    *reinterpret_cast<const int4*>(&smem[r * BNout + HB + c8 * 8]);
        }
        // fp8 gather words: row stride BNout/2 dwords, tile offset bn*(BNout/4)
#pragma unroll
        for (int p = 0; p < (BM * (BNout / 4)) / 256; ++p) {
            int idx = p * 256 + tid;
            int r = idx / (BNout / 4);
            int k = idx % (BNout / 4);
            int grow = m0 + r;
            if (grow < M) {
                unsigned lw = *reinterpret_cast<const unsigned*>(&smem[r * BNout + 2 * k]);
                unsigned hw = *reinterpret_cast<const unsigned*>(&smem[r * BNout + HB + 2 * k]);
                unsigned w;
                if (BNout == 128) {
                    // L1: bytes {xl0, xl1, xh0, xh1}
                    w = __builtin_amdgcn_cvt_pk_fp8_f32(b2f_lo(lw), b2f_hi(lw), 0, false);
                    w = __builtin_amdgcn_cvt_pk_fp8_f32(b2f_lo(hw), b2f_hi(hw), w, true);
                } else {
                    // L2: bytes {xl0, xh0, xl1, xh1}
                    w = __builtin_amdgcn_cvt_pk_fp8_f32(b2f_lo(lw), b2f_lo(hw), 0, false);
                    w = __builtin_amdgcn_cvt_pk_fp8_f32(b2f_hi(lw), b2f_hi(hw), w, true);
                }
                xq[(size_t)grow * (BNout / 2) + bn * (BNout / 4) + k] = w;
            }
        }
    }
}

// ---------------------------------------------------------------------------
// Fused layer-1 GEMM + edge scatter (Bresenham-interleaved roles)
// ---------------------------------------------------------------------------
template <int K, int BNout>
__global__ __launch_bounds__(256) void gemm_scatter(const short* __restrict__ A,
                                                    const short* __restrict__ Bt,
                                                    unsigned* __restrict__ xq,
                                                    short* __restrict__ xh,
                                                    short* __restrict__ xm,
                                                    int M, int nGemm,
                                                    const int* __restrict__ row,
                                                    const int* __restrict__ col,
                                                    const float* __restrict__ val,
                                                    int* __restrict__ cursor,
                                                    int2* __restrict__ edges, int E,
                                                    int nScat) {
    __shared__ short smem[128 * 64 + BNout * 64];

    const int total = nGemm + nScat;
    const int swz = xcd_swz(blockIdx.x, total);
    const long ns_b = ((long)swz * nScat) / total;
    const long ns_a = ((long)(swz + 1) * nScat) / total;

    if (ns_a != ns_b) {
        int i = (int)ns_b * 256 + threadIdx.x;
        if (i < E) {
            int r = row[i];
            int p = atomicAdd(&cursor[r], 1);
            int2 rec;
            rec.x = col[i];
            rec.y = __builtin_bit_cast(int, val[i]);
            edges[p] = rec;
        }
        return;
    }
    gemm_body<K, BNout>(A, Bt, xq, xh, xm, M, swz - (int)ns_b, smem);
}

// ---------------------------------------------------------------------------
// Standalone layer-2 GEMM
// ---------------------------------------------------------------------------
template <int K, int BNout>
__global__ __launch_bounds__(256) void gemm_mfma(const short* __restrict__ A,
                                                 const short* __restrict__ Bt,
                                                 unsigned* __restrict__ xq,
                                                 short* __restrict__ xh,
                                                 short* __restrict__ xm,
                                                 int M) {
    __shared__ short smem[128 * 64 + BNout * 64];
    gemm_body<K, BNout>(A, Bt, xq, xh, xm, M, xcd_swz(blockIdx.x, gridDim.x), smem);
}

// ---------------------------------------------------------------------------
// CSR scan chain
// ---------------------------------------------------------------------------
__global__ __launch_bounds__(256) void block_sums_kernel(const int* __restrict__ counts,
                                                         int* __restrict__ bsums, int n) {
    __shared__ int s[256];
    int tid = threadIdx.x;
    int i = blockIdx.x * 256 + tid;
    s[tid] = (i < n) ? counts[i] : 0;
    __syncthreads();
#pragma unroll
    for (int off = 128; off > 0; off >>= 1) {
        if (tid < off) s[tid] += s[tid + off];
        __syncthreads();
    }
    if (tid == 0) bsums[blockIdx.x] = s[0];
}

__global__ __launch_bounds__(256) void scan_bsums_kernel(int* __restrict__ bsums, int nb) {
    __shared__ int s[256];
    int t = threadIdx.x;
    int v = (t < nb) ? bsums[t] : 0;
    s[t] = v;
    __syncthreads();
#pragma unroll
    for (int off = 1; off < 256; off <<= 1) {
        int u = (t >= off) ? s[t - off] : 0;
        __syncthreads();
        s[t] += u;
        __syncthreads();
    }
    if (t < nb) bsums[t] = s[t] - v;      // exclusive
}

__global__ __launch_bounds__(256) void scan_final_kernel(const int* __restrict__ counts,
                                                         const int* __restrict__ bsums,
                                                         int* __restrict__ rowptr,
                                                         int* __restrict__ cursor, int n) {
    __shared__ int s[256];
    int tid = threadIdx.x;
    int i = blockIdx.x * 256 + tid;
    int v = (i < n) ? counts[i] : 0;
    s[tid] = v;
    __syncthreads();
#pragma unroll
    for (int off = 1; off < 256; off <<= 1) {
        int t = (tid >= off) ? s[tid - off] : 0;
        __syncthreads();
        s[tid] += t;
        __syncthreads();
    }
    int excl = s[tid] - v + bsums[blockIdx.x];
    if (i < n) {
        rowptr[i] = excl;
        cursor[i] = excl;
        if (i == n - 1) rowptr[n] = excl + v;
    }
}

// ---------------------------------------------------------------------------
__device__ __forceinline__ float wave_sum(float v) {
#pragma unroll
    for (int off = 32; off > 0; off >>= 1) v += __shfl_xor(v, off, 64);
    return v;
}
__device__ __forceinline__ float wave_max(float v) {
#pragma unroll
    for (int off = 32; off > 0; off >>= 1) v = fmaxf(v, __shfl_xor(v, off, 64));
    return v;
}

// ---------------------------------------------------------------------------
// Layer-1 fused: dual CSR spmm (fp8 gathers) + attention + combine -> h bf16.
// ---------------------------------------------------------------------------
__global__ __launch_bounds__(256) void spmm_att1(const int* __restrict__ rowptr,
                                                 const int2* __restrict__ edges,
                                                 const unsigned* __restrict__ xq,
                                                 const unsigned* __restrict__ xhp,
                                                 const unsigned* __restrict__ xmp,
                                                 const float* __restrict__ a_low,
                                                 const float* __restrict__ a_high,
                                                 const float* __restrict__ a_mlp,
                                                 const float* __restrict__ av,
                                                 short* __restrict__ hb,
                                                 int n) {
    const int node = blockIdx.x * 4 + (threadIdx.x >> 6);
    const int lane = threadIdx.x & 63;
    if (node >= n) return;

    const int s = __builtin_amdgcn_readfirstlane(rowptr[node]);
    const int e = __builtin_amdgcn_readfirstlane(rowptr[node + 1]);

    float l0 = 0.f, l1 = 0.f, h0 = 0.f, h1 = 0.f;
    for (int j = s; j < e; j += 8) {
        int   cq[8];
        float vq[8];
#pragma unroll
        for (int q = 0; q < 8; ++q) {
            const int jj = min(j + q, e - 1);
            const int2 rec = edges[jj];
            cq[q] = __builtin_amdgcn_readfirstlane(rec.x);
            int vb = __builtin_amdgcn_readfirstlane(rec.y);
            float t = __builtin_bit_cast(float, vb);
            vq[q] = (j + q < e) ? t : 0.f;
        }
        unsigned p[8];
#pragma unroll
        for (int q = 0; q < 8; ++q)
            p[q] = xq[(size_t)cq[q] * 64 + lane];
#pragma unroll
        for (int q = 0; q < 8; ++q) {
            const f32x2 lo = q2_lo(p[q]);
            const f32x2 hi = q2_hi(p[q]);
            l0 += vq[q] * lo.x; l1 += vq[q] * lo.y;
            h0 += vq[q] * hi.x; h1 += vq[q] * hi.y;
        }
    }

    const unsigned xhn = xhp[(size_t)node * 64 + lane];
    const unsigned xmn = xmp[(size_t)node * 64 + lane];
    float ol0 = fmaxf(l0, 0.f);
    float ol1 = fmaxf(l1, 0.f);
    float oh0 = fmaxf(b2f_lo(xhn) - h0, 0.f);
    float oh1 = fmaxf(b2f_hi(xhn) - h1, 0.f);
    float om0 = fmaxf(b2f_lo(xmn), 0.f);
    float om1 = fmaxf(b2f_hi(xmn), 0.f);

    const float2 aL = ((const float2*)a_low)[lane];
    const float2 aH = ((const float2*)a_high)[lane];
    const float2 aM = ((const float2*)a_mlp)[lane];
    float dl = wave_sum(ol0 * aL.x + ol1 * aL.y);
    float dh = wave_sum(oh0 * aH.x + oh1 * aH.y);
    float dm = wave_sum(om0 * aM.x + om1 * aM.y);

    const float g0 = 1.f / (1.f + expf(-dl));
    const float g1 = 1.f / (1.f + expf(-dh));
    const float g2 = 1.f / (1.f + expf(-dm));
    float s0 = (g0 * av[0] + g1 * av[3] + g2 * av[6]) * (1.f / 3.f);
    float s1 = (g0 * av[1] + g1 * av[4] + g2 * av[7]) * (1.f / 3.f);
    float s2 = (g0 * av[2] + g1 * av[5] + g2 * av[8]) * (1.f / 3.f);
    float mx = fmaxf(s0, fmaxf(s1, s2));
    float e0 = expf(s0 - mx), e1 = expf(s1 - mx), e2 = expf(s2 - mx);
    float inv = 1.f / (e0 + e1 + e2);
    float at0 = e0 * inv, at1 = e1 * inv, at2 = e2 * inv;

    float ho0 = 3.f * (at0 * ol0 + at1 * oh0 + at2 * om0);
    float ho1 = 3.f * (at0 * ol1 + at1 * oh1 + at2 * om1);
    unsigned pk = (unsigned)(unsigned short)f2b(ho0) |
                  ((unsigned)(unsigned short)f2b(ho1) << 16);
    ((unsigned*)hb)[(size_t)node * 64 + lane] = pk;
}

// ---------------------------------------------------------------------------
// Layer-2 fused: dual CSR spmm (fp8 ushort gathers) + attention + combine +
// log_softmax -> out.
// ---------------------------------------------------------------------------
__global__ __launch_bounds__(256) void spmm_att2(const int* __restrict__ rowptr,
                                                 const int2* __restrict__ edges,
                                                 const unsigned short* __restrict__ xq,
                                                 const short* __restrict__ xhp,
                                                 const short* __restrict__ xmp,
                                                 const float* __restrict__ a_low,
                                                 const float* __restrict__ a_high,
                                                 const float* __restrict__ a_mlp,
                                                 const float* __restrict__ av,
                                                 float* __restrict__ out,
                                                 int n) {
    const int node = blockIdx.x * 4 + (threadIdx.x >> 6);
    const int lane = threadIdx.x & 63;
    if (node >= n) return;

    const int s = __builtin_amdgcn_readfirstlane(rowptr[node]);
    const int e = __builtin_amdgcn_readfirstlane(rowptr[node + 1]);

    float accl = 0.f, acch = 0.f;
    for (int j = s; j < e; j += 8) {
        int   cq[8];
        float vq[8];
#pragma unroll
        for (int q = 0; q < 8; ++q) {
            const int jj = min(j + q, e - 1);
            const int2 rec = edges[jj];
            cq[q] = __builtin_amdgcn_readfirstlane(rec.x);
            int vb = __builtin_amdgcn_readfirstlane(rec.y);
            float t = __builtin_bit_cast(float, vb);
            vq[q] = (j + q < e) ? t : 0.f;
        }
        unsigned short p[8];
#pragma unroll
        for (int q = 0; q < 8; ++q)
            p[q] = xq[(size_t)cq[q] * 64 + lane];
#pragma unroll
        for (int q = 0; q < 8; ++q) {
            const f32x2 d = q2_lo((unsigned)p[q]);
            accl += vq[q] * d.x;
            acch += vq[q] * d.y;
        }
    }

    float ol = fmaxf(accl, 0.f);
    float oh = fmaxf(b2f(xhp[(size_t)node * 64 + lane]) - acch, 0.f);
    float om = fmaxf(b2f(xmp[(size_t)node * 64 + lane]), 0.f);

    float dl = wave_sum(ol * a_low[lane]);
    float dh = wave_sum(oh * a_high[lane]);
    float dm = wave_sum(om * a_mlp[lane]);

    const float g0 = 1.f / (1.f + expf(-dl));
    const float g1 = 1.f / (1.f + expf(-dh));
    const float g2 = 1.f / (1.f + expf(-dm));
    float s0 = (g0 * av[0] + g1 * av[3] + g2 * av[6]) * (1.f / 3.f);
    float s1 = (g0 * av[1] + g1 * av[4] + g2 * av[7]) * (1.f / 3.f);
    float s2 = (g0 * av[2] + g1 * av[5] + g2 * av[8]) * (1.f / 3.f);
    float mx3 = fmaxf(s0, fmaxf(s1, s2));
    float e0 = expf(s0 - mx3), e1 = expf(s1 - mx3), e2 = expf(s2 - mx3);
    float inv = 1.f / (e0 + e1 + e2);
    float at0 = e0 * inv, at1 = e1 * inv, at2 = e2 * inv;

    float o = 3.f * (at0 * ol + at1 * oh + at2 * om);

    float m = wave_max(o);
    float ex = expf(o - m);
    float su = wave_sum(ex);
    out[(size_t)node * 64 + lane] = o - m - logf(su);
}

// ---------------------------------------------------------------------------
extern "C" void kernel_launch(void* const* d_in, const int* in_sizes, int n_in,
                              void* d_out, int out_size, void* d_ws, size_t ws_size,
                              hipStream_t stream) {
    const float* x    = (const float*)d_in[0];
    const int*   erow = (const int*)d_in[1];
    const int*   ecol = (const int*)d_in[2];
    const float* eval = (const float*)d_in[3];
    const float* Wl   = (const float*)d_in[4];
    const float* Wh   = (const float*)d_in[5];
    const float* Wm   = (const float*)d_in[6];
    const float* al   = (const float*)d_in[7];
    const float* ah   = (const float*)d_in[8];
    const float* am   = (const float*)d_in[9];
    const float* av   = (const float*)d_in[10];
    const float* Wl2  = (const float*)d_in[11];
    const float* Wh2  = (const float*)d_in[12];
    const float* Wm2  = (const float*)d_in[13];
    const float* al2  = (const float*)d_in[14];
    const float* ah2  = (const float*)d_in[15];
    const float* am2  = (const float*)d_in[16];
    const float* av2  = (const float*)d_in[17];
    float* out = (float*)d_out;

    const int E = in_sizes[1];
    const int N = NN;

    short* ws    = (short*)d_ws;
    short* xb    = ws;                          // N*512 bf16 (converted x)
    short* xh1   = xb + (size_t)N * 512;        // N*128 bf16 plane
    short* xm1   = xh1 + (size_t)N * 128;       // N*128 bf16 plane
    short* hb    = xm1 + (size_t)N * 128;       // N*128 bf16
    unsigned* xq1 = (unsigned*)(hb + (size_t)N * 128);   // N*64 dwords (12.8 MB)
    short* Bt1   = (short*)(xq1 + (size_t)N * 64);       // 384*512
    short* Bt2   = Bt1 + 384 * 512;             // 192*128
    int*   ip    = (int*)(Bt2 + 192 * 128);
    int*   counts = ip;                         // N
    int*   rowptr = ip + N;                     // N+1
    int*   cursor = ip + 2 * N + 1;             // N
    int*   bsums  = ip + 3 * N + 1;             // 256
    int2*  edges  = (int2*)(((size_t)(ip + 3 * N + 1 + 256) + 15) & ~(size_t)15); // E int2

    // Layer-2 aliases (xh1/xm1/xq1 dead after spmm_att1)
    unsigned* xq2 = xq1;                        // N*32 dwords (N*64 fp8 ushorts)
    short* xh2 = xh1;                           // N*64 bf16
    short* xm2 = xh1 + (size_t)N * 64;          // N*64 bf16

    const int NB = (N + 255) / 256;
    const int EB = (E + 255) / 256;
    const int node_blocks = (N + 3) / 4;
    const int MT = (N + 127) / 128;
    const int XCB = (N * F_IN / 8 + 255) / 256;
    const int W1B = (3 * HH * (F_IN / 8) + 255) / 256;
    const int W2B = (3 * CC * (HH / 8) + 255) / 256;
    const int nGemm1 = MT * 3;

    // ---------------- prep (fused) + CSR scan chain ----------------
    prep0<<<NB + W1B + W2B, 256, 0, stream>>>(counts, N, Wl, Wh, Wm, Bt1,
                                              Wl2, Wh2, Wm2, Bt2, NB, W1B);
    hist_xconv<<<EB + XCB, 256, 0, stream>>>(erow, counts, E, x, xb,
                                             N * F_IN / 8, EB);
    block_sums_kernel<<<NB, 256, 0, stream>>>(counts, bsums, N);
    scan_bsums_kernel<<<1, 256, 0, stream>>>(bsums, NB);
    scan_final_kernel<<<NB, 256, 0, stream>>>(counts, bsums, rowptr, cursor, N);

    // ---------------- Layer 1 (gemm interleaved with edge scatter) ----------
    gemm_scatter<F_IN, HH><<<nGemm1 + EB, 256, 0, stream>>>(
        xb, Bt1, xq1, xh1, xm1, N, nGemm1, erow, ecol, eval, cursor, edges, E, EB);
    spmm_att1<<<node_blocks, 256, 0, stream>>>(rowptr, edges, xq1,
                                               (const unsigned*)xh1,
                                               (const unsigned*)xm1,
                                               al, ah, am, av, hb, N);

    // ---------------- Layer 2 ----------------
    gemm_mfma<HH, CC><<<MT * 3, 256, 0, stream>>>(hb, Bt2, xq2, xh2, xm2, N);
    spmm_att2<<<node_blocks, 256, 0, stream>>>(rowptr, edges,
                                               (const unsigned short*)xq2,
                                               xh2, xm2,
                                               al2, ah2, am2, av2, out, N);
}

// Round 17
// 195.843 us; speedup vs baseline: 1.9404x; 1.0002x over previous
//
#include <hip/hip_runtime.h>
#include <hip/hip_bf16.h>

// Problem constants (reference file)
#define NN 50000
#define F_IN 512
#define HH 128
#define CC 64

typedef __attribute__((ext_vector_type(8))) short short8v;   // 8 bf16 (4 VGPRs)
typedef __attribute__((ext_vector_type(4))) float f32x4;     // MFMA accumulator
typedef __attribute__((ext_vector_type(2))) float f32x2;

__device__ __forceinline__ short f2b(float f) {
    unsigned u = __builtin_bit_cast(unsigned, f);
    unsigned r = (u + 0x7fffu + ((u >> 16) & 1u)) >> 16;     // RNE
    return (short)r;
}
__device__ __forceinline__ float b2f(short s) {
    unsigned u = ((unsigned)(unsigned short)s) << 16;
    return __builtin_bit_cast(float, u);
}
__device__ __forceinline__ float b2f_lo(unsigned p) {
    return __builtin_bit_cast(float, p << 16);
}
__device__ __forceinline__ float b2f_hi(unsigned p) {
    return __builtin_bit_cast(float, p & 0xffff0000u);
}

// fp8 e4m3 (OCP) decode via gfx950 HW converts
__device__ __forceinline__ f32x2 q2_lo(unsigned p) {   // bytes 0,1
    return __builtin_amdgcn_cvt_pk_f32_fp8(p, false);
}
__device__ __forceinline__ f32x2 q2_hi(unsigned p) {   // bytes 2,3
    return __builtin_amdgcn_cvt_pk_f32_fp8(p, true);
}

// Bijective XCD swizzle (m204)
__device__ __forceinline__ int xcd_swz(int bid, int nwg) {
    int q = nwg >> 3, r = nwg & 7;
    int xcd = bid & 7, off = bid >> 3;
    return (xcd < r ? xcd * (q + 1) : r * (q + 1) + (xcd - r) * q) + off;
}

// async global->LDS, 16 B per lane
__device__ __forceinline__ void load_lds16(const short* g, short* l) {
    __builtin_amdgcn_global_load_lds(
        (const __attribute__((address_space(1))) unsigned int*)g,
        (__attribute__((address_space(3))) unsigned int*)l,
        16, 0, 0);
}

// ---------------------------------------------------------------------------
// Weight prep body: interleaved column-tiles.
// ---------------------------------------------------------------------------
template <int K, int OUTW>
__device__ __forceinline__ void wprep_body(const float* __restrict__ W0,
                                           const float* __restrict__ W1,
                                           const float* __restrict__ W2,
                                           short* __restrict__ Bt, int id) {
    const int nth = 3 * OUTW * (K / 8);
    if (id >= nth) return;
    const int n = id / (K / 8);
    const int kq = id % (K / 8);
    constexpr int HB = OUTW / 2;
    const int t = n / OUTW;
    const int r = n % OUTW;
    int sel, c;
    if (t < 2) { sel = (r >= HB) ? 1 : 0; c = t * HB + (r % HB); }
    else       { sel = 2; c = r; }
    const float* W = sel == 0 ? W0 : (sel == 1 ? W1 : W2);
    short v[8];
#pragma unroll
    for (int j = 0; j < 8; ++j) v[j] = f2b(W[(size_t)(kq * 8 + j) * OUTW + c]);
#pragma unroll
    for (int j = 0; j < 8; ++j) Bt[(size_t)n * K + kq * 8 + j] = v[j];
}

// ---------------------------------------------------------------------------
// prep0: zero_counts + wprep(L1) + wprep(L2) in one launch
// ---------------------------------------------------------------------------
__global__ __launch_bounds__(256) void prep0(int* __restrict__ counts, int n,
                                             const float* __restrict__ Wl,
                                             const float* __restrict__ Wh,
                                             const float* __restrict__ Wm,
                                             short* __restrict__ Bt1,
                                             const float* __restrict__ Wl2,
                                             const float* __restrict__ Wh2,
                                             const float* __restrict__ Wm2,
                                             short* __restrict__ Bt2,
                                             int nZero, int nW1) {
    const int b = blockIdx.x;
    if (b < nZero) {
        int i = b * 256 + threadIdx.x;
        if (i < n) counts[i] = 0;
    } else if (b < nZero + nW1) {
        wprep_body<F_IN, HH>(Wl, Wh, Wm, Bt1, (b - nZero) * 256 + threadIdx.x);
    } else {
        wprep_body<HH, CC>(Wl2, Wh2, Wm2, Bt2, (b - nZero - nW1) * 256 + threadIdx.x);
    }
}

// ---------------------------------------------------------------------------
// hist_xconv: histogram atomics interleaved under BW-bound xconv (Bresenham)
// ---------------------------------------------------------------------------
__global__ __launch_bounds__(256) void hist_xconv(const int* __restrict__ erow,
                                                  int* __restrict__ counts, int E,
                                                  const float* __restrict__ x,
                                                  short* __restrict__ xb, int n8,
                                                  int nHist) {
    const int b = blockIdx.x;
    const int total = gridDim.x;
    const long hb4 = ((long)b * nHist) / total;
    const long ha4 = ((long)(b + 1) * nHist) / total;
    if (ha4 != hb4) {
        int i = (int)hb4 * 256 + threadIdx.x;
        if (i < E) atomicAdd(&counts[erow[i]], 1);
        return;
    }
    int i = (b - (int)hb4) * 256 + threadIdx.x;
    if (i >= n8) return;
    const float4* xp = (const float4*)x;
    const float4 a = xp[2 * i];
    const float4 bb = xp[2 * i + 1];
    short8v o;
    o[0] = f2b(a.x); o[1] = f2b(a.y); o[2] = f2b(a.z); o[3] = f2b(a.w);
    o[4] = f2b(bb.x); o[5] = f2b(bb.y); o[6] = f2b(bb.z); o[7] = f2b(bb.w);
    *reinterpret_cast<short8v*>(&xb[(size_t)i * 8]) = o;
}

// ---------------------------------------------------------------------------
// GEMM body: double-buffered BK=32 pipeline, counted vmcnt across raw
// barriers (loads for tile t+1 stay in flight during tile t's MFMA).
// Epilogue: LDS-staged; bn<2 writes xh bf16 half-plane + fp8 gather words,
// bn==2 writes xm bf16 plane.
// ---------------------------------------------------------------------------
template <int K, int BNout>
__device__ __forceinline__ void gemm_body(const short* __restrict__ A,
                                          const short* __restrict__ Bt,
                                          unsigned* __restrict__ xq,
                                          short* __restrict__ xh,
                                          short* __restrict__ xm,
                                          int M, int wg, short* smem) {
    constexpr int BM = 128, BK = 32;
    constexpr int FM = (BNout == 128) ? 4 : 2;
    constexpr int FN = 4;
    constexpr int WM = FM * 16;
    constexpr int NKT = K / BK;
    constexpr int AW = (BM * BK / 512) / 4;       // A gll per wave (2)
    constexpr int BW_ = (BNout * BK / 512) / 4;   // B gll per wave (2 or 1)
    constexpr int VMC = AW + BW_;                 // per-tile in-flight per wave
    constexpr int HALF = BM * BK + BNout * BK;    // shorts per buffer
    constexpr int HB = BNout / 2;

    const int tid = threadIdx.x;
    const int lane = tid & 63;
    const int wid = tid >> 6;
    const int bm = wg / 3;
    const int bn = wg % 3;
    const int m0 = bm * BM;
    const int n0 = bn * BNout;
    const int wm = (BNout == 128) ? (wid >> 1) : wid;
    const int wn = (BNout == 128) ? (wid & 1) : 0;

    const int rl = lane >> 2;                     // row-within-chunk 0..15
    const int sl = (lane & 3) ^ ((lane >> 3) & 3);  // source slot (bank swizzle)

    f32x4 acc[FM][FN];
#pragma unroll
    for (int i = 0; i < FM; ++i)
#pragma unroll
        for (int j = 0; j < FN; ++j) acc[i][j] = (f32x4){0.f, 0.f, 0.f, 0.f};

    auto issue = [&](int kt, int b) {
        const int k0 = kt * BK;
        short* As = smem + b * HALF;
        short* Bs = As + BM * BK;
#pragma unroll
        for (int i = 0; i < AW; ++i) {
            int g = wid * AW + i;
            int r = g * 16 + rl;
            int gr = m0 + r; if (gr >= M) gr = M - 1;
            load_lds16(&A[(size_t)gr * K + k0 + sl * 8], &As[g * 512]);
        }
#pragma unroll
        for (int i = 0; i < BW_; ++i) {
            int g = wid * BW_ + i;
            int r = g * 16 + rl;
            load_lds16(&Bt[(size_t)(n0 + r) * K + k0 + sl * 8], &Bs[g * 512]);
        }
    };

    issue(0, 0);

    const int mrow = lane & 15;
    const int kg = lane >> 4;                     // 0..3
    for (int kt = 0; kt < NKT; ++kt) {
        const int cur = kt & 1;
        if (kt + 1 < NKT) {
            issue(kt + 1, cur ^ 1);
            asm volatile("s_waitcnt vmcnt(%0)" :: "n"(VMC) : "memory");
        } else {
            asm volatile("s_waitcnt vmcnt(0)" ::: "memory");
        }
        __builtin_amdgcn_s_barrier();
        __builtin_amdgcn_sched_barrier(0);

        const short* As = smem + cur * HALF;
        const short* Bs = As + BM * BK;
        short8v af[FM], bf[FN];
#pragma unroll
        for (int f = 0; f < FM; ++f) {
            int m = wm * WM + f * 16 + mrow;
            af[f] = *reinterpret_cast<const short8v*>(
                &As[m * 32 + ((kg ^ ((m >> 1) & 3)) << 3)]);
        }
#pragma unroll
        for (int f = 0; f < FN; ++f) {
            int nr = wn * 64 + f * 16 + mrow;
            bf[f] = *reinterpret_cast<const short8v*>(
                &Bs[nr * 32 + ((kg ^ ((nr >> 1) & 3)) << 3)]);
        }
#pragma unroll
        for (int i = 0; i < FM; ++i)
#pragma unroll
            for (int j = 0; j < FN; ++j)
                acc[i][j] = __builtin_amdgcn_mfma_f32_16x16x32_bf16(
                    af[i], bf[j], acc[i][j], 0, 0, 0);

        asm volatile("s_waitcnt lgkmcnt(0)" ::: "memory");
        __builtin_amdgcn_sched_barrier(0);
        __builtin_amdgcn_s_barrier();
    }

    // ---- stage accumulator tile into LDS (bf16) ----
#pragma unroll
    for (int i = 0; i < FM; ++i)
#pragma unroll
        for (int j = 0; j < FN; ++j) {
            int cc = wn * 64 + j * 16 + (lane & 15);
#pragma unroll
            for (int e = 0; e < 4; ++e) {
                int r = wm * WM + i * 16 + (lane >> 4) * 4 + e;
                smem[r * BNout + cc] = f2b(acc[i][j][e]);
            }
        }
    __syncthreads();

    if (bn == 2) {
        constexpr int CH = BM * BNout / 8;
#pragma unroll
        for (int p = 0; p < CH / 256; ++p) {
            int idx = p * 256 + tid;
            int r = idx / (BNout / 8);
            int c8 = idx % (BNout / 8);
            int grow = m0 + r;
            if (grow < M)
                *reinterpret_cast<int4*>(&xm[(size_t)grow * BNout + c8 * 8]) =
                    *reinterpret_cast<const int4*>(&smem[r * BNout + c8 * 8]);
        }
    } else {
#pragma unroll
        for (int p = 0; p < (BM * (HB / 8)) / 256; ++p) {
            int idx = p * 256 + tid;
            int r = idx / (HB / 8);
            int c8 = idx % (HB / 8);
            int grow = m0 + r;
            if (grow < M)
                *reinterpret_cast<int4*>(&xh[(size_t)grow * BNout + bn * HB + c8 * 8]) =
                    *reinterpret_cast<const int4*>(&smem[r * BNout + HB + c8 * 8]);
        }
#pragma unroll
        for (int p = 0; p < (BM * (BNout / 4)) / 256; ++p) {
            int idx = p * 256 + tid;
            int r = idx / (BNout / 4);
            int k = idx % (BNout / 4);
            int grow = m0 + r;
            if (grow < M) {
                unsigned lw = *reinterpret_cast<const unsigned*>(&smem[r * BNout + 2 * k]);
                unsigned hw = *reinterpret_cast<const unsigned*>(&smem[r * BNout + HB + 2 * k]);
                unsigned w;
                if (BNout == 128) {
                    w = __builtin_amdgcn_cvt_pk_fp8_f32(b2f_lo(lw), b2f_hi(lw), 0, false);
                    w = __builtin_amdgcn_cvt_pk_fp8_f32(b2f_lo(hw), b2f_hi(hw), w, true);
                } else {
                    w = __builtin_amdgcn_cvt_pk_fp8_f32(b2f_lo(lw), b2f_lo(hw), 0, false);
                    w = __builtin_amdgcn_cvt_pk_fp8_f32(b2f_hi(lw), b2f_hi(hw), w, true);
                }
                xq[(size_t)grow * (BNout / 2) + bn * (BNout / 4) + k] = w;
            }
        }
    }
}

template <int BNout>
struct GemmSmem {
    static constexpr int SM1 = 2 * (128 * 32 + BNout * 32);
    static constexpr int SM2 = 128 * BNout;
    static constexpr int SZ = SM1 > SM2 ? SM1 : SM2;
};

// ---------------------------------------------------------------------------
// Fused layer-1 GEMM + edge scatter (Bresenham-interleaved roles)
// ---------------------------------------------------------------------------
template <int K, int BNout>
__global__ __launch_bounds__(256) void gemm_scatter(const short* __restrict__ A,
                                                    const short* __restrict__ Bt,
                                                    unsigned* __restrict__ xq,
                                                    short* __restrict__ xh,
                                                    short* __restrict__ xm,
                                                    int M, int nGemm,
                                                    const int* __restrict__ row,
                                                    const int* __restrict__ col,
                                                    const float* __restrict__ val,
                                                    int* __restrict__ cursor,
                                                    int2* __restrict__ edges, int E,
                                                    int nScat) {
    __shared__ short smem[GemmSmem<BNout>::SZ];

    const int total = nGemm + nScat;
    const int swz = xcd_swz(blockIdx.x, total);
    const long ns_b = ((long)swz * nScat) / total;
    const long ns_a = ((long)(swz + 1) * nScat) / total;

    if (ns_a != ns_b) {
        int i = (int)ns_b * 256 + threadIdx.x;
        if (i < E) {
            int r = row[i];
            int p = atomicAdd(&cursor[r], 1);
            int2 rec;
            rec.x = col[i];
            rec.y = __builtin_bit_cast(int, val[i]);
            edges[p] = rec;
        }
        return;
    }
    gemm_body<K, BNout>(A, Bt, xq, xh, xm, M, swz - (int)ns_b, smem);
}

// ---------------------------------------------------------------------------
// Standalone layer-2 GEMM
// ---------------------------------------------------------------------------
template <int K, int BNout>
__global__ __launch_bounds__(256) void gemm_mfma(const short* __restrict__ A,
                                                 const short* __restrict__ Bt,
                                                 unsigned* __restrict__ xq,
                                                 short* __restrict__ xh,
                                                 short* __restrict__ xm,
                                                 int M) {
    __shared__ short smem[GemmSmem<BNout>::SZ];
    gemm_body<K, BNout>(A, Bt, xq, xh, xm, M, xcd_swz(blockIdx.x, gridDim.x), smem);
}

// ---------------------------------------------------------------------------
// CSR scan chain
// ---------------------------------------------------------------------------
__global__ __launch_bounds__(256) void block_sums_kernel(const int* __restrict__ counts,
                                                         int* __restrict__ bsums, int n) {
    __shared__ int s[256];
    int tid = threadIdx.x;
    int i = blockIdx.x * 256 + tid;
    s[tid] = (i < n) ? counts[i] : 0;
    __syncthreads();
#pragma unroll
    for (int off = 128; off > 0; off >>= 1) {
        if (tid < off) s[tid] += s[tid + off];
        __syncthreads();
    }
    if (tid == 0) bsums[blockIdx.x] = s[0];
}

__global__ __launch_bounds__(256) void scan_bsums_kernel(int* __restrict__ bsums, int nb) {
    __shared__ int s[256];
    int t = threadIdx.x;
    int v = (t < nb) ? bsums[t] : 0;
    s[t] = v;
    __syncthreads();
#pragma unroll
    for (int off = 1; off < 256; off <<= 1) {
        int u = (t >= off) ? s[t - off] : 0;
        __syncthreads();
        s[t] += u;
        __syncthreads();
    }
    if (t < nb) bsums[t] = s[t] - v;      // exclusive
}

__global__ __launch_bounds__(256) void scan_final_kernel(const int* __restrict__ counts,
                                                         const int* __restrict__ bsums,
                                                         int* __restrict__ rowptr,
                                                         int* __restrict__ cursor, int n) {
    __shared__ int s[256];
    int tid = threadIdx.x;
    int i = blockIdx.x * 256 + tid;
    int v = (i < n) ? counts[i] : 0;
    s[tid] = v;
    __syncthreads();
#pragma unroll
    for (int off = 1; off < 256; off <<= 1) {
        int t = (tid >= off) ? s[tid - off] : 0;
        __syncthreads();
        s[tid] += t;
        __syncthreads();
    }
    int excl = s[tid] - v + bsums[blockIdx.x];
    if (i < n) {
        rowptr[i] = excl;
        cursor[i] = excl;
        if (i == n - 1) rowptr[n] = excl + v;
    }
}

// ---------------------------------------------------------------------------
__device__ __forceinline__ float wave_sum(float v) {
#pragma unroll
    for (int off = 32; off > 0; off >>= 1) v += __shfl_xor(v, off, 64);
    return v;
}
__device__ __forceinline__ float wave_max(float v) {
#pragma unroll
    for (int off = 32; off > 0; off >>= 1) v = fmaxf(v, __shfl_xor(v, off, 64));
    return v;
}

// ---------------------------------------------------------------------------
// Layer-1 fused: dual CSR spmm (fp8 gathers) + attention + combine -> h bf16.
// ---------------------------------------------------------------------------
__global__ __launch_bounds__(256) void spmm_att1(const int* __restrict__ rowptr,
                                                 const int2* __restrict__ edges,
                                                 const unsigned* __restrict__ xq,
                                                 const unsigned* __restrict__ xhp,
                                                 const unsigned* __restrict__ xmp,
                                                 const float* __restrict__ a_low,
                                                 const float* __restrict__ a_high,
                                                 const float* __restrict__ a_mlp,
                                                 const float* __restrict__ av,
                                                 short* __restrict__ hb,
                                                 int n) {
    const int node = blockIdx.x * 4 + (threadIdx.x >> 6);
    const int lane = threadIdx.x & 63;
    if (node >= n) return;

    const int s = __builtin_amdgcn_readfirstlane(rowptr[node]);
    const int e = __builtin_amdgcn_readfirstlane(rowptr[node + 1]);

    float l0 = 0.f, l1 = 0.f, h0 = 0.f, h1 = 0.f;
    for (int j = s; j < e; j += 8) {
        int   cq[8];
        float vq[8];
#pragma unroll
        for (int q = 0; q < 8; ++q) {
            const int jj = min(j + q, e - 1);
            const int2 rec = edges[jj];
            cq[q] = __builtin_amdgcn_readfirstlane(rec.x);
            int vb = __builtin_amdgcn_readfirstlane(rec.y);
            float t = __builtin_bit_cast(float, vb);
            vq[q] = (j + q < e) ? t : 0.f;
        }
        unsigned p[8];
#pragma unroll
        for (int q = 0; q < 8; ++q)
            p[q] = xq[(size_t)cq[q] * 64 + lane];
#pragma unroll
        for (int q = 0; q < 8; ++q) {
            const f32x2 lo = q2_lo(p[q]);
            const f32x2 hi = q2_hi(p[q]);
            l0 += vq[q] * lo.x; l1 += vq[q] * lo.y;
            h0 += vq[q] * hi.x; h1 += vq[q] * hi.y;
        }
    }

    const unsigned xhn = xhp[(size_t)node * 64 + lane];
    const unsigned xmn = xmp[(size_t)node * 64 + lane];
    float ol0 = fmaxf(l0, 0.f);
    float ol1 = fmaxf(l1, 0.f);
    float oh0 = fmaxf(b2f_lo(xhn) - h0, 0.f);
    float oh1 = fmaxf(b2f_hi(xhn) - h1, 0.f);
    float om0 = fmaxf(b2f_lo(xmn), 0.f);
    float om1 = fmaxf(b2f_hi(xmn), 0.f);

    const float2 aL = ((const float2*)a_low)[lane];
    const float2 aH = ((const float2*)a_high)[lane];
    const float2 aM = ((const float2*)a_mlp)[lane];
    float dl = wave_sum(ol0 * aL.x + ol1 * aL.y);
    float dh = wave_sum(oh0 * aH.x + oh1 * aH.y);
    float dm = wave_sum(om0 * aM.x + om1 * aM.y);

    const float g0 = 1.f / (1.f + expf(-dl));
    const float g1 = 1.f / (1.f + expf(-dh));
    const float g2 = 1.f / (1.f + expf(-dm));
    float s0 = (g0 * av[0] + g1 * av[3] + g2 * av[6]) * (1.f / 3.f);
    float s1 = (g0 * av[1] + g1 * av[4] + g2 * av[7]) * (1.f / 3.f);
    float s2 = (g0 * av[2] + g1 * av[5] + g2 * av[8]) * (1.f / 3.f);
    float mx = fmaxf(s0, fmaxf(s1, s2));
    float e0 = expf(s0 - mx), e1 = expf(s1 - mx), e2 = expf(s2 - mx);
    float inv = 1.f / (e0 + e1 + e2);
    float at0 = e0 * inv, at1 = e1 * inv, at2 = e2 * inv;

    float ho0 = 3.f * (at0 * ol0 + at1 * oh0 + at2 * om0);
    float ho1 = 3.f * (at0 * ol1 + at1 * oh1 + at2 * om1);
    unsigned pk = (unsigned)(unsigned short)f2b(ho0) |
                  ((unsigned)(unsigned short)f2b(ho1) << 16);
    ((unsigned*)hb)[(size_t)node * 64 + lane] = pk;
}

// ---------------------------------------------------------------------------
// Layer-2 fused: dual CSR spmm (fp8 ushort gathers) + attention + combine +
// log_softmax -> out.
// ---------------------------------------------------------------------------
__global__ __launch_bounds__(256) void spmm_att2(const int* __restrict__ rowptr,
                                                 const int2* __restrict__ edges,
                                                 const unsigned short* __restrict__ xq,
                                                 const short* __restrict__ xhp,
                                                 const short* __restrict__ xmp,
                                                 const float* __restrict__ a_low,
                                                 const float* __restrict__ a_high,
                                                 const float* __restrict__ a_mlp,
                                                 const float* __restrict__ av,
                                                 float* __restrict__ out,
                                                 int n) {
    const int node = blockIdx.x * 4 + (threadIdx.x >> 6);
    const int lane = threadIdx.x & 63;
    if (node >= n) return;

    const int s = __builtin_amdgcn_readfirstlane(rowptr[node]);
    const int e = __builtin_amdgcn_readfirstlane(rowptr[node + 1]);

    float accl = 0.f, acch = 0.f;
    for (int j = s; j < e; j += 8) {
        int   cq[8];
        float vq[8];
#pragma unroll
        for (int q = 0; q < 8; ++q) {
            const int jj = min(j + q, e - 1);
            const int2 rec = edges[jj];
            cq[q] = __builtin_amdgcn_readfirstlane(rec.x);
            int vb = __builtin_amdgcn_readfirstlane(rec.y);
            float t = __builtin_bit_cast(float, vb);
            vq[q] = (j + q < e) ? t : 0.f;
        }
        unsigned short p[8];
#pragma unroll
        for (int q = 0; q < 8; ++q)
            p[q] = xq[(size_t)cq[q] * 64 + lane];
#pragma unroll
        for (int q = 0; q < 8; ++q) {
            const f32x2 d = q2_lo((unsigned)p[q]);
            accl += vq[q] * d.x;
            acch += vq[q] * d.y;
        }
    }

    float ol = fmaxf(accl, 0.f);
    float oh = fmaxf(b2f(xhp[(size_t)node * 64 + lane]) - acch, 0.f);
    float om = fmaxf(b2f(xmp[(size_t)node * 64 + lane]), 0.f);

    float dl = wave_sum(ol * a_low[lane]);
    float dh = wave_sum(oh * a_high[lane]);
    float dm = wave_sum(om * a_mlp[lane]);

    const float g0 = 1.f / (1.f + expf(-dl));
    const float g1 = 1.f / (1.f + expf(-dh));
    const float g2 = 1.f / (1.f + expf(-dm));
    float s0 = (g0 * av[0] + g1 * av[3] + g2 * av[6]) * (1.f / 3.f);
    float s1 = (g0 * av[1] + g1 * av[4] + g2 * av[7]) * (1.f / 3.f);
    float s2 = (g0 * av[2] + g1 * av[5] + g2 * av[8]) * (1.f / 3.f);
    float mx3 = fmaxf(s0, fmaxf(s1, s2));
    float e0 = expf(s0 - mx3), e1 = expf(s1 - mx3), e2 = expf(s2 - mx3);
    float inv = 1.f / (e0 + e1 + e2);
    float at0 = e0 * inv, at1 = e1 * inv, at2 = e2 * inv;

    float o = 3.f * (at0 * ol + at1 * oh + at2 * om);

    float m = wave_max(o);
    float ex = expf(o - m);
    float su = wave_sum(ex);
    out[(size_t)node * 64 + lane] = o - m - logf(su);
}

// ---------------------------------------------------------------------------
extern "C" void kernel_launch(void* const* d_in, const int* in_sizes, int n_in,
                              void* d_out, int out_size, void* d_ws, size_t ws_size,
                              hipStream_t stream) {
    const float* x    = (const float*)d_in[0];
    const int*   erow = (const int*)d_in[1];
    const int*   ecol = (const int*)d_in[2];
    const float* eval = (const float*)d_in[3];
    const float* Wl   = (const float*)d_in[4];
    const float* Wh   = (const float*)d_in[5];
    const float* Wm   = (const float*)d_in[6];
    const float* al   = (const float*)d_in[7];
    const float* ah   = (const float*)d_in[8];
    const float* am   = (const float*)d_in[9];
    const float* av   = (const float*)d_in[10];
    const float* Wl2  = (const float*)d_in[11];
    const float* Wh2  = (const float*)d_in[12];
    const float* Wm2  = (const float*)d_in[13];
    const float* al2  = (const float*)d_in[14];
    const float* ah2  = (const float*)d_in[15];
    const float* am2  = (const float*)d_in[16];
    const float* av2  = (const float*)d_in[17];
    float* out = (float*)d_out;

    const int E = in_sizes[1];
    const int N = NN;

    short* ws    = (short*)d_ws;
    short* xb    = ws;                          // N*512 bf16 (converted x)
    short* xh1   = xb + (size_t)N * 512;        // N*128 bf16 plane
    short* xm1   = xh1 + (size_t)N * 128;       // N*128 bf16 plane
    short* hb    = xm1 + (size_t)N * 128;       // N*128 bf16
    unsigned* xq1 = (unsigned*)(hb + (size_t)N * 128);   // N*64 dwords (12.8 MB)
    short* Bt1   = (short*)(xq1 + (size_t)N * 64);       // 384*512
    short* Bt2   = Bt1 + 384 * 512;             // 192*128
    int*   ip    = (int*)(Bt2 + 192 * 128);
    int*   counts = ip;                         // N
    int*   rowptr = ip + N;                     // N+1
    int*   cursor = ip + 2 * N + 1;             // N
    int*   bsums  = ip + 3 * N + 1;             // 256
    int2*  edges  = (int2*)(((size_t)(ip + 3 * N + 1 + 256) + 15) & ~(size_t)15); // E int2

    // Layer-2 aliases (xh1/xm1/xq1 dead after spmm_att1)
    unsigned* xq2 = xq1;                        // N*32 dwords (N*64 fp8 ushorts)
    short* xh2 = xh1;                           // N*64 bf16
    short* xm2 = xh1 + (size_t)N * 64;          // N*64 bf16

    const int NB = (N + 255) / 256;
    const int EB = (E + 255) / 256;
    const int node_blocks = (N + 3) / 4;
    const int MT = (N + 127) / 128;
    const int XCB = (N * F_IN / 8 + 255) / 256;
    const int W1B = (3 * HH * (F_IN / 8) + 255) / 256;
    const int W2B = (3 * CC * (HH / 8) + 255) / 256;
    const int nGemm1 = MT * 3;

    // ---------------- prep (fused) + CSR scan chain ----------------
    prep0<<<NB + W1B + W2B, 256, 0, stream>>>(counts, N, Wl, Wh, Wm, Bt1,
                                              Wl2, Wh2, Wm2, Bt2, NB, W1B);
    hist_xconv<<<EB + XCB, 256, 0, stream>>>(erow, counts, E, x, xb,
                                             N * F_IN / 8, EB);
    block_sums_kernel<<<NB, 256, 0, stream>>>(counts, bsums, N);
    scan_bsums_kernel<<<1, 256, 0, stream>>>(bsums, NB);
    scan_final_kernel<<<NB, 256, 0, stream>>>(counts, bsums, rowptr, cursor, N);

    // ---------------- Layer 1 (gemm interleaved with edge scatter) ----------
    gemm_scatter<F_IN, HH><<<nGemm1 + EB, 256, 0, stream>>>(
        xb, Bt1, xq1, xh1, xm1, N, nGemm1, erow, ecol, eval, cursor, edges, E, EB);
    spmm_att1<<<node_blocks, 256, 0, stream>>>(rowptr, edges, xq1,
                                               (const unsigned*)xh1,
                                               (const unsigned*)xm1,
                                               al, ah, am, av, hb, N);

    // ---------------- Layer 2 ----------------
    gemm_mfma<HH, CC><<<MT * 3, 256, 0, stream>>>(hb, Bt2, xq2, xh2, xm2, N);
    spmm_att2<<<node_blocks, 256, 0, stream>>>(rowptr, edges,
                                               (const unsigned short*)xq2,
                                               xh2, xm2,
                                               al2, ah2, am2, av2, out, N);
}